// Round 1
// baseline (367.388 us; speedup 1.0000x reference)
//
#include <hip/hip_runtime.h>

#define SS 30
#define DD 14
#define MM 28

// LDS layout (float offsets)
#define XB  0      // 420: x, later tanh(y_s)
#define XN  420    // 420: xn, later y_m
#define ULO 840    // 840: ul, later h
#define URO 1680   // 840: ur
#define CBO 2520   // 840: c
#define QBO 3360   // 840: q, later e
#define KBO 4200   // 840: k
#define VBO 5040   // 840: v, later gx(240)+hs(60)
#define GIF 5880   // 60
#define STT 5940   // 60
#define SMTOT 6000

__device__ __forceinline__ float fsigm(float v){ return 1.f/(1.f+__expf(-v)); }
__device__ __forceinline__ float fsilu(float v){ return v/(1.f+__expf(-v)); }
__device__ __forceinline__ float ftanh_(float v){
    float c = fminf(fmaxf(v, -15.f), 15.f);
    float e = __expf(2.f*c);
    return (e-1.f)/(e+1.f);
}
__device__ __forceinline__ float fgelu(float v){
    float t = ftanh_(0.7978845608028654f*(v + 0.044715f*v*v*v));
    return 0.5f*v*(1.f+t);
}

extern "C" __global__ void __launch_bounds__(64)
net_kernel(const float* __restrict__ xg,
           const float* __restrict__ ln_g, const float* __restrict__ ln_b,
           const float* __restrict__ Wup_l, const float* __restrict__ bup_l,
           const float* __restrict__ Wup_r, const float* __restrict__ bup_r,
           const float* __restrict__ conv_w, const float* __restrict__ conv_b,
           const float* __restrict__ Wq, const float* __restrict__ bq,
           const float* __restrict__ Wk, const float* __restrict__ bk,
           const float* __restrict__ Wv, const float* __restrict__ bv,
           const float* __restrict__ Wif, const float* __restrict__ bif,
           const float* __restrict__ gn_g, const float* __restrict__ gn_b,
           const float* __restrict__ skip,
           const float* __restrict__ Wdown, const float* __restrict__ bdown,
           const float* __restrict__ s_ln_g, const float* __restrict__ s_ln_b,
           const float* __restrict__ sW, const float* __restrict__ sR, const float* __restrict__ sb,
           const float* __restrict__ s_gn_g, const float* __restrict__ s_gn_b,
           const float* __restrict__ sWup1, const float* __restrict__ sbup1,
           const float* __restrict__ sWup2, const float* __restrict__ sbup2,
           const float* __restrict__ sWdown, const float* __restrict__ sbdown,
           const float* __restrict__ fc1w, const float* __restrict__ fc1b,
           const float* __restrict__ fc3w, const float* __restrict__ fc3b,
           float* __restrict__ out)
{
    __shared__ float sm[SMTOT];
    const int lane = threadIdx.x;
    const int b = blockIdx.x;
    const float* xp = xg + (size_t)b * (SS*DD);

    // ---- load x ----
    for (int idx = lane; idx < SS*DD; idx += 64) sm[XB+idx] = xp[idx];
    __syncthreads();

    // ---- LN1 stats ----
    if (lane < SS) {
        float s=0.f, s2=0.f;
        #pragma unroll
        for (int d=0; d<DD; d++){ float v = sm[XB+lane*DD+d]; s+=v; s2+=v*v; }
        float mu = s*(1.f/DD);
        float var = s2*(1.f/DD) - mu*mu;
        sm[STT+lane*2]   = mu;
        sm[STT+lane*2+1] = rsqrtf(var + 1e-5f);
    }
    __syncthreads();
    // ---- xn ----
    for (int idx = lane; idx < SS*DD; idx += 64){
        int t = idx / DD, d = idx - t*DD;
        sm[XN+idx] = (sm[XB+idx]-sm[STT+t*2])*sm[STT+t*2+1]*ln_g[d] + ln_b[d];
    }
    __syncthreads();
    // ---- ul, ur ----
    for (int idx = lane; idx < SS*MM; idx += 64){
        int t = idx / MM, j = idx - t*MM;
        float a = bup_l[j], c = bup_r[j];
        #pragma unroll
        for (int d=0; d<DD; d++){
            float xv = sm[XN+t*DD+d];
            a += xv * Wup_l[d*MM+j];
            c += xv * Wup_r[d*MM+j];
        }
        sm[ULO+idx] = a;
        sm[URO+idx] = c;
    }
    __syncthreads();
    // ---- conv + silu -> c ----
    for (int idx = lane; idx < SS*MM; idx += 64){
        int t = idx / MM, j = idx - t*MM;
        float a = conv_b[j];
        #pragma unroll
        for (int k=0; k<4; k++){
            int tt = t - 3 + k;
            if (tt >= 0) a += sm[ULO+tt*MM+j] * conv_w[k*MM+j];
        }
        sm[CBO+idx] = fsilu(a);
    }
    __syncthreads();
    // ---- q, k, v ----
    const float rs28 = 0.18898223650461363f; // 1/sqrt(28)
    for (int idx = lane; idx < SS*MM; idx += 64){
        int t = idx / MM, j = idx - t*MM;
        float aq = bq[j], ak = bk[j], av = bv[j];
        #pragma unroll
        for (int h=0; h<MM; h++){
            float cv = sm[CBO+t*MM+h];
            float uv = sm[ULO+t*MM+h];
            aq += cv * Wq[h*MM+j];
            ak += cv * Wk[h*MM+j];
            av += uv * Wv[h*MM+j];
        }
        sm[QBO+idx] = aq;
        sm[KBO+idx] = ak * rs28;
        sm[VBO+idx] = av;
    }
    // ---- gif ----
    for (int idx = lane; idx < SS*2; idx += 64){
        int t = idx >> 1, g = idx & 1;
        float a = bif[g];
        #pragma unroll
        for (int h=0; h<MM; h++) a += sm[CBO+t*MM+h]*Wif[h*2+g];
        sm[GIF+idx] = a;
    }
    __syncthreads();

    // ---- mLSTM scan: lane i owns row i of C ----
    {
        float C[MM];
        #pragma unroll
        for (int j=0;j<MM;j++) C[j]=0.f;
        float n_i = 0.f, mst = 0.f;
        const int i = lane;
        for (int t=0; t<SS; t++){
            float it = sm[GIF+t*2], ft = sm[GIF+t*2+1];
            float mnew = fmaxf(ft+mst, it);
            float ig = __expf(it-mnew);
            float fg = __expf(ft+mst-mnew);
            mst = mnew;
            float vi = (i<MM) ? sm[VBO+t*MM+i] : 0.f;
            float igv = ig*vi;
            float kk4[MM], qq4[MM];
            const float4* kp = (const float4*)&sm[KBO+t*MM];
            const float4* qp = (const float4*)&sm[QBO+t*MM];
            #pragma unroll
            for (int j4=0;j4<7;j4++){
                float4 kf = kp[j4], qf = qp[j4];
                kk4[4*j4+0]=kf.x; kk4[4*j4+1]=kf.y; kk4[4*j4+2]=kf.z; kk4[4*j4+3]=kf.w;
                qq4[4*j4+0]=qf.x; qq4[4*j4+1]=qf.y; qq4[4*j4+2]=qf.z; qq4[4*j4+3]=qf.w;
            }
            float h0=0.f,h1=0.f,h2a=0.f,h3=0.f;
            #pragma unroll
            for (int j=0;j<MM;j+=4){
                C[j]   = fg*C[j]   + igv*kk4[j];
                C[j+1] = fg*C[j+1] + igv*kk4[j+1];
                C[j+2] = fg*C[j+2] + igv*kk4[j+2];
                C[j+3] = fg*C[j+3] + igv*kk4[j+3];
                h0 += C[j]*qq4[j];
                h1 += C[j+1]*qq4[j+1];
                h2a += C[j+2]*qq4[j+2];
                h3 += C[j+3]*qq4[j+3];
            }
            float ki = (i<MM) ? kk4[0]*0.f + sm[KBO+t*MM+i] : 0.f;
            float qi = (i<MM) ? sm[QBO+t*MM+i] : 0.f;
            n_i = fg*n_i + ig*ki;
            float p = n_i*qi;
            #pragma unroll
            for (int off=32; off>=1; off>>=1) p += __shfl_xor(p, off, 64);
            float denom = fmaxf(fabsf(p), 1.f);
            float inv = 1.f/denom;
            if (i < MM) sm[ULO+t*MM+i] = (h0+h1+h2a+h3)*inv;  // h overlays ul
        }
    }
    __syncthreads();

    // ---- GroupNorm stats over h rows ----
    if (lane < SS) {
        float s=0.f, s2=0.f;
        #pragma unroll
        for (int j=0;j<MM;j++){ float v=sm[ULO+lane*MM+j]; s+=v; s2+=v*v; }
        float mu = s*(1.f/MM);
        float var = s2*(1.f/MM) - mu*mu;
        sm[STT+lane*2]   = mu;
        sm[STT+lane*2+1] = rsqrtf(var+1e-5f);
    }
    __syncthreads();
    // ---- e = (hn + skip*c)*silu(ur) -> overlays q ----
    for (int idx = lane; idx < SS*MM; idx += 64){
        int t = idx / MM, j = idx - t*MM;
        float hn = (sm[ULO+idx]-sm[STT+t*2])*sm[STT+t*2+1]*gn_g[j] + gn_b[j];
        float h2v = hn + skip[j]*sm[CBO+idx];
        sm[QBO+idx] = h2v * fsilu(sm[URO+idx]);
    }
    __syncthreads();
    // ---- y_m = e @ Wdown + bdown + x -> overlays xn ----
    for (int idx = lane; idx < SS*DD; idx += 64){
        int t = idx / DD, d = idx - t*DD;
        float a = bdown[d] + sm[XB+idx];
        #pragma unroll
        for (int i2=0;i2<MM;i2++) a += sm[QBO+t*MM+i2]*Wdown[i2*DD+d];
        sm[XN+idx] = a;
    }
    __syncthreads();

    // ---- sLSTM LN stats over y_m ----
    if (lane < SS) {
        float s=0.f, s2=0.f;
        #pragma unroll
        for (int d=0; d<DD; d++){ float v=sm[XN+lane*DD+d]; s+=v; s2+=v*v; }
        float mu = s*(1.f/DD);
        float var = s2*(1.f/DD) - mu*mu;
        sm[STT+lane*2]   = mu;
        sm[STT+lane*2+1] = rsqrtf(var+1e-5f);
    }
    __syncthreads();
    // ---- gx = yn @ sW + sb -> overlays v region ----
    for (int idx = lane; idx < SS*8; idx += 64){
        int t = idx >> 3, g = idx & 7;
        float a = sb[g];
        float mu = sm[STT+t*2], rsg = sm[STT+t*2+1];
        #pragma unroll
        for (int d=0; d<DD; d++){
            float yn = (sm[XN+t*DD+d]-mu)*rsg*s_ln_g[d] + s_ln_b[d];
            a += yn * sW[d*8+g];
        }
        sm[VBO+idx] = a;
    }
    __syncthreads();
    // ---- sLSTM scan (redundant on all lanes; lane0 writes hs) ----
    {
        float R0[8], R1[8];
        #pragma unroll
        for (int g=0; g<8; g++){ R0[g]=sR[g]; R1[g]=sR[8+g]; }
        float h0=0.f,h1=0.f,c0=0.f,c1=0.f,n0=0.f,n1=0.f,m0=0.f,m1=0.f;
        for (int t=0; t<SS; t++){
            float g[8];
            #pragma unroll
            for (int gg=0; gg<8; gg++) g[gg] = sm[VBO+t*8+gg] + h0*R0[gg] + h1*R1[gg];
            float z0=ftanh_(g[0]), z1=ftanh_(g[1]);
            float i0=g[2], i1=g[3], f0=g[4], f1=g[5];
            float o0=fsigm(g[6]), o1=fsigm(g[7]);
            float mn0=fmaxf(f0+m0, i0), mn1=fmaxf(f1+m1, i1);
            float ie0=__expf(i0-mn0), ie1=__expf(i1-mn1);
            float fe0=__expf(f0+m0-mn0), fe1=__expf(f1+m1-mn1);
            c0 = fe0*c0 + ie0*z0;  c1 = fe1*c1 + ie1*z1;
            n0 = fe0*n0 + ie0;     n1 = fe1*n1 + ie1;
            h0 = o0*c0/n0;         h1 = o1*c1/n1;
            m0 = mn0; m1 = mn1;
            if (lane == 0){ sm[VBO+240+t*2] = h0; sm[VBO+240+t*2+1] = h1; }
        }
    }
    __syncthreads();
    // ---- y_s epilogue + tanh -> overlays x ----
    for (int idx = lane; idx < SS*DD; idx += 64){
        int t = idx / DD, d = idx - t*DD;
        float a0 = sm[VBO+240+t*2], a1 = sm[VBO+240+t*2+1];
        float mu = 0.5f*(a0+a1);
        float d0 = a0-mu, d1 = a1-mu;
        float var = 0.5f*(d0*d0 + d1*d1);
        float rsg = rsqrtf(var + 1e-5f);
        float hn0 = d0*rsg*s_gn_g[0] + s_gn_b[0];
        float hn1 = d1*rsg*s_gn_g[1] + s_gn_b[1];
        float acc = sbdown[d] + sm[XN+idx];
        #pragma unroll
        for (int u3=0; u3<3; u3++){
            float p1 = hn0*sWup1[u3] + hn1*sWup1[3+u3] + sbup1[u3];
            float p2 = hn0*sWup2[u3] + hn1*sWup2[3+u3] + sbup2[u3];
            acc += fgelu(p1)*p2*sWdown[u3*DD+d];
        }
        sm[XB+idx] = ftanh_(acc);
    }
    __syncthreads();
    // ---- head: fc1 (420->32, relu) then fc3 (32->1) ----
    {
        int j = lane & 31, half = lane >> 5;
        float a = 0.f;
        int dbase = half*210;
        for (int d=0; d<210; d++)
            a += sm[XB+dbase+d]*fc1w[(dbase+d)*32+j];
        a += __shfl_xor(a, 32, 64);
        a += fc1b[j];
        float r = fmaxf(a, 0.f);
        float p = r * fc3w[j];
        #pragma unroll
        for (int off=16; off>=1; off>>=1) p += __shfl_xor(p, off, 64);
        if (lane == 0) out[b] = p + fc3b[0];
    }
}

extern "C" void kernel_launch(void* const* d_in, const int* in_sizes, int n_in,
                              void* d_out, int out_size, void* d_ws, size_t ws_size,
                              hipStream_t stream) {
    const float* x      = (const float*)d_in[0];
    const float* ln_g   = (const float*)d_in[1];
    const float* ln_b   = (const float*)d_in[2];
    const float* Wup_l  = (const float*)d_in[3];
    const float* bup_l  = (const float*)d_in[4];
    const float* Wup_r  = (const float*)d_in[5];
    const float* bup_r  = (const float*)d_in[6];
    const float* conv_w = (const float*)d_in[7];
    const float* conv_b = (const float*)d_in[8];
    const float* Wq     = (const float*)d_in[9];
    const float* bq     = (const float*)d_in[10];
    const float* Wk     = (const float*)d_in[11];
    const float* bk     = (const float*)d_in[12];
    const float* Wv     = (const float*)d_in[13];
    const float* bv     = (const float*)d_in[14];
    const float* Wif    = (const float*)d_in[15];
    const float* bif    = (const float*)d_in[16];
    const float* gn_g   = (const float*)d_in[17];
    const float* gn_b   = (const float*)d_in[18];
    const float* skip   = (const float*)d_in[19];
    const float* Wdown  = (const float*)d_in[20];
    const float* bdown  = (const float*)d_in[21];
    const float* s_ln_g = (const float*)d_in[22];
    const float* s_ln_b = (const float*)d_in[23];
    const float* sW     = (const float*)d_in[24];
    const float* sR     = (const float*)d_in[25];
    const float* sb     = (const float*)d_in[26];
    const float* s_gn_g = (const float*)d_in[27];
    const float* s_gn_b = (const float*)d_in[28];
    const float* sWup1  = (const float*)d_in[29];
    const float* sbup1  = (const float*)d_in[30];
    const float* sWup2  = (const float*)d_in[31];
    const float* sbup2  = (const float*)d_in[32];
    const float* sWdown = (const float*)d_in[33];
    const float* sbdown = (const float*)d_in[34];
    const float* fc1w   = (const float*)d_in[35];
    const float* fc1b   = (const float*)d_in[36];
    const float* fc3w   = (const float*)d_in[37];
    const float* fc3b   = (const float*)d_in[38];
    float* out = (float*)d_out;

    hipLaunchKernelGGL(net_kernel, dim3(8192), dim3(64), 0, stream,
        x, ln_g, ln_b, Wup_l, bup_l, Wup_r, bup_r, conv_w, conv_b,
        Wq, bq, Wk, bk, Wv, bv, Wif, bif, gn_g, gn_b, skip, Wdown, bdown,
        s_ln_g, s_ln_b, sW, sR, sb, s_gn_g, s_gn_b,
        sWup1, sbup1, sWup2, sbup2, sWdown, sbdown,
        fc1w, fc1b, fc3w, fc3b, out);
}

// Round 2
// 221.144 us; speedup vs baseline: 1.6613x; 1.6613x over previous
//
#include <hip/hip_runtime.h>

#define SS 30
#define DD 14
#define MM 28

// LDS float offsets (all multiples of 4 for b128 alignment)
#define XN 0       // 420: xn -> later y_m
#define UL 420     // 840: ul -> later h (row stride 28)
#define CB 1260    // 840: c  -> later tanh(y_s) (first 420)
#define QP 2100    // 960: q, rows padded to 32
#define KP 3060    // 960: k, rows padded to 32 -> later e (row stride 28)
#define VB 4020    // 840: v -> later gx(240)+hs(60)
#define GIF 4860   // 60
#define ST 4920    // 60
#define SMTOT 4980 // 19,920 B -> 8 blocks/CU

__device__ __forceinline__ float fsigm(float v){ return 1.f/(1.f+__expf(-v)); }
__device__ __forceinline__ float fsilu(float v){ return v/(1.f+__expf(-v)); }
__device__ __forceinline__ float ftanh_(float v){
    float c = fminf(fmaxf(v, -15.f), 15.f);
    float e = __expf(2.f*c);
    return (e-1.f)/(e+1.f);
}
__device__ __forceinline__ float fgelu(float v){
    float t = ftanh_(0.7978845608028654f*(v + 0.044715f*v*v*v));
    return 0.5f*v*(1.f+t);
}

extern "C" __global__ void __launch_bounds__(64)
net_kernel(const float* __restrict__ xg,
           const float* __restrict__ ln_g, const float* __restrict__ ln_b,
           const float* __restrict__ Wup_l, const float* __restrict__ bup_l,
           const float* __restrict__ Wup_r, const float* __restrict__ bup_r,
           const float* __restrict__ conv_w, const float* __restrict__ conv_b,
           const float* __restrict__ Wq, const float* __restrict__ bq,
           const float* __restrict__ Wk, const float* __restrict__ bk,
           const float* __restrict__ Wv, const float* __restrict__ bv,
           const float* __restrict__ Wif, const float* __restrict__ bif,
           const float* __restrict__ gn_g, const float* __restrict__ gn_b,
           const float* __restrict__ skip,
           const float* __restrict__ Wdown, const float* __restrict__ bdown,
           const float* __restrict__ s_ln_g, const float* __restrict__ s_ln_b,
           const float* __restrict__ sW, const float* __restrict__ sR, const float* __restrict__ sb,
           const float* __restrict__ s_gn_g, const float* __restrict__ s_gn_b,
           const float* __restrict__ sWup1, const float* __restrict__ sbup1,
           const float* __restrict__ sWup2, const float* __restrict__ sbup2,
           const float* __restrict__ sWdown, const float* __restrict__ sbdown,
           const float* __restrict__ fc1w, const float* __restrict__ fc1b,
           const float* __restrict__ fc3w, const float* __restrict__ fc3b,
           float* __restrict__ out)
{
    __shared__ __align__(16) float sm[SMTOT];
    const int lane = threadIdx.x;
    const int b = blockIdx.x;
    const float* xp = xg + (size_t)b * (SS*DD);

    // ---- Phase A: LN1 -> xn (lane = t) ----
    if (lane < SS){
        float xv[DD];
        const float2* xr = (const float2*)(xp + lane*DD);
        float s=0.f, s2=0.f;
        #pragma unroll
        for (int u=0;u<7;u++){ float2 f=xr[u]; xv[2*u]=f.x; xv[2*u+1]=f.y; s+=f.x+f.y; s2+=f.x*f.x+f.y*f.y; }
        float mu=s*(1.f/DD), var=s2*(1.f/DD)-mu*mu, rsg=rsqrtf(var+1e-5f);
        #pragma unroll
        for (int d=0; d<DD; d++) sm[XN+lane*DD+d] = (xv[d]-mu)*rsg*ln_g[d]+ln_b[d];
    }
    __syncthreads();

    // ---- Phase B: ul = xn @ Wup_l + bup_l  (lanes = (j, t-half), weights in regs) ----
    {
        const int jq = lane % MM;
        const int gq = lane / MM;
        const bool act = lane < 56;
        float wl[DD]; float blr=0.f;
        if (act){
            #pragma unroll
            for (int d=0; d<DD; d++) wl[d] = Wup_l[d*MM+jq];
            blr = bup_l[jq];
        }
        #pragma unroll
        for (int tt=0; tt<15; tt++){
            int t = gq*15+tt;
            if (act){
                const float2* xr = (const float2*)&sm[XN + t*DD];
                float a = blr;
                #pragma unroll
                for (int u=0;u<7;u++){ float2 f = xr[u]; a += f.x*wl[2*u] + f.y*wl[2*u+1]; }
                sm[UL + t*MM + jq] = a;
            }
        }
    }
    __syncthreads();

    // ---- Phase C: causal conv + silu -> c ----
    for (int idx=lane; idx<SS*MM; idx+=64){
        int t = idx/MM, j = idx-t*MM;
        float a = conv_b[j];
        #pragma unroll
        for (int k=0;k<4;k++){
            int tt=t-3+k;
            if (tt>=0) a += sm[UL+tt*MM+j]*conv_w[k*MM+j];
        }
        sm[CB+idx] = fsilu(a);
    }
    __syncthreads();

    // ---- Phase D0: zero the q/k column pads (cols 28..31) ----
    for (int idx=lane; idx<240; idx+=64){
        int row = idx>>3, m=(idx>>2)&1, jj=MM+(idx&3);
        sm[(m?KP:QP) + row*32 + jj] = 0.f;
    }
    // ---- Phase D1: gif = c @ Wif + bif ----
    for (int idx=lane; idx<SS*2; idx+=64){
        int t=idx>>1, gg=idx&1;
        float a = bif[gg];
        const float4* cr = (const float4*)&sm[CB+t*MM];
        #pragma unroll
        for (int h4=0;h4<7;h4++){ float4 cf=cr[h4];
            a += cf.x*Wif[(4*h4)*2+gg] + cf.y*Wif[(4*h4+1)*2+gg]
               + cf.z*Wif[(4*h4+2)*2+gg] + cf.w*Wif[(4*h4+3)*2+gg]; }
        sm[GIF+idx]=a;
    }
    // ---- Phase D2: q,k,v GEMMs (weights in regs, activation rows as float4) ----
    {
        const int jq = lane % MM, gq = lane / MM;
        const bool act = lane < 56;
        float wq[MM], wk[MM], wv[MM];
        float bqr=0.f, bkr=0.f, bvr=0.f;
        if (act){
            #pragma unroll
            for (int h=0;h<MM;h++){ wq[h]=Wq[h*MM+jq]; wk[h]=Wk[h*MM+jq]; wv[h]=Wv[h*MM+jq]; }
            bqr=bq[jq]; bkr=bk[jq]; bvr=bv[jq];
        }
        const float rs28 = 0.18898223650461363f; // 1/sqrt(28)
        #pragma unroll
        for (int tt=0; tt<15; tt++){
            int t = gq*15+tt;
            if (act){
                const float4* cr = (const float4*)&sm[CB + t*MM];
                const float4* ur = (const float4*)&sm[UL + t*MM];
                float aq=bqr, ak=bkr, av=bvr;
                #pragma unroll
                for (int h4=0;h4<7;h4++){
                    float4 cf=cr[h4], uf=ur[h4];
                    aq += cf.x*wq[4*h4] + cf.y*wq[4*h4+1] + cf.z*wq[4*h4+2] + cf.w*wq[4*h4+3];
                    ak += cf.x*wk[4*h4] + cf.y*wk[4*h4+1] + cf.z*wk[4*h4+2] + cf.w*wk[4*h4+3];
                    av += uf.x*wv[4*h4] + uf.y*wv[4*h4+1] + uf.z*wv[4*h4+2] + uf.w*wv[4*h4+3];
                }
                sm[QP + t*32 + jq] = aq;
                sm[KP + t*32 + jq] = ak*rs28;
                sm[VB + t*MM + jq] = av;
            }
        }
    }
    __syncthreads();

    // ---- Phase E: mLSTM scan — lane (i = l&31 row, g = l>>5 col-half of 16) ----
    {
        const int i = lane & 31;
        const int g = lane >> 5;
        const bool rowok = i < MM;
        float C[16];
        #pragma unroll
        for (int j=0;j<16;j++) C[j]=0.f;
        float n_i=0.f, mst=0.f;
        for (int t=0;t<SS;t++){
            float it = sm[GIF+2*t], ft = sm[GIF+2*t+1];
            float mnew = fmaxf(ft+mst, it);
            float ig = __expf(it-mnew);
            float fg = __expf(ft+mst-mnew);
            mst = mnew;
            float vi = rowok ? sm[VB+t*MM+i] : 0.f;
            float igv = ig*vi;
            const float4* kr = (const float4*)&sm[KP + t*32 + g*16];
            const float4* qr = (const float4*)&sm[QP + t*32 + g*16];
            float hp=0.f;
            #pragma unroll
            for (int c4=0;c4<4;c4++){
                float4 kf=kr[c4], qf=qr[c4];
                C[4*c4]   = fg*C[4*c4]   + igv*kf.x; hp += C[4*c4]*qf.x;
                C[4*c4+1] = fg*C[4*c4+1] + igv*kf.y; hp += C[4*c4+1]*qf.y;
                C[4*c4+2] = fg*C[4*c4+2] + igv*kf.z; hp += C[4*c4+2]*qf.z;
                C[4*c4+3] = fg*C[4*c4+3] + igv*kf.w; hp += C[4*c4+3]*qf.w;
            }
            float ki = rowok ? sm[KP+t*32+i] : 0.f;
            float qi = rowok ? sm[QP+t*32+i] : 0.f;
            n_i = fg*n_i + ig*ki;
            float p = n_i*qi*0.5f;   // rows duplicated across halves -> x0.5
            #pragma unroll
            for (int off=32; off>=1; off>>=1) p += __shfl_xor(p, off, 64);
            float inv = 1.f/fmaxf(fabsf(p), 1.f);
            float ho = hp + __shfl_xor(hp, 32, 64);
            if (g==0 && rowok) sm[UL + t*MM + i] = ho*inv;  // h overlays ul
        }
    }
    __syncthreads();

    // ---- Phase F: GroupNorm stats over h rows ----
    if (lane < SS){
        const float4* hr = (const float4*)&sm[UL+lane*MM];
        float s=0.f,s2=0.f;
        #pragma unroll
        for (int u=0;u<7;u++){ float4 f=hr[u]; s+=f.x+f.y+f.z+f.w; s2+=f.x*f.x+f.y*f.y+f.z*f.z+f.w*f.w; }
        float mu=s*(1.f/MM), var=s2*(1.f/MM)-mu*mu;
        sm[ST+lane*2]=mu; sm[ST+lane*2+1]=rsqrtf(var+1e-5f);
    }
    __syncthreads();

    // ---- Phase G: e = (hn + skip*c) * silu(ur), ur recomputed from xn ----
    {
        const int jq = lane % MM, gq = lane / MM;
        const bool act = lane < 56;
        float wr[DD];
        float brr=0.f, skr=0.f, gg_=0.f, gb_=0.f;
        if (act){
            #pragma unroll
            for (int d=0;d<DD;d++) wr[d]=Wup_r[d*MM+jq];
            brr=bup_r[jq]; skr=skip[jq]; gg_=gn_g[jq]; gb_=gn_b[jq];
        }
        #pragma unroll
        for (int tt=0;tt<15;tt++){
            int t=gq*15+tt;
            if (act){
                const float2* xr = (const float2*)&sm[XN+t*DD];
                float urv = brr;
                #pragma unroll
                for (int u=0;u<7;u++){ float2 f=xr[u]; urv += f.x*wr[2*u]+f.y*wr[2*u+1]; }
                float hv = sm[UL+t*MM+jq];
                float mu = sm[ST+t*2], rs = sm[ST+t*2+1];
                float hn = (hv-mu)*rs*gg_ + gb_;
                float h2 = hn + skr*sm[CB+t*MM+jq];
                sm[KP + t*MM + jq] = h2 * fsilu(urv);   // e overlays k (stride 28)
            }
        }
    }
    __syncthreads();

    // ---- Phase H: y_m = e @ Wdown + bdown + x (x re-read from global) ----
    {
        const int dq = lane % DD;
        const int g4 = lane / DD;   // 0..3 for lane<56
        const bool act = lane < 56;
        float wd[MM]; float bdr=0.f;
        if (act){
            #pragma unroll
            for (int i2=0;i2<MM;i2++) wd[i2]=Wdown[i2*DD+dq];
            bdr=bdown[dq];
        }
        #pragma unroll
        for (int tt=0;tt<8;tt++){
            int t=g4*8+tt;
            if (act && t<SS){
                const float4* er=(const float4*)&sm[KP+t*MM];
                float a = bdr + xp[t*DD+dq];
                #pragma unroll
                for (int u=0;u<7;u++){ float4 f=er[u]; a += f.x*wd[4*u]+f.y*wd[4*u+1]+f.z*wd[4*u+2]+f.w*wd[4*u+3]; }
                sm[XN+t*DD+dq]=a;   // y_m overlays xn
            }
        }
    }
    __syncthreads();

    // ---- Phase I: sLSTM LN stats over y_m ----
    if (lane<SS){
        const float2* yr=(const float2*)&sm[XN+lane*DD];
        float s=0.f,s2=0.f;
        #pragma unroll
        for (int u=0;u<7;u++){ float2 f=yr[u]; s+=f.x+f.y; s2+=f.x*f.x+f.y*f.y; }
        float mu=s*(1.f/DD), var=s2*(1.f/DD)-mu*mu;
        sm[ST+lane*2]=mu; sm[ST+lane*2+1]=rsqrtf(var+1e-5f);
    }
    __syncthreads();

    // ---- Phase J: gx = yn @ sW + sb (overlays v) ----
    for (int idx=lane; idx<SS*8; idx+=64){
        int t=idx>>3, gg=idx&7;
        float a=sb[gg];
        float mu=sm[ST+t*2], rs=sm[ST+t*2+1];
        #pragma unroll
        for (int d=0;d<DD;d++){
            float yn=(sm[XN+t*DD+d]-mu)*rs*s_ln_g[d]+s_ln_b[d];
            a += yn*sW[d*8+gg];
        }
        sm[VB+idx]=a;
    }
    __syncthreads();

    // ---- Phase K: sLSTM scan (redundant on all lanes; lane0 writes hs) ----
    {
        float R0[8], R1[8];
        #pragma unroll
        for (int g=0; g<8; g++){ R0[g]=sR[g]; R1[g]=sR[8+g]; }
        float h0=0.f,h1=0.f,c0=0.f,c1=0.f,n0=0.f,n1=0.f,m0=0.f,m1=0.f;
        for (int t=0; t<SS; t++){
            float g[8];
            #pragma unroll
            for (int gg=0; gg<8; gg++) g[gg] = sm[VB+t*8+gg] + h0*R0[gg] + h1*R1[gg];
            float z0=ftanh_(g[0]), z1=ftanh_(g[1]);
            float i0=g[2], i1=g[3], f0=g[4], f1=g[5];
            float o0=fsigm(g[6]), o1=fsigm(g[7]);
            float mn0=fmaxf(f0+m0, i0), mn1=fmaxf(f1+m1, i1);
            float ie0=__expf(i0-mn0), ie1=__expf(i1-mn1);
            float fe0=__expf(f0+m0-mn0), fe1=__expf(f1+m1-mn1);
            c0 = fe0*c0 + ie0*z0;  c1 = fe1*c1 + ie1*z1;
            n0 = fe0*n0 + ie0;     n1 = fe1*n1 + ie1;
            h0 = o0*c0/n0;         h1 = o1*c1/n1;
            m0 = mn0; m1 = mn1;
            if (lane == 0){ sm[VB+240+t*2] = h0; sm[VB+240+t*2+1] = h1; }
        }
    }
    __syncthreads();

    // ---- Phase L: sLSTM epilogue + tanh -> CB ----
    for (int idx = lane; idx < SS*DD; idx += 64){
        int t = idx / DD, d = idx - t*DD;
        float a0 = sm[VB+240+t*2], a1 = sm[VB+240+t*2+1];
        float mu = 0.5f*(a0+a1);
        float d0 = a0-mu, d1 = a1-mu;
        float var = 0.5f*(d0*d0 + d1*d1);
        float rsg = rsqrtf(var + 1e-5f);
        float hn0 = d0*rsg*s_gn_g[0] + s_gn_b[0];
        float hn1 = d1*rsg*s_gn_g[1] + s_gn_b[1];
        float acc = sbdown[d] + sm[XN+idx];
        #pragma unroll
        for (int u3=0; u3<3; u3++){
            float p1 = hn0*sWup1[u3] + hn1*sWup1[3+u3] + sbup1[u3];
            float p2 = hn0*sWup2[u3] + hn1*sWup2[3+u3] + sbup2[u3];
            acc += fgelu(p1)*p2*sWdown[u3*DD+d];
        }
        sm[CB+idx] = ftanh_(acc);
    }
    __syncthreads();

    // ---- Phase M: head fc1(420->32,relu) + fc3(32->1) ----
    {
        int j = lane & 31, half = lane >> 5;
        const float2* tyr = (const float2*)&sm[CB + half*210];
        float a = 0.f;
        const float* w1 = fc1w + (half*210)*32 + j;
        for (int d2=0; d2<105; d2++){
            float2 tv = tyr[d2];
            a += tv.x*w1[(2*d2)*32] + tv.y*w1[(2*d2+1)*32];
        }
        a += __shfl_xor(a, 32, 64);
        a += fc1b[j];
        float r = fmaxf(a, 0.f);
        float p = r * fc3w[j];
        #pragma unroll
        for (int off=16; off>=1; off>>=1) p += __shfl_xor(p, off, 64);
        if (lane == 0) out[b] = p + fc3b[0];
    }
}

extern "C" void kernel_launch(void* const* d_in, const int* in_sizes, int n_in,
                              void* d_out, int out_size, void* d_ws, size_t ws_size,
                              hipStream_t stream) {
    const float* x      = (const float*)d_in[0];
    const float* ln_g   = (const float*)d_in[1];
    const float* ln_b   = (const float*)d_in[2];
    const float* Wup_l  = (const float*)d_in[3];
    const float* bup_l  = (const float*)d_in[4];
    const float* Wup_r  = (const float*)d_in[5];
    const float* bup_r  = (const float*)d_in[6];
    const float* conv_w = (const float*)d_in[7];
    const float* conv_b = (const float*)d_in[8];
    const float* Wq     = (const float*)d_in[9];
    const float* bq     = (const float*)d_in[10];
    const float* Wk     = (const float*)d_in[11];
    const float* bk     = (const float*)d_in[12];
    const float* Wv     = (const float*)d_in[13];
    const float* bv     = (const float*)d_in[14];
    const float* Wif    = (const float*)d_in[15];
    const float* bif    = (const float*)d_in[16];
    const float* gn_g   = (const float*)d_in[17];
    const float* gn_b   = (const float*)d_in[18];
    const float* skip   = (const float*)d_in[19];
    const float* Wdown  = (const float*)d_in[20];
    const float* bdown  = (const float*)d_in[21];
    const float* s_ln_g = (const float*)d_in[22];
    const float* s_ln_b = (const float*)d_in[23];
    const float* sW     = (const float*)d_in[24];
    const float* sR     = (const float*)d_in[25];
    const float* sb     = (const float*)d_in[26];
    const float* s_gn_g = (const float*)d_in[27];
    const float* s_gn_b = (const float*)d_in[28];
    const float* sWup1  = (const float*)d_in[29];
    const float* sbup1  = (const float*)d_in[30];
    const float* sWup2  = (const float*)d_in[31];
    const float* sbup2  = (const float*)d_in[32];
    const float* sWdown = (const float*)d_in[33];
    const float* sbdown = (const float*)d_in[34];
    const float* fc1w   = (const float*)d_in[35];
    const float* fc1b   = (const float*)d_in[36];
    const float* fc3w   = (const float*)d_in[37];
    const float* fc3b   = (const float*)d_in[38];
    float* out = (float*)d_out;

    hipLaunchKernelGGL(net_kernel, dim3(8192), dim3(64), 0, stream,
        x, ln_g, ln_b, Wup_l, bup_l, Wup_r, bup_r, conv_w, conv_b,
        Wq, bq, Wk, bk, Wv, bv, Wif, bif, gn_g, gn_b, skip, Wdown, bdown,
        s_ln_g, s_ln_b, sW, sR, sb, s_gn_g, s_gn_b,
        sWup1, sbup1, sWup2, sbup2, sWdown, sbdown,
        fc1w, fc1b, fc3w, fc3b, out);
}

// Round 3
// 202.801 us; speedup vs baseline: 1.8116x; 1.0905x over previous
//
#include <hip/hip_runtime.h>

#define SS 30
#define DD 14
#define MM 28

// LDS float offsets
#define XN 0       // 420: xn -> later y_m
#define UL 420     // 840 stride28: ul -> later e
#define CB 1260    // 840 stride28: c -> later tanh(y_s) (first 420)
#define QA 2100    // 960 stride32: q (pad cols zeroed) -> scores A (in-place)
#define KH 3060    // 990: k stride33 -> h stride32 (first 960)
#define VV 4050    // 870 stride29: v + ones col -> later gx(240)+hs@240(60)
#define GIF 4920   // 60
#define EA 4980    // 30: a_s = i_s - F_s
#define ECM 5010   // 30: cm_t = max(0, cummax a)
#define ST 4920    // 90 (overlays GIF/EA after scores): per-t stats
#define SMTOT 5040 // 20,160 B -> 8 blocks/CU

__device__ __forceinline__ float fsigm(float v){ return 1.f/(1.f+__expf(-v)); }
__device__ __forceinline__ float fsilu(float v){ return v/(1.f+__expf(-v)); }
__device__ __forceinline__ float ftanh_(float v){
    float c = fminf(fmaxf(v, -15.f), 15.f);
    float e = __expf(2.f*c);
    return (e-1.f)/(e+1.f);
}
__device__ __forceinline__ float fgelu(float v){
    float t = ftanh_(0.7978845608028654f*(v + 0.044715f*v*v*v));
    return 0.5f*v*(1.f+t);
}

extern "C" __global__ void __launch_bounds__(64)
net_kernel(const float* __restrict__ xg,
           const float* __restrict__ ln_g, const float* __restrict__ ln_b,
           const float* __restrict__ Wup_l, const float* __restrict__ bup_l,
           const float* __restrict__ Wup_r, const float* __restrict__ bup_r,
           const float* __restrict__ conv_w, const float* __restrict__ conv_b,
           const float* __restrict__ Wq, const float* __restrict__ bq,
           const float* __restrict__ Wk, const float* __restrict__ bk,
           const float* __restrict__ Wv, const float* __restrict__ bv,
           const float* __restrict__ Wif, const float* __restrict__ bif,
           const float* __restrict__ gn_g, const float* __restrict__ gn_b,
           const float* __restrict__ skip,
           const float* __restrict__ Wdown, const float* __restrict__ bdown,
           const float* __restrict__ s_ln_g, const float* __restrict__ s_ln_b,
           const float* __restrict__ sW, const float* __restrict__ sR, const float* __restrict__ sb,
           const float* __restrict__ s_gn_g, const float* __restrict__ s_gn_b,
           const float* __restrict__ sWup1, const float* __restrict__ sbup1,
           const float* __restrict__ sWup2, const float* __restrict__ sbup2,
           const float* __restrict__ sWdown, const float* __restrict__ sbdown,
           const float* __restrict__ fc1w, const float* __restrict__ fc1b,
           const float* __restrict__ fc3w, const float* __restrict__ fc3b,
           float* __restrict__ out)
{
    __shared__ __align__(16) float sm[SMTOT];
    const int lane = threadIdx.x;
    const int b = blockIdx.x;
    const float* xp = xg + (size_t)b * (SS*DD);

    // ---- Phase A: LN1 -> xn (lane = t) ----
    if (lane < SS){
        float xv[DD];
        const float2* xr = (const float2*)(xp + lane*DD);
        float s=0.f, s2=0.f;
        #pragma unroll
        for (int u=0;u<7;u++){ float2 f=xr[u]; xv[2*u]=f.x; xv[2*u+1]=f.y; s+=f.x+f.y; s2+=f.x*f.x+f.y*f.y; }
        float mu=s*(1.f/DD), var=s2*(1.f/DD)-mu*mu, rsg=rsqrtf(var+1e-5f);
        #pragma unroll
        for (int d=0; d<DD; d++) sm[XN+lane*DD+d] = (xv[d]-mu)*rsg*ln_g[d]+ln_b[d];
    }
    __syncthreads();

    // ---- Phase B: ul = xn @ Wup_l + bup_l ----
    {
        const int jq = lane % MM, gq = lane / MM;
        const bool act = lane < 56;
        float wl[DD]; float blr=0.f;
        if (act){
            #pragma unroll
            for (int d=0; d<DD; d++) wl[d] = Wup_l[d*MM+jq];
            blr = bup_l[jq];
        }
        #pragma unroll
        for (int tt=0; tt<15; tt++){
            int t = gq*15+tt;
            if (act){
                const float2* xr = (const float2*)&sm[XN + t*DD];
                float a = blr;
                #pragma unroll
                for (int u=0;u<7;u++){ float2 f = xr[u]; a += f.x*wl[2*u] + f.y*wl[2*u+1]; }
                sm[UL + t*MM + jq] = a;
            }
        }
    }
    __syncthreads();

    // ---- Phase C: causal conv + silu -> c ----
    for (int idx=lane; idx<SS*MM; idx+=64){
        int t = idx/MM, j = idx-t*MM;
        float a = conv_b[j];
        #pragma unroll
        for (int k=0;k<4;k++){
            int tt=t-3+k;
            if (tt>=0) a += sm[UL+tt*MM+j]*conv_w[k*MM+j];
        }
        sm[CB+idx] = fsilu(a);
    }
    __syncthreads();

    // ---- Phase D: q (stride32), k (stride33), v (stride29) GEMMs + gif + pads ----
    {
        const int jq = lane % MM, gq = lane / MM;
        const bool act = lane < 56;
        float wq[MM], wk[MM], wv[MM];
        float bqr=0.f, bkr=0.f, bvr=0.f;
        if (act){
            #pragma unroll
            for (int h=0;h<MM;h++){ wq[h]=Wq[h*MM+jq]; wk[h]=Wk[h*MM+jq]; wv[h]=Wv[h*MM+jq]; }
            bqr=bq[jq]; bkr=bk[jq]; bvr=bv[jq];
        }
        const float rs28 = 0.18898223650461363f; // 1/sqrt(28)
        #pragma unroll
        for (int tt=0; tt<15; tt++){
            int t = gq*15+tt;
            if (act){
                const float4* cr = (const float4*)&sm[CB + t*MM];
                const float4* ur = (const float4*)&sm[UL + t*MM];
                float aq=bqr, ak=bkr, av=bvr;
                #pragma unroll
                for (int h4=0;h4<7;h4++){
                    float4 cf=cr[h4], uf=ur[h4];
                    aq += cf.x*wq[4*h4] + cf.y*wq[4*h4+1] + cf.z*wq[4*h4+2] + cf.w*wq[4*h4+3];
                    ak += cf.x*wk[4*h4] + cf.y*wk[4*h4+1] + cf.z*wk[4*h4+2] + cf.w*wk[4*h4+3];
                    av += uf.x*wv[4*h4] + uf.y*wv[4*h4+1] + uf.z*wv[4*h4+2] + uf.w*wv[4*h4+3];
                }
                sm[QA + t*32 + jq] = aq;
                sm[KH + t*33 + jq] = ak*rs28;
                sm[VV + t*29 + jq] = av;
            }
        }
    }
    // gif = c @ Wif + bif
    for (int idx=lane; idx<SS*2; idx+=64){
        int t=idx>>1, gg=idx&1;
        float a = bif[gg];
        const float4* cr = (const float4*)&sm[CB+t*MM];
        #pragma unroll
        for (int h4=0;h4<7;h4++){ float4 cf=cr[h4];
            a += cf.x*Wif[(4*h4)*2+gg] + cf.y*Wif[(4*h4+1)*2+gg]
               + cf.z*Wif[(4*h4+2)*2+gg] + cf.w*Wif[(4*h4+3)*2+gg]; }
        sm[GIF+idx]=a;
    }
    // zero q pad cols (28..31) and set v ones col (28)
    for (int idx=lane; idx<150; idx+=64){
        int row = idx/5, w = idx-row*5;
        if (w<4) sm[QA+row*32+28+w]=0.f; else sm[VV+row*29+28]=1.f;
    }
    __syncthreads();

    // ---- Phase D3: gate pre-scan: F=cumsum(f), a=i-F, cm=max(0,cummax(a)) ----
    if (lane < SS){
        float i_ = sm[GIF+2*lane], f_ = sm[GIF+2*lane+1];
        float F = f_, v;
        v = __shfl_up(F,1,64);  if (lane>=1)  F += v;
        v = __shfl_up(F,2,64);  if (lane>=2)  F += v;
        v = __shfl_up(F,4,64);  if (lane>=4)  F += v;
        v = __shfl_up(F,8,64);  if (lane>=8)  F += v;
        v = __shfl_up(F,16,64); if (lane>=16) F += v;
        float a = i_ - F;
        float cm = a;
        v = __shfl_up(cm,1,64);  if (lane>=1)  cm = fmaxf(cm,v);
        v = __shfl_up(cm,2,64);  if (lane>=2)  cm = fmaxf(cm,v);
        v = __shfl_up(cm,4,64);  if (lane>=4)  cm = fmaxf(cm,v);
        v = __shfl_up(cm,8,64);  if (lane>=8)  cm = fmaxf(cm,v);
        v = __shfl_up(cm,16,64); if (lane>=16) cm = fmaxf(cm,v);
        cm = fmaxf(cm, 0.f);   // m0 = 0 branch
        sm[EA+lane] = a;
        sm[ECM+lane] = cm;
    }
    __syncthreads();

    // ---- Phase E: scores A[t][s] = (q_t . k_s) * exp(a_s - cm_t), s<=t (in-place over q) ----
    {
        const int s = lane & 31, gq = lane >> 5;
        const bool act = s < SS;
        float kreg[MM]; float eas = 0.f;
        if (act){
            #pragma unroll
            for (int h=0;h<MM;h++) kreg[h] = sm[KH + s*33 + h];
            eas = sm[EA + s];
        }
        #pragma unroll
        for (int tt=0; tt<15; tt++){
            int t = gq*15 + tt;
            if (act){
                const float4* qr = (const float4*)&sm[QA + t*32];
                float d = 0.f;
                #pragma unroll
                for (int h4=0;h4<7;h4++){
                    float4 qf = qr[h4];
                    d += qf.x*kreg[4*h4] + qf.y*kreg[4*h4+1] + qf.z*kreg[4*h4+2] + qf.w*kreg[4*h4+3];
                }
                float w = (s <= t) ? __expf(eas - sm[ECM+t]) : 0.f;
                sm[QA + t*32 + s] = d * w;   // same-wave: q row t already read this iter
            }
        }
    }
    __syncthreads();

    // ---- Phase F: h_t[j] = sum_s A[t][s] * v_s[j]  (j==28 -> rowsum via ones col) ----
    {
        const int j = lane & 31, gq = lane >> 5;
        const bool act = j < 29;
        float vcol[32];
        if (act){
            #pragma unroll
            for (int s=0;s<SS;s++) vcol[s] = sm[VV + s*29 + j];
        }
        vcol[30]=0.f; vcol[31]=0.f;
        #pragma unroll
        for (int tt=0; tt<15; tt++){
            int t = gq*15 + tt;
            if (act){
                const float4* ar = (const float4*)&sm[QA + t*32];
                float acc = 0.f;
                #pragma unroll
                for (int s4=0;s4<8;s4++){
                    float4 af = ar[s4];
                    acc += af.x*vcol[4*s4] + af.y*vcol[4*s4+1] + af.z*vcol[4*s4+2] + af.w*vcol[4*s4+3];
                }
                sm[KH + t*32 + j] = acc;   // h overlays k
            }
        }
    }
    __syncthreads();

    // ---- Phase G0: per-t stats: inv=1/max(|rowsum|,1); GN stats of h*inv ----
    if (lane < SS){
        const float4* hr = (const float4*)&sm[KH+lane*32];
        float s=0.f,s2=0.f;
        #pragma unroll
        for (int u=0;u<7;u++){ float4 f=hr[u]; s+=f.x+f.y+f.z+f.w; s2+=f.x*f.x+f.y*f.y+f.z*f.z+f.w*f.w; }
        float inv = 1.f/fmaxf(fabsf(sm[KH+lane*32+28]), 1.f);
        float mu=s*(1.f/MM), var=s2*(1.f/MM)-mu*mu;
        sm[ST+lane*3]   = mu*inv;
        sm[ST+lane*3+1] = rsqrtf(var*inv*inv + 1e-5f);
        sm[ST+lane*3+2] = inv;
    }
    __syncthreads();

    // ---- Phase G: e = (hn + skip*c) * silu(ur), ur recomputed from xn ----
    {
        const int jq = lane % MM, gq = lane / MM;
        const bool act = lane < 56;
        float wr[DD];
        float brr=0.f, skr=0.f, gg_=0.f, gb_=0.f;
        if (act){
            #pragma unroll
            for (int d=0;d<DD;d++) wr[d]=Wup_r[d*MM+jq];
            brr=bup_r[jq]; skr=skip[jq]; gg_=gn_g[jq]; gb_=gn_b[jq];
        }
        #pragma unroll
        for (int tt=0;tt<15;tt++){
            int t=gq*15+tt;
            if (act){
                const float2* xr = (const float2*)&sm[XN+t*DD];
                float urv = brr;
                #pragma unroll
                for (int u=0;u<7;u++){ float2 f=xr[u]; urv += f.x*wr[2*u]+f.y*wr[2*u+1]; }
                float inv = sm[ST+t*3+2];
                float hv = sm[KH+t*32+jq]*inv;
                float hn = (hv-sm[ST+t*3])*sm[ST+t*3+1]*gg_ + gb_;
                float h2 = hn + skr*sm[CB+t*MM+jq];
                sm[UL + t*MM + jq] = h2 * fsilu(urv);   // e overlays ul
            }
        }
    }
    __syncthreads();

    // ---- Phase H: y_m = e @ Wdown + bdown + x ----
    {
        const int dq = lane % DD;
        const int g4 = lane / DD;
        const bool act = lane < 56;
        float wd[MM]; float bdr=0.f;
        if (act){
            #pragma unroll
            for (int i2=0;i2<MM;i2++) wd[i2]=Wdown[i2*DD+dq];
            bdr=bdown[dq];
        }
        #pragma unroll
        for (int tt=0;tt<8;tt++){
            int t=g4*8+tt;
            if (act && t<SS){
                const float4* er=(const float4*)&sm[UL+t*MM];
                float a = bdr + xp[t*DD+dq];
                #pragma unroll
                for (int u=0;u<7;u++){ float4 f=er[u]; a += f.x*wd[4*u]+f.y*wd[4*u+1]+f.z*wd[4*u+2]+f.w*wd[4*u+3]; }
                sm[XN+t*DD+dq]=a;   // y_m overlays xn
            }
        }
    }
    __syncthreads();

    // ---- Phase I: sLSTM LN stats over y_m ----
    if (lane<SS){
        const float2* yr=(const float2*)&sm[XN+lane*DD];
        float s=0.f,s2=0.f;
        #pragma unroll
        for (int u=0;u<7;u++){ float2 f=yr[u]; s+=f.x+f.y; s2+=f.x*f.x+f.y*f.y; }
        float mu=s*(1.f/DD), var=s2*(1.f/DD)-mu*mu;
        sm[ST+lane*2]=mu; sm[ST+lane*2+1]=rsqrtf(var+1e-5f);
    }
    __syncthreads();

    // ---- Phase J: gx = yn @ sW + sb (overlays v) ----
    for (int idx=lane; idx<SS*8; idx+=64){
        int t=idx>>3, gg=idx&7;
        float a=sb[gg];
        float mu=sm[ST+t*2], rs=sm[ST+t*2+1];
        #pragma unroll
        for (int d=0;d<DD;d++){
            float yn=(sm[XN+t*DD+d]-mu)*rs*s_ln_g[d]+s_ln_b[d];
            a += yn*sW[d*8+gg];
        }
        sm[VV+idx]=a;
    }
    __syncthreads();

    // ---- Phase K: sLSTM scan (redundant on all lanes; lane0 writes hs) ----
    {
        float R0[8], R1[8];
        #pragma unroll
        for (int g=0; g<8; g++){ R0[g]=sR[g]; R1[g]=sR[8+g]; }
        float h0=0.f,h1=0.f,c0=0.f,c1=0.f,n0=0.f,n1=0.f,m0=0.f,m1=0.f;
        for (int t=0; t<SS; t++){
            float g[8];
            #pragma unroll
            for (int gg=0; gg<8; gg++) g[gg] = sm[VV+t*8+gg] + h0*R0[gg] + h1*R1[gg];
            float z0=ftanh_(g[0]), z1=ftanh_(g[1]);
            float i0=g[2], i1=g[3], f0=g[4], f1=g[5];
            float o0=fsigm(g[6]), o1=fsigm(g[7]);
            float mn0=fmaxf(f0+m0, i0), mn1=fmaxf(f1+m1, i1);
            float ie0=__expf(i0-mn0), ie1=__expf(i1-mn1);
            float fe0=__expf(f0+m0-mn0), fe1=__expf(f1+m1-mn1);
            c0 = fe0*c0 + ie0*z0;  c1 = fe1*c1 + ie1*z1;
            n0 = fe0*n0 + ie0;     n1 = fe1*n1 + ie1;
            h0 = o0*c0/n0;         h1 = o1*c1/n1;
            m0 = mn0; m1 = mn1;
            if (lane == 0){ sm[VV+240+t*2] = h0; sm[VV+240+t*2+1] = h1; }
        }
    }
    __syncthreads();

    // ---- Phase L: sLSTM epilogue + tanh -> CB ----
    for (int idx = lane; idx < SS*DD; idx += 64){
        int t = idx / DD, d = idx - t*DD;
        float a0 = sm[VV+240+t*2], a1 = sm[VV+240+t*2+1];
        float mu = 0.5f*(a0+a1);
        float d0 = a0-mu, d1 = a1-mu;
        float var = 0.5f*(d0*d0 + d1*d1);
        float rsg = rsqrtf(var + 1e-5f);
        float hn0 = d0*rsg*s_gn_g[0] + s_gn_b[0];
        float hn1 = d1*rsg*s_gn_g[1] + s_gn_b[1];
        float acc = sbdown[d] + sm[XN+idx];
        #pragma unroll
        for (int u3=0; u3<3; u3++){
            float p1 = hn0*sWup1[u3] + hn1*sWup1[3+u3] + sbup1[u3];
            float p2 = hn0*sWup2[u3] + hn1*sWup2[3+u3] + sbup2[u3];
            acc += fgelu(p1)*p2*sWdown[u3*DD+d];
        }
        sm[CB+idx] = ftanh_(acc);
    }
    __syncthreads();

    // ---- Phase M: head fc1(420->32,relu) + fc3(32->1) ----
    {
        int j = lane & 31, half = lane >> 5;
        const float2* tyr = (const float2*)&sm[CB + half*210];
        float a = 0.f;
        const float* w1 = fc1w + (half*210)*32 + j;
        for (int d2=0; d2<105; d2++){
            float2 tv = tyr[d2];
            a += tv.x*w1[(2*d2)*32] + tv.y*w1[(2*d2+1)*32];
        }
        a += __shfl_xor(a, 32, 64);
        a += fc1b[j];
        float r = fmaxf(a, 0.f);
        float p = r * fc3w[j];
        #pragma unroll
        for (int off=16; off>=1; off>>=1) p += __shfl_xor(p, off, 64);
        if (lane == 0) out[b] = p + fc3b[0];
    }
}

extern "C" void kernel_launch(void* const* d_in, const int* in_sizes, int n_in,
                              void* d_out, int out_size, void* d_ws, size_t ws_size,
                              hipStream_t stream) {
    const float* x      = (const float*)d_in[0];
    const float* ln_g   = (const float*)d_in[1];
    const float* ln_b   = (const float*)d_in[2];
    const float* Wup_l  = (const float*)d_in[3];
    const float* bup_l  = (const float*)d_in[4];
    const float* Wup_r  = (const float*)d_in[5];
    const float* bup_r  = (const float*)d_in[6];
    const float* conv_w = (const float*)d_in[7];
    const float* conv_b = (const float*)d_in[8];
    const float* Wq     = (const float*)d_in[9];
    const float* bq     = (const float*)d_in[10];
    const float* Wk     = (const float*)d_in[11];
    const float* bk     = (const float*)d_in[12];
    const float* Wv     = (const float*)d_in[13];
    const float* bv     = (const float*)d_in[14];
    const float* Wif    = (const float*)d_in[15];
    const float* bif    = (const float*)d_in[16];
    const float* gn_g   = (const float*)d_in[17];
    const float* gn_b   = (const float*)d_in[18];
    const float* skip   = (const float*)d_in[19];
    const float* Wdown  = (const float*)d_in[20];
    const float* bdown  = (const float*)d_in[21];
    const float* s_ln_g = (const float*)d_in[22];
    const float* s_ln_b = (const float*)d_in[23];
    const float* sW     = (const float*)d_in[24];
    const float* sR     = (const float*)d_in[25];
    const float* sb     = (const float*)d_in[26];
    const float* s_gn_g = (const float*)d_in[27];
    const float* s_gn_b = (const float*)d_in[28];
    const float* sWup1  = (const float*)d_in[29];
    const float* sbup1  = (const float*)d_in[30];
    const float* sWup2  = (const float*)d_in[31];
    const float* sbup2  = (const float*)d_in[32];
    const float* sWdown = (const float*)d_in[33];
    const float* sbdown = (const float*)d_in[34];
    const float* fc1w   = (const float*)d_in[35];
    const float* fc1b   = (const float*)d_in[36];
    const float* fc3w   = (const float*)d_in[37];
    const float* fc3b   = (const float*)d_in[38];
    float* out = (float*)d_out;

    hipLaunchKernelGGL(net_kernel, dim3(8192), dim3(64), 0, stream,
        x, ln_g, ln_b, Wup_l, bup_l, Wup_r, bup_r, conv_w, conv_b,
        Wq, bq, Wk, bk, Wv, bv, Wif, bif, gn_g, gn_b, skip, Wdown, bdown,
        s_ln_g, s_ln_b, sW, sR, sb, s_gn_g, s_gn_b,
        sWup1, sbup1, sWup2, sbup2, sWdown, sbdown,
        fc1w, fc1b, fc3w, fc3b, out);
}

// Round 4
// 172.522 us; speedup vs baseline: 2.1295x; 1.1755x over previous
//
#include <hip/hip_runtime.h>

#define SS 30
#define DD 14
#define MM 28

// LDS float offsets
#define XN 0       // 420: xn -> later y_m
#define UL 420     // 840 stride28: ul -> later e
#define CB 1260    // 840 stride28: c -> later tanh(y_s) (first 420)
#define QA 2100    // 960 stride32: q -> scores A (in-place) -> L0 u-values (90)
#define KH 3060    // 990: k stride33 -> h stride29 (first 870)
#define VV 4050    // 870 stride29: v + ones col -> later gx(240)+hs@240(60)
#define GIF 4920   // 60: gif -> ST stats (G0 stride3: 90 @4920; I stride2: 60 @4920)
#define EA 4980    // 30: exp(a_s)
#define ECM 5010   // 30: exp(-cm_t)
#define ST 4920
#define SMTOT 5040 // 20,160 B -> 8 blocks/CU

__device__ __forceinline__ float fsigm(float v){ return 1.f/(1.f+__expf(-v)); }
__device__ __forceinline__ float fsilu(float v){ return v/(1.f+__expf(-v)); }
__device__ __forceinline__ float ftanh_(float v){
    float c = fminf(fmaxf(v, -15.f), 15.f);
    float e = __expf(2.f*c);
    return (e-1.f)/(e+1.f);
}
__device__ __forceinline__ float fgelu(float v){
    float t = ftanh_(0.7978845608028654f*(v + 0.044715f*v*v*v));
    return 0.5f*v*(1.f+t);
}

extern "C" __global__ void __launch_bounds__(64)
net_kernel(const float* __restrict__ xg,
           const float* __restrict__ ln_g, const float* __restrict__ ln_b,
           const float* __restrict__ Wup_l, const float* __restrict__ bup_l,
           const float* __restrict__ Wup_r, const float* __restrict__ bup_r,
           const float* __restrict__ conv_w, const float* __restrict__ conv_b,
           const float* __restrict__ Wq, const float* __restrict__ bq,
           const float* __restrict__ Wk, const float* __restrict__ bk,
           const float* __restrict__ Wv, const float* __restrict__ bv,
           const float* __restrict__ Wif, const float* __restrict__ bif,
           const float* __restrict__ gn_g, const float* __restrict__ gn_b,
           const float* __restrict__ skip,
           const float* __restrict__ Wdown, const float* __restrict__ bdown,
           const float* __restrict__ s_ln_g, const float* __restrict__ s_ln_b,
           const float* __restrict__ sW, const float* __restrict__ sR, const float* __restrict__ sb,
           const float* __restrict__ s_gn_g, const float* __restrict__ s_gn_b,
           const float* __restrict__ sWup1, const float* __restrict__ sbup1,
           const float* __restrict__ sWup2, const float* __restrict__ sbup2,
           const float* __restrict__ sWdown, const float* __restrict__ sbdown,
           const float* __restrict__ fc1w, const float* __restrict__ fc1b,
           const float* __restrict__ fc3w, const float* __restrict__ fc3b,
           float* __restrict__ out)
{
    __shared__ __align__(16) float sm[SMTOT];
    const int lane = threadIdx.x;
    const int b = blockIdx.x;
    const float* xp = xg + (size_t)b * (SS*DD);

    const int jq = lane % MM;          // hoisted once
    const int gq = lane / MM;
    const bool act = lane < 56;
    const int jqi = act ? jq : 0;

    // ---- Preload weights for phases B/C/D (loads overlap A-C compute) ----
    float wl[DD], cw[4], wq[MM], wk[MM], wv[MM];
    float blr, cbr, bqr, bkr, bvr;
    {
        #pragma unroll
        for (int d=0; d<DD; d++) wl[d] = Wup_l[d*MM+jqi];
        #pragma unroll
        for (int k=0; k<4; k++) cw[k] = conv_w[k*MM+jqi];
        #pragma unroll
        for (int h=0; h<MM; h++){ wq[h]=Wq[h*MM+jqi]; wk[h]=Wk[h*MM+jqi]; wv[h]=Wv[h*MM+jqi]; }
        blr = bup_l[jqi]; cbr = conv_b[jqi];
        bqr = bq[jqi]; bkr = bk[jqi]; bvr = bv[jqi];
    }

    // ---- Phase A: LN1 -> xn (lane = t) ----
    if (lane < SS){
        float xv[DD];
        const float2* xr = (const float2*)(xp + lane*DD);
        float s=0.f, s2=0.f;
        #pragma unroll
        for (int u=0;u<7;u++){ float2 f=xr[u]; xv[2*u]=f.x; xv[2*u+1]=f.y; s+=f.x+f.y; s2+=f.x*f.x+f.y*f.y; }
        float mu=s*(1.f/DD), var=s2*(1.f/DD)-mu*mu, rsg=rsqrtf(var+1e-5f);
        #pragma unroll
        for (int d=0; d<DD; d++) sm[XN+lane*DD+d] = (xv[d]-mu)*rsg*ln_g[d]+ln_b[d];
    }
    __syncthreads();

    // ---- Phase B: ul = xn @ Wup_l + bup_l ----
    #pragma unroll
    for (int tt=0; tt<15; tt++){
        int t = gq*15+tt;
        if (act){
            const float2* xr = (const float2*)&sm[XN + t*DD];
            float a = blr;
            #pragma unroll
            for (int u=0;u<7;u++){ float2 f = xr[u]; a += f.x*wl[2*u] + f.y*wl[2*u+1]; }
            sm[UL + t*MM + jq] = a;
        }
    }
    __syncthreads();

    // ---- Phase C: causal conv + silu -> c  ((j,half) mapping, no div) ----
    #pragma unroll
    for (int tt=0; tt<15; tt++){
        int t = gq*15+tt;
        if (act){
            float a = cbr;
            #pragma unroll
            for (int k=0;k<4;k++){
                int ts = t-3+k;
                if (ts>=0) a += sm[UL+ts*MM+jq]*cw[k];
            }
            sm[CB + t*MM + jq] = fsilu(a);
        }
    }
    __syncthreads();

    // ---- Phase D: q (stride32), k (stride33), v (stride29) GEMMs ----
    {
        const float rs28 = 0.18898223650461363f; // 1/sqrt(28)
        #pragma unroll
        for (int tt=0; tt<15; tt++){
            int t = gq*15+tt;
            if (act){
                const float4* cr = (const float4*)&sm[CB + t*MM];
                const float4* ur = (const float4*)&sm[UL + t*MM];
                float aq=bqr, ak=bkr, av=bvr;
                #pragma unroll
                for (int h4=0;h4<7;h4++){
                    float4 cf=cr[h4], uf=ur[h4];
                    aq += cf.x*wq[4*h4] + cf.y*wq[4*h4+1] + cf.z*wq[4*h4+2] + cf.w*wq[4*h4+3];
                    ak += cf.x*wk[4*h4] + cf.y*wk[4*h4+1] + cf.z*wk[4*h4+2] + cf.w*wk[4*h4+3];
                    av += uf.x*wv[4*h4] + uf.y*wv[4*h4+1] + uf.z*wv[4*h4+2] + uf.w*wv[4*h4+3];
                }
                sm[QA + t*32 + jq] = aq;
                sm[KH + t*33 + jq] = ak*rs28;
                sm[VV + t*29 + jq] = av;
            }
        }
    }
    // gif = c @ Wif + bif  (lane<60, 1 iter)
    if (lane < SS*2){
        int t=lane>>1, gg=lane&1;
        float a = bif[gg];
        const float4* cr = (const float4*)&sm[CB+t*MM];
        #pragma unroll
        for (int h4=0;h4<7;h4++){ float4 cf=cr[h4];
            a += cf.x*Wif[(4*h4)*2+gg] + cf.y*Wif[(4*h4+1)*2+gg]
               + cf.z*Wif[(4*h4+2)*2+gg] + cf.w*Wif[(4*h4+3)*2+gg]; }
        sm[GIF+lane]=a;
    }
    // zero A cols 30,31 (rows 0..29) and set v ones col (28)
    if (lane < 60) sm[QA + (lane>>1)*32 + 30 + (lane&1)] = 0.f;
    if (lane < SS) sm[VV + lane*29 + 28] = 1.f;
    __syncthreads();

    // ---- Preload weights for phases G/H (loads overlap D3/E/F compute) ----
    const int dq  = lane % DD;
    const int g4  = lane / DD;
    const int dqi = act ? dq : 0;
    float wr[DD], wd[MM];
    float brr, skr, ggr, gbr, bdr;
    {
        #pragma unroll
        for (int d=0;d<DD;d++) wr[d]=Wup_r[d*MM+jqi];
        #pragma unroll
        for (int i2=0;i2<MM;i2++) wd[i2]=Wdown[i2*DD+dqi];
        brr=bup_r[jqi]; skr=skip[jqi]; ggr=gn_g[jqi]; gbr=gn_b[jqi]; bdr=bdown[dqi];
    }

    // ---- Phase D3: gate pre-scan; store exp(a_s), exp(-cm_t) ----
    if (lane < SS){
        float i_ = sm[GIF+2*lane], f_ = sm[GIF+2*lane+1];
        float F = f_, v;
        v = __shfl_up(F,1,64);  if (lane>=1)  F += v;
        v = __shfl_up(F,2,64);  if (lane>=2)  F += v;
        v = __shfl_up(F,4,64);  if (lane>=4)  F += v;
        v = __shfl_up(F,8,64);  if (lane>=8)  F += v;
        v = __shfl_up(F,16,64); if (lane>=16) F += v;
        float a = i_ - F;
        float cm = a;
        v = __shfl_up(cm,1,64);  if (lane>=1)  cm = fmaxf(cm,v);
        v = __shfl_up(cm,2,64);  if (lane>=2)  cm = fmaxf(cm,v);
        v = __shfl_up(cm,4,64);  if (lane>=4)  cm = fmaxf(cm,v);
        v = __shfl_up(cm,8,64);  if (lane>=8)  cm = fmaxf(cm,v);
        v = __shfl_up(cm,16,64); if (lane>=16) cm = fmaxf(cm,v);
        cm = fmaxf(cm, 0.f);   // m0 = 0 branch
        sm[EA+lane]  = __expf(a);
        sm[ECM+lane] = __expf(-cm);
    }
    __syncthreads();

    // ---- Phase E: A[t][s] = (q_t.k_s) * ea_s * ecm_t, s<=t (in-place over q) ----
    {
        const int s = lane & 31, gh = lane >> 5;
        const bool sact = s < SS;
        float kreg[MM]; float eas = 0.f;
        if (sact){
            #pragma unroll
            for (int h=0;h<MM;h++) kreg[h] = sm[KH + s*33 + h];
            eas = sm[EA + s];
        }
        #pragma unroll
        for (int tt=0; tt<15; tt++){
            int t = gh*15 + tt;
            if (sact){
                const float4* qr = (const float4*)&sm[QA + t*32];
                float d = 0.f;
                #pragma unroll
                for (int h4=0;h4<7;h4++){
                    float4 qf = qr[h4];
                    d += qf.x*kreg[4*h4] + qf.y*kreg[4*h4+1] + qf.z*kreg[4*h4+2] + qf.w*kreg[4*h4+3];
                }
                float w = (s <= t) ? eas * sm[ECM+t] : 0.f;
                sm[QA + t*32 + s] = d * w;
            }
        }
    }
    __syncthreads();

    // ---- Phase F: h_t[j] = sum_s A[t][s] * v_s[j] -> h stride 29 ----
    {
        const int j = lane & 31, gh = lane >> 5;
        const bool jact = j < 29;
        float vcol[32];
        if (jact){
            #pragma unroll
            for (int s=0;s<SS;s++) vcol[s] = sm[VV + s*29 + j];
        }
        vcol[30]=0.f; vcol[31]=0.f;
        #pragma unroll
        for (int tt=0; tt<15; tt++){
            int t = gh*15 + tt;
            if (jact){
                const float4* ar = (const float4*)&sm[QA + t*32];
                float acc = 0.f;
                #pragma unroll
                for (int s4=0;s4<8;s4++){
                    float4 af = ar[s4];
                    acc += af.x*vcol[4*s4] + af.y*vcol[4*s4+1] + af.z*vcol[4*s4+2] + af.w*vcol[4*s4+3];
                }
                sm[KH + t*29 + j] = acc;
            }
        }
    }
    __syncthreads();

    // ---- Phase G0: per-t stats (stride-29 rows: conflict-free scalars) ----
    if (lane < SS){
        float s=0.f,s2=0.f;
        #pragma unroll
        for (int u=0;u<MM;u++){ float v=sm[KH+lane*29+u]; s+=v; s2+=v*v; }
        float inv = 1.f/fmaxf(fabsf(sm[KH+lane*29+28]), 1.f);
        float mu=s*(1.f/MM), var=s2*(1.f/MM)-mu*mu;
        sm[ST+lane*3]   = mu*inv;
        sm[ST+lane*3+1] = rsqrtf(var*inv*inv + 1e-5f);
        sm[ST+lane*3+2] = inv;
    }
    __syncthreads();

    // ---- Phase G: e = (hn + skip*c) * silu(ur), ur from xn ----
    #pragma unroll
    for (int tt=0;tt<15;tt++){
        int t=gq*15+tt;
        if (act){
            const float2* xr = (const float2*)&sm[XN+t*DD];
            float urv = brr;
            #pragma unroll
            for (int u=0;u<7;u++){ float2 f=xr[u]; urv += f.x*wr[2*u]+f.y*wr[2*u+1]; }
            float inv = sm[ST+t*3+2];
            float hv = sm[KH+t*29+jq]*inv;
            float hn = (hv-sm[ST+t*3])*sm[ST+t*3+1]*ggr + gbr;
            float h2 = hn + skr*sm[CB+t*MM+jq];
            sm[UL + t*MM + jq] = h2 * fsilu(urv);   // e overlays ul
        }
    }
    __syncthreads();

    // ---- Phase H: y_m = e @ Wdown + bdown + x ----
    #pragma unroll
    for (int tt=0;tt<8;tt++){
        int t=g4*8+tt;
        if (act && t<SS){
            const float4* er=(const float4*)&sm[UL+t*MM];
            float a = bdr + xp[t*DD+dq];
            #pragma unroll
            for (int u=0;u<7;u++){ float4 f=er[u]; a += f.x*wd[4*u]+f.y*wd[4*u+1]+f.z*wd[4*u+2]+f.w*wd[4*u+3]; }
            sm[XN+t*DD+dq]=a;   // y_m overlays xn
        }
    }
    __syncthreads();

    // ---- Phase I: sLSTM LN stats over y_m ----
    if (lane<SS){
        const float2* yr=(const float2*)&sm[XN+lane*DD];
        float s=0.f,s2=0.f;
        #pragma unroll
        for (int u=0;u<7;u++){ float2 f=yr[u]; s+=f.x+f.y; s2+=f.x*f.x+f.y*f.y; }
        float mu=s*(1.f/DD), var=s2*(1.f/DD)-mu*mu;
        sm[ST+lane*2]=mu; sm[ST+lane*2+1]=rsqrtf(var+1e-5f);
    }
    __syncthreads();

    // ---- Phase J: gx = yn @ sW + sb (overlays v) ----
    for (int idx=lane; idx<SS*8; idx+=64){
        int t=idx>>3, gg=idx&7;
        float a=sb[gg];
        float mu=sm[ST+t*2], rs=sm[ST+t*2+1];
        #pragma unroll
        for (int d=0;d<DD;d++){
            float yn=(sm[XN+t*DD+d]-mu)*rs*s_ln_g[d]+s_ln_b[d];
            a += yn*sW[d*8+gg];
        }
        sm[VV+idx]=a;
    }
    __syncthreads();

    // ---- Preload epilogue weights (loads overlap sLSTM scan) ----
    float swd0 = sWdown[0*DD+dqi], swd1 = sWdown[1*DD+dqi], swd2 = sWdown[2*DD+dqi];
    float sbd  = sbdown[dqi];

    // ---- Phase K: sLSTM scan (redundant on all lanes; lane0 writes hs) ----
    {
        float R0[8], R1[8];
        #pragma unroll
        for (int g=0; g<8; g++){ R0[g]=sR[g]; R1[g]=sR[8+g]; }
        float h0=0.f,h1=0.f,c0=0.f,c1=0.f,n0=0.f,n1=0.f,m0=0.f,m1=0.f;
        for (int t=0; t<SS; t++){
            float g[8];
            #pragma unroll
            for (int gg=0; gg<8; gg++) g[gg] = sm[VV+t*8+gg] + h0*R0[gg] + h1*R1[gg];
            float z0=ftanh_(g[0]), z1=ftanh_(g[1]);
            float i0=g[2], i1=g[3], f0=g[4], f1=g[5];
            float o0=fsigm(g[6]), o1=fsigm(g[7]);
            float mn0=fmaxf(f0+m0, i0), mn1=fmaxf(f1+m1, i1);
            float ie0=__expf(i0-mn0), ie1=__expf(i1-mn1);
            float fe0=__expf(f0+m0-mn0), fe1=__expf(f1+m1-mn1);
            c0 = fe0*c0 + ie0*z0;  c1 = fe1*c1 + ie1*z1;
            n0 = fe0*n0 + ie0;     n1 = fe1*n1 + ie1;
            h0 = o0*c0/n0;         h1 = o1*c1/n1;
            m0 = mn0; m1 = mn1;
            if (lane == 0){ sm[VV+240+t*2] = h0; sm[VV+240+t*2+1] = h1; }
        }
    }
    __syncthreads();

    // ---- Phase L0: per-t u-values u[t][k]=gelu(p1)*p2 -> QA (free) ----
    if (lane < SS){
        float a0 = sm[VV+240+lane*2], a1 = sm[VV+240+lane*2+1];
        float mu = 0.5f*(a0+a1);
        float d0 = a0-mu, d1 = a1-mu;
        float var = 0.5f*(d0*d0 + d1*d1);
        float rsg = rsqrtf(var + 1e-5f);
        float hn0 = d0*rsg*s_gn_g[0] + s_gn_b[0];
        float hn1 = d1*rsg*s_gn_g[1] + s_gn_b[1];
        #pragma unroll
        for (int u3=0; u3<3; u3++){
            float p1 = hn0*sWup1[u3] + hn1*sWup1[3+u3] + sbup1[u3];
            float p2 = hn0*sWup2[u3] + hn1*sWup2[3+u3] + sbup2[u3];
            sm[QA + lane*3 + u3] = fgelu(p1)*p2;
        }
    }
    __syncthreads();

    // ---- Phase L: y_s + tanh -> CB ((d,quarter) mapping, no div) ----
    #pragma unroll
    for (int tt=0; tt<8; tt++){
        int t=g4*8+tt;
        if (act && t<SS){
            float acc = sbd + sm[XN+t*DD+dq]
                      + sm[QA+t*3]*swd0 + sm[QA+t*3+1]*swd1 + sm[QA+t*3+2]*swd2;
            sm[CB+t*DD+dq] = ftanh_(acc);
        }
    }
    __syncthreads();

    // ---- Phase M: head fc1(420->32,relu) + fc3(32->1) ----
    {
        int j = lane & 31, half = lane >> 5;
        const float2* tyr = (const float2*)&sm[CB + half*210];
        float a = 0.f;
        const float* w1 = fc1w + (half*210)*32 + j;
        for (int d2=0; d2<105; d2++){
            float2 tv = tyr[d2];
            a += tv.x*w1[(2*d2)*32] + tv.y*w1[(2*d2+1)*32];
        }
        a += __shfl_xor(a, 32, 64);
        a += fc1b[j];
        float r = fmaxf(a, 0.f);
        float p = r * fc3w[j];
        #pragma unroll
        for (int off=16; off>=1; off>>=1) p += __shfl_xor(p, off, 64);
        if (lane == 0) out[b] = p + fc3b[0];
    }
}

extern "C" void kernel_launch(void* const* d_in, const int* in_sizes, int n_in,
                              void* d_out, int out_size, void* d_ws, size_t ws_size,
                              hipStream_t stream) {
    const float* x      = (const float*)d_in[0];
    const float* ln_g   = (const float*)d_in[1];
    const float* ln_b   = (const float*)d_in[2];
    const float* Wup_l  = (const float*)d_in[3];
    const float* bup_l  = (const float*)d_in[4];
    const float* Wup_r  = (const float*)d_in[5];
    const float* bup_r  = (const float*)d_in[6];
    const float* conv_w = (const float*)d_in[7];
    const float* conv_b = (const float*)d_in[8];
    const float* Wq     = (const float*)d_in[9];
    const float* bq     = (const float*)d_in[10];
    const float* Wk     = (const float*)d_in[11];
    const float* bk     = (const float*)d_in[12];
    const float* Wv     = (const float*)d_in[13];
    const float* bv     = (const float*)d_in[14];
    const float* Wif    = (const float*)d_in[15];
    const float* bif    = (const float*)d_in[16];
    const float* gn_g   = (const float*)d_in[17];
    const float* gn_b   = (const float*)d_in[18];
    const float* skip   = (const float*)d_in[19];
    const float* Wdown  = (const float*)d_in[20];
    const float* bdown  = (const float*)d_in[21];
    const float* s_ln_g = (const float*)d_in[22];
    const float* s_ln_b = (const float*)d_in[23];
    const float* sW     = (const float*)d_in[24];
    const float* sR     = (const float*)d_in[25];
    const float* sb     = (const float*)d_in[26];
    const float* s_gn_g = (const float*)d_in[27];
    const float* s_gn_b = (const float*)d_in[28];
    const float* sWup1  = (const float*)d_in[29];
    const float* sbup1  = (const float*)d_in[30];
    const float* sWup2  = (const float*)d_in[31];
    const float* sbup2  = (const float*)d_in[32];
    const float* sWdown = (const float*)d_in[33];
    const float* sbdown = (const float*)d_in[34];
    const float* fc1w   = (const float*)d_in[35];
    const float* fc1b   = (const float*)d_in[36];
    const float* fc3w   = (const float*)d_in[37];
    const float* fc3b   = (const float*)d_in[38];
    float* out = (float*)d_out;

    hipLaunchKernelGGL(net_kernel, dim3(8192), dim3(64), 0, stream,
        x, ln_g, ln_b, Wup_l, bup_l, Wup_r, bup_r, conv_w, conv_b,
        Wq, bq, Wk, bk, Wv, bv, Wif, bif, gn_g, gn_b, skip, Wdown, bdown,
        s_ln_g, s_ln_b, sW, sR, sb, s_gn_g, s_gn_b,
        sWup1, sbup1, sWup2, sbup2, sWdown, sbdown,
        fc1w, fc1b, fc3w, fc3b, out);
}

// Round 5
// 162.753 us; speedup vs baseline: 2.2573x; 1.0600x over previous
//
#include <hip/hip_runtime.h>

#define SS 30
#define DD 14
#define MM 28

// LDS float offsets (16,320 B total -> 10 blocks/CU)
#define XN 0       // 420: xn -> later y_m
#define UL 420     // 840 stride28: ul -> q (D, in-place) -> h (F)
#define CB 1260    // 840 stride28: c -> tanh(y_s) (first 420, phase L)
#define KH 2100    // 990: k stride33 -> scores A stride32 (E) -> e stride28 (G)
#define VV 3090    // 870 stride29: v + ones col -> gx(240)+hs@240(60)
#define GIF 3960   // 60: gif -> ST stats (G0 stride3 / I stride2)
#define EA 4020    // 30: exp(a_s) -> h rowsum (F)
#define ECM 4050   // 30: exp(-cm_t)
#define ST 3960
#define UV 2940    // 90: u-values (inside dead e region, KH+840)
#define SMTOT 4080

__device__ __forceinline__ float frcp(float v){ return __builtin_amdgcn_rcpf(v); }
__device__ __forceinline__ float frsq(float v){ return __builtin_amdgcn_rsqf(v); }
__device__ __forceinline__ float fsigm(float v){ return frcp(1.f+__expf(-v)); }
__device__ __forceinline__ float fsilu(float v){ return v*frcp(1.f+__expf(-v)); }
__device__ __forceinline__ float ftanh_(float v){
    float c = fminf(fmaxf(v, -15.f), 15.f);
    float e = __expf(2.f*c);
    return (e-1.f)*frcp(e+1.f);
}
__device__ __forceinline__ float fgelu(float v){
    float t = ftanh_(0.7978845608028654f*(v + 0.044715f*v*v*v));
    return 0.5f*v*(1.f+t);
}

extern "C" __global__ void __launch_bounds__(64)
net_kernel(const float* __restrict__ xg,
           const float* __restrict__ ln_g, const float* __restrict__ ln_b,
           const float* __restrict__ Wup_l, const float* __restrict__ bup_l,
           const float* __restrict__ Wup_r, const float* __restrict__ bup_r,
           const float* __restrict__ conv_w, const float* __restrict__ conv_b,
           const float* __restrict__ Wq, const float* __restrict__ bq,
           const float* __restrict__ Wk, const float* __restrict__ bk,
           const float* __restrict__ Wv, const float* __restrict__ bv,
           const float* __restrict__ Wif, const float* __restrict__ bif,
           const float* __restrict__ gn_g, const float* __restrict__ gn_b,
           const float* __restrict__ skip,
           const float* __restrict__ Wdown, const float* __restrict__ bdown,
           const float* __restrict__ s_ln_g, const float* __restrict__ s_ln_b,
           const float* __restrict__ sW, const float* __restrict__ sR, const float* __restrict__ sb,
           const float* __restrict__ s_gn_g, const float* __restrict__ s_gn_b,
           const float* __restrict__ sWup1, const float* __restrict__ sbup1,
           const float* __restrict__ sWup2, const float* __restrict__ sbup2,
           const float* __restrict__ sWdown, const float* __restrict__ sbdown,
           const float* __restrict__ fc1w, const float* __restrict__ fc1b,
           const float* __restrict__ fc3w, const float* __restrict__ fc3b,
           float* __restrict__ out)
{
    __shared__ __align__(16) float sm[SMTOT];
    const int lane = threadIdx.x;
    const int b = blockIdx.x;
    const float* xp = xg + (size_t)b * (SS*DD);

    const int jq = lane % MM;
    const int gq = lane / MM;
    const bool act = lane < 56;
    const int jqi = act ? jq : 0;

    // ---- Preload weights for phases B/C/D ----
    float wl[DD], cw[4], wq[MM], wk[MM], wv[MM];
    float blr, cbr, bqr, bkr, bvr;
    {
        #pragma unroll
        for (int d=0; d<DD; d++) wl[d] = Wup_l[d*MM+jqi];
        #pragma unroll
        for (int k=0; k<4; k++) cw[k] = conv_w[k*MM+jqi];
        #pragma unroll
        for (int h=0; h<MM; h++){ wq[h]=Wq[h*MM+jqi]; wk[h]=Wk[h*MM+jqi]; wv[h]=Wv[h*MM+jqi]; }
        blr = bup_l[jqi]; cbr = conv_b[jqi];
        bqr = bq[jqi]; bkr = bk[jqi]; bvr = bv[jqi];
    }

    // ---- Phase A: LN1 -> xn (lane = t) ----
    if (lane < SS){
        float xv[DD];
        const float2* xr = (const float2*)(xp + lane*DD);
        float s=0.f, s2=0.f;
        #pragma unroll
        for (int u=0;u<7;u++){ float2 f=xr[u]; xv[2*u]=f.x; xv[2*u+1]=f.y; s+=f.x+f.y; s2+=f.x*f.x+f.y*f.y; }
        float mu=s*(1.f/DD), var=s2*(1.f/DD)-mu*mu, rsg=frsq(var+1e-5f);
        #pragma unroll
        for (int d=0; d<DD; d++) sm[XN+lane*DD+d] = (xv[d]-mu)*rsg*ln_g[d]+ln_b[d];
    }
    __syncthreads();

    // ---- Phase B: ul = xn @ Wup_l + bup_l ----
    #pragma unroll
    for (int tt=0; tt<15; tt++){
        int t = gq*15+tt;
        if (act){
            const float2* xr = (const float2*)&sm[XN + t*DD];
            float a = blr;
            #pragma unroll
            for (int u=0;u<7;u++){ float2 f = xr[u]; a += f.x*wl[2*u] + f.y*wl[2*u+1]; }
            sm[UL + t*MM + jq] = a;
        }
    }
    __syncthreads();

    // ---- Phase C: causal conv + silu -> c ----
    #pragma unroll
    for (int tt=0; tt<15; tt++){
        int t = gq*15+tt;
        if (act){
            float a = cbr;
            #pragma unroll
            for (int k=0;k<4;k++){
                int ts = t-3+k;
                if (ts>=0) a += sm[UL+ts*MM+jq]*cw[k];
            }
            sm[CB + t*MM + jq] = fsilu(a);
        }
    }
    __syncthreads();

    // ---- Phase D: q (->UL in-place), k (KH stride33), v (VV stride29) ----
    {
        const float rs28 = 0.18898223650461363f; // 1/sqrt(28)
        #pragma unroll
        for (int tt=0; tt<15; tt++){
            int t = gq*15+tt;
            if (act){
                const float4* cr = (const float4*)&sm[CB + t*MM];
                const float4* ur = (const float4*)&sm[UL + t*MM];
                float aq=bqr, ak=bkr, av=bvr;
                #pragma unroll
                for (int h4=0;h4<7;h4++){
                    float4 cf=cr[h4], uf=ur[h4];
                    aq += cf.x*wq[4*h4] + cf.y*wq[4*h4+1] + cf.z*wq[4*h4+2] + cf.w*wq[4*h4+3];
                    ak += cf.x*wk[4*h4] + cf.y*wk[4*h4+1] + cf.z*wk[4*h4+2] + cf.w*wk[4*h4+3];
                    av += uf.x*wv[4*h4] + uf.y*wv[4*h4+1] + uf.z*wv[4*h4+2] + uf.w*wv[4*h4+3];
                }
                sm[UL + t*MM + jq] = aq;      // q over ul (row read first)
                sm[KH + t*33 + jq] = ak*rs28;
                sm[VV + t*29 + jq] = av;
            }
        }
    }
    // gif = c @ Wif + bif  (lane<60)
    if (lane < SS*2){
        int t=lane>>1, gg=lane&1;
        float a = bif[gg];
        const float4* cr = (const float4*)&sm[CB+t*MM];
        #pragma unroll
        for (int h4=0;h4<7;h4++){ float4 cf=cr[h4];
            a += cf.x*Wif[(4*h4)*2+gg] + cf.y*Wif[(4*h4+1)*2+gg]
               + cf.z*Wif[(4*h4+2)*2+gg] + cf.w*Wif[(4*h4+3)*2+gg]; }
        sm[GIF+lane]=a;
    }
    if (lane < SS) sm[VV + lane*29 + 28] = 1.f;   // ones col
    __syncthreads();

    // ---- Preload weights for phases G/H ----
    const int dq  = lane % DD;
    const int g4  = lane / DD;
    const int dqi = act ? dq : 0;
    float wr[DD], wd[MM];
    float brr, skr, ggr, gbr, bdr;
    {
        #pragma unroll
        for (int d=0;d<DD;d++) wr[d]=Wup_r[d*MM+jqi];
        #pragma unroll
        for (int i2=0;i2<MM;i2++) wd[i2]=Wdown[i2*DD+dqi];
        brr=bup_r[jqi]; skr=skip[jqi]; ggr=gn_g[jqi]; gbr=gn_b[jqi]; bdr=bdown[dqi];
    }

    // ---- Phase D3: gate pre-scan; store exp(a_s), exp(-cm_t) ----
    if (lane < SS){
        float i_ = sm[GIF+2*lane], f_ = sm[GIF+2*lane+1];
        float F = f_, v;
        v = __shfl_up(F,1,64);  if (lane>=1)  F += v;
        v = __shfl_up(F,2,64);  if (lane>=2)  F += v;
        v = __shfl_up(F,4,64);  if (lane>=4)  F += v;
        v = __shfl_up(F,8,64);  if (lane>=8)  F += v;
        v = __shfl_up(F,16,64); if (lane>=16) F += v;
        float a = i_ - F;
        float cm = a;
        v = __shfl_up(cm,1,64);  if (lane>=1)  cm = fmaxf(cm,v);
        v = __shfl_up(cm,2,64);  if (lane>=2)  cm = fmaxf(cm,v);
        v = __shfl_up(cm,4,64);  if (lane>=4)  cm = fmaxf(cm,v);
        v = __shfl_up(cm,8,64);  if (lane>=8)  cm = fmaxf(cm,v);
        v = __shfl_up(cm,16,64); if (lane>=16) cm = fmaxf(cm,v);
        cm = fmaxf(cm, 0.f);   // m0 = 0 branch
        sm[EA+lane]  = __expf(a);
        sm[ECM+lane] = __expf(-cm);
    }
    __syncthreads();

    // ---- Phase E: A[t][s] = (q_t.k_s)*ea_s*ecm_t (s<=t), A -> KH stride32 ----
    {
        const int s = lane & 31, gh = lane >> 5;
        const bool sact = s < SS;
        float kreg[MM]; float eas = 0.f;
        #pragma unroll
        for (int h=0;h<MM;h++) kreg[h]=0.f;
        if (sact){
            #pragma unroll
            for (int h=0;h<MM;h++) kreg[h] = sm[KH + s*33 + h];  // all reads precede A writes
            eas = sm[EA + s];
        }
        #pragma unroll
        for (int tt=0; tt<15; tt++){
            int t = gh*15 + tt;
            const float4* qr = (const float4*)&sm[UL + t*MM];
            float d = 0.f;
            #pragma unroll
            for (int h4=0;h4<7;h4++){
                float4 qf = qr[h4];
                d += qf.x*kreg[4*h4] + qf.y*kreg[4*h4+1] + qf.z*kreg[4*h4+2] + qf.w*kreg[4*h4+3];
            }
            float val = (sact && s <= t) ? d * eas * sm[ECM+t] : 0.f;
            sm[KH + t*32 + s] = val;   // lanes s=30,31 write the pad zeros
        }
    }
    __syncthreads();

    // ---- Phase F: h_t[j] = sum_s A[t][s]*v_s[j]; j<28 -> UL, j==28 -> EA ----
    {
        const int j = lane & 31, gh = lane >> 5;
        const bool jact = j < 29;
        float vcol[32];
        if (jact){
            #pragma unroll
            for (int s=0;s<SS;s++) vcol[s] = sm[VV + s*29 + j];
        }
        vcol[30]=0.f; vcol[31]=0.f;
        #pragma unroll
        for (int tt=0; tt<15; tt++){
            int t = gh*15 + tt;
            if (jact){
                const float4* ar = (const float4*)&sm[KH + t*32];
                float acc = 0.f;
                #pragma unroll
                for (int s4=0;s4<8;s4++){
                    float4 af = ar[s4];
                    acc += af.x*vcol[4*s4] + af.y*vcol[4*s4+1] + af.z*vcol[4*s4+2] + af.w*vcol[4*s4+3];
                }
                if (j < MM) sm[UL + t*MM + j] = acc;   // h over q
                else        sm[EA + t] = acc;          // rowsum over dead exp(a)
            }
        }
    }
    __syncthreads();

    // ---- Phase G0: per-t stats ----
    if (lane < SS){
        float s=0.f,s2=0.f;
        #pragma unroll
        for (int u=0;u<MM;u++){ float v=sm[UL+lane*MM+u]; s+=v; s2+=v*v; }
        float inv = frcp(fmaxf(fabsf(sm[EA+lane]), 1.f));
        float mu=s*(1.f/MM), var=s2*(1.f/MM)-mu*mu;
        sm[ST+lane*3]   = mu*inv;                     // ST writes after EA read
        sm[ST+lane*3+1] = frsq(var*inv*inv + 1e-5f);
        sm[ST+lane*3+2] = inv;
    }
    __syncthreads();

    // ---- Phase G: e = (hn + skip*c)*silu(ur) -> KH stride28 ----
    #pragma unroll
    for (int tt=0;tt<15;tt++){
        int t=gq*15+tt;
        if (act){
            const float2* xr = (const float2*)&sm[XN+t*DD];
            float urv = brr;
            #pragma unroll
            for (int u=0;u<7;u++){ float2 f=xr[u]; urv += f.x*wr[2*u]+f.y*wr[2*u+1]; }
            float inv = sm[ST+t*3+2];
            float hv = sm[UL+t*MM+jq]*inv;
            float hn = (hv-sm[ST+t*3])*sm[ST+t*3+1]*ggr + gbr;
            float h2 = hn + skr*sm[CB+t*MM+jq];
            sm[KH + t*MM + jq] = h2 * fsilu(urv);
        }
    }
    __syncthreads();

    // ---- Phase H: y_m = e @ Wdown + bdown + x -> XN ----
    #pragma unroll
    for (int tt=0;tt<8;tt++){
        int t=g4*8+tt;
        if (act && t<SS){
            const float4* er=(const float4*)&sm[KH+t*MM];
            float a = bdr + xp[t*DD+dq];
            #pragma unroll
            for (int u=0;u<7;u++){ float4 f=er[u]; a += f.x*wd[4*u]+f.y*wd[4*u+1]+f.z*wd[4*u+2]+f.w*wd[4*u+3]; }
            sm[XN+t*DD+dq]=a;
        }
    }
    __syncthreads();

    // ---- Phase I: sLSTM LN stats over y_m ----
    if (lane<SS){
        const float2* yr=(const float2*)&sm[XN+lane*DD];
        float s=0.f,s2=0.f;
        #pragma unroll
        for (int u=0;u<7;u++){ float2 f=yr[u]; s+=f.x+f.y; s2+=f.x*f.x+f.y*f.y; }
        float mu=s*(1.f/DD), var=s2*(1.f/DD)-mu*mu;
        sm[ST+lane*2]=mu; sm[ST+lane*2+1]=frsq(var+1e-5f);
    }
    __syncthreads();

    // ---- Phase J: gx = yn @ sW + sb -> VV ----
    for (int idx=lane; idx<SS*8; idx+=64){
        int t=idx>>3, gg=idx&7;
        float a=sb[gg];
        float mu=sm[ST+t*2], rs=sm[ST+t*2+1];
        #pragma unroll
        for (int d=0;d<DD;d++){
            float yn=(sm[XN+t*DD+d]-mu)*rs*s_ln_g[d]+s_ln_b[d];
            a += yn*sW[d*8+gg];
        }
        sm[VV+idx]=a;
    }
    __syncthreads();

    // ---- Preload epilogue weights ----
    float swd0 = sWdown[0*DD+dqi], swd1 = sWdown[1*DD+dqi], swd2 = sWdown[2*DD+dqi];
    float sbd  = sbdown[dqi];

    // ---- Phase K: sLSTM scan (redundant on all lanes; lane0 writes hs) ----
    {
        float R0[8], R1[8];
        #pragma unroll
        for (int g=0; g<8; g++){ R0[g]=sR[g]; R1[g]=sR[8+g]; }
        float h0=0.f,h1=0.f,c0=0.f,c1=0.f,n0=0.f,n1=0.f,m0=0.f,m1=0.f;
        for (int t=0; t<SS; t++){
            float g[8];
            #pragma unroll
            for (int gg=0; gg<8; gg++) g[gg] = sm[VV+t*8+gg] + h0*R0[gg] + h1*R1[gg];
            float z0=ftanh_(g[0]), z1=ftanh_(g[1]);
            float i0=g[2], i1=g[3], f0=g[4], f1=g[5];
            float o0=fsigm(g[6]), o1=fsigm(g[7]);
            float mn0=fmaxf(f0+m0, i0), mn1=fmaxf(f1+m1, i1);
            float ie0=__expf(i0-mn0), ie1=__expf(i1-mn1);
            float fe0=__expf(f0+m0-mn0), fe1=__expf(f1+m1-mn1);
            c0 = fe0*c0 + ie0*z0;  c1 = fe1*c1 + ie1*z1;
            n0 = fe0*n0 + ie0;     n1 = fe1*n1 + ie1;
            h0 = o0*c0*frcp(n0);   h1 = o1*c1*frcp(n1);
            m0 = mn0; m1 = mn1;
            if (lane == 0){ sm[VV+240+t*2] = h0; sm[VV+240+t*2+1] = h1; }
        }
    }
    __syncthreads();

    // ---- Phase L0: per-t u-values -> UV ----
    if (lane < SS){
        float a0 = sm[VV+240+lane*2], a1 = sm[VV+240+lane*2+1];
        float mu = 0.5f*(a0+a1);
        float d0 = a0-mu, d1 = a1-mu;
        float var = 0.5f*(d0*d0 + d1*d1);
        float rsg = frsq(var + 1e-5f);
        float hn0 = d0*rsg*s_gn_g[0] + s_gn_b[0];
        float hn1 = d1*rsg*s_gn_g[1] + s_gn_b[1];
        #pragma unroll
        for (int u3=0; u3<3; u3++){
            float p1 = hn0*sWup1[u3] + hn1*sWup1[3+u3] + sbup1[u3];
            float p2 = hn0*sWup2[u3] + hn1*sWup2[3+u3] + sbup2[u3];
            sm[UV + lane*3 + u3] = fgelu(p1)*p2;
        }
    }
    __syncthreads();

    // ---- Phase L: y_s + tanh -> CB ----
    #pragma unroll
    for (int tt=0; tt<8; tt++){
        int t=g4*8+tt;
        if (act && t<SS){
            float acc = sbd + sm[XN+t*DD+dq]
                      + sm[UV+t*3]*swd0 + sm[UV+t*3+1]*swd1 + sm[UV+t*3+2]*swd2;
            sm[CB+t*DD+dq] = ftanh_(acc);
        }
    }
    __syncthreads();

    // ---- Phase M: head fc1(420->32,relu) + fc3(32->1) ----
    {
        int j = lane & 31, half = lane >> 5;
        const float2* tyr = (const float2*)&sm[CB + half*210];
        float a = 0.f;
        const float* w1 = fc1w + (half*210)*32 + j;
        for (int d2=0; d2<105; d2++){
            float2 tv = tyr[d2];
            a += tv.x*w1[(2*d2)*32] + tv.y*w1[(2*d2+1)*32];
        }
        a += __shfl_xor(a, 32, 64);
        a += fc1b[j];
        float r = fmaxf(a, 0.f);
        float p = r * fc3w[j];
        #pragma unroll
        for (int off=16; off>=1; off>>=1) p += __shfl_xor(p, off, 64);
        if (lane == 0) out[b] = p + fc3b[0];
    }
}

extern "C" void kernel_launch(void* const* d_in, const int* in_sizes, int n_in,
                              void* d_out, int out_size, void* d_ws, size_t ws_size,
                              hipStream_t stream) {
    const float* x      = (const float*)d_in[0];
    const float* ln_g   = (const float*)d_in[1];
    const float* ln_b   = (const float*)d_in[2];
    const float* Wup_l  = (const float*)d_in[3];
    const float* bup_l  = (const float*)d_in[4];
    const float* Wup_r  = (const float*)d_in[5];
    const float* bup_r  = (const float*)d_in[6];
    const float* conv_w = (const float*)d_in[7];
    const float* conv_b = (const float*)d_in[8];
    const float* Wq     = (const float*)d_in[9];
    const float* bq     = (const float*)d_in[10];
    const float* Wk     = (const float*)d_in[11];
    const float* bk     = (const float*)d_in[12];
    const float* Wv     = (const float*)d_in[13];
    const float* bv     = (const float*)d_in[14];
    const float* Wif    = (const float*)d_in[15];
    const float* bif    = (const float*)d_in[16];
    const float* gn_g   = (const float*)d_in[17];
    const float* gn_b   = (const float*)d_in[18];
    const float* skip   = (const float*)d_in[19];
    const float* Wdown  = (const float*)d_in[20];
    const float* bdown  = (const float*)d_in[21];
    const float* s_ln_g = (const float*)d_in[22];
    const float* s_ln_b = (const float*)d_in[23];
    const float* sW     = (const float*)d_in[24];
    const float* sR     = (const float*)d_in[25];
    const float* sb     = (const float*)d_in[26];
    const float* s_gn_g = (const float*)d_in[27];
    const float* s_gn_b = (const float*)d_in[28];
    const float* sWup1  = (const float*)d_in[29];
    const float* sbup1  = (const float*)d_in[30];
    const float* sWup2  = (const float*)d_in[31];
    const float* sbup2  = (const float*)d_in[32];
    const float* sWdown = (const float*)d_in[33];
    const float* sbdown = (const float*)d_in[34];
    const float* fc1w   = (const float*)d_in[35];
    const float* fc1b   = (const float*)d_in[36];
    const float* fc3w   = (const float*)d_in[37];
    const float* fc3b   = (const float*)d_in[38];
    float* out = (float*)d_out;

    hipLaunchKernelGGL(net_kernel, dim3(8192), dim3(64), 0, stream,
        x, ln_g, ln_b, Wup_l, bup_l, Wup_r, bup_r, conv_w, conv_b,
        Wq, bq, Wk, bk, Wv, bv, Wif, bif, gn_g, gn_b, skip, Wdown, bdown,
        s_ln_g, s_ln_b, sW, sR, sb, s_gn_g, s_gn_b,
        sWup1, sbup1, sWup2, sbup2, sWdown, sbdown,
        fc1w, fc1b, fc3w, fc3b, out);
}

// Round 6
// 155.478 us; speedup vs baseline: 2.3630x; 1.0468x over previous
//
#include <hip/hip_runtime.h>

#define SS 30
#define DD 14
#define MM 28

// LDS float offsets (20,160 B). Single-wave block: no __syncthreads, compiler
// memory fences at phase boundaries; LDS ops from one wave complete in order.
#define XN  0      // 420: xn -> y_m (H)
#define UL  420    // 840 stride28: ul -> e (G)
#define CB  1260   // 840 stride28: c -> tanh(y_s) (L, first 420)
#define QH  2100   // 960: q stride32 (D) -> h stride29 (F)
#define KA  3060   // 990: k stride33 (D) -> A stride32 (E, 960) -> UV (L0, 90)
#define VV  4050   // 870 stride29: v + ones -> gx(240)+hs@240(60) (J/K)
#define ST2 4920   // 60: gif (D) -> {mu,rs} stride2 (G0) -> LN stats (I)
#define EA  4980   // 30: exp(a) (D3) -> rowsum (F)
#define SIV 5010   // 30: exp(-cm) (D3) -> inv (G0)
#define UV  3060   // 90 (dead A region)
#define SMTOT 5040

#define WSYNC() asm volatile("" ::: "memory")

__device__ __forceinline__ float frcp(float v){ return __builtin_amdgcn_rcpf(v); }
__device__ __forceinline__ float frsq(float v){ return __builtin_amdgcn_rsqf(v); }
__device__ __forceinline__ float fsigm(float v){ return frcp(1.f+__expf(-v)); }
__device__ __forceinline__ float fsilu(float v){ return v*frcp(1.f+__expf(-v)); }
__device__ __forceinline__ float ftanh_(float v){
    float c = fminf(fmaxf(v, -15.f), 15.f);
    float e = __expf(2.f*c);
    return (e-1.f)*frcp(e+1.f);
}
__device__ __forceinline__ float fgelu(float v){
    float t = ftanh_(0.7978845608028654f*(v + 0.044715f*v*v*v));
    return 0.5f*v*(1.f+t);
}

extern "C" __global__ void __launch_bounds__(64)
net_kernel(const float* __restrict__ xg,
           const float* __restrict__ ln_g, const float* __restrict__ ln_b,
           const float* __restrict__ Wup_l, const float* __restrict__ bup_l,
           const float* __restrict__ Wup_r, const float* __restrict__ bup_r,
           const float* __restrict__ conv_w, const float* __restrict__ conv_b,
           const float* __restrict__ Wq, const float* __restrict__ bq,
           const float* __restrict__ Wk, const float* __restrict__ bk,
           const float* __restrict__ Wv, const float* __restrict__ bv,
           const float* __restrict__ Wif, const float* __restrict__ bif,
           const float* __restrict__ gn_g, const float* __restrict__ gn_b,
           const float* __restrict__ skip,
           const float* __restrict__ Wdown, const float* __restrict__ bdown,
           const float* __restrict__ s_ln_g, const float* __restrict__ s_ln_b,
           const float* __restrict__ sW, const float* __restrict__ sR, const float* __restrict__ sb,
           const float* __restrict__ s_gn_g, const float* __restrict__ s_gn_b,
           const float* __restrict__ sWup1, const float* __restrict__ sbup1,
           const float* __restrict__ sWup2, const float* __restrict__ sbup2,
           const float* __restrict__ sWdown, const float* __restrict__ sbdown,
           const float* __restrict__ fc1w, const float* __restrict__ fc1b,
           const float* __restrict__ fc3w, const float* __restrict__ fc3b,
           float* __restrict__ out)
{
    __shared__ __align__(16) float sm[SMTOT];
    const int lane = threadIdx.x;
    const int b = blockIdx.x;
    const float* xp = xg + (size_t)b * (SS*DD);

    const int jq = lane % MM;
    const int gq = lane / MM;
    const bool act = lane < 56;
    const int jqi = act ? jq : 0;

    // ---- Preload weights for phases B/C/D (float until first use) ----
    float wl[DD], cw[4], wq[MM], wk[MM], wv[MM];
    float blr, cbr, bqr, bkr, bvr;
    {
        #pragma unroll
        for (int d=0; d<DD; d++) wl[d] = Wup_l[d*MM+jqi];
        #pragma unroll
        for (int k=0; k<4; k++) cw[k] = conv_w[k*MM+jqi];
        #pragma unroll
        for (int h=0; h<MM; h++){ wq[h]=Wq[h*MM+jqi]; wk[h]=Wk[h*MM+jqi]; wv[h]=Wv[h*MM+jqi]; }
        blr = bup_l[jqi]; cbr = conv_b[jqi];
        bqr = bq[jqi]; bkr = bk[jqi]; bvr = bv[jqi];
    }

    // ---- Phase A: LN1 -> xn (lane = t) ----
    if (lane < SS){
        float xv[DD];
        const float2* xr = (const float2*)(xp + lane*DD);
        float s=0.f, s2=0.f;
        #pragma unroll
        for (int u=0;u<7;u++){ float2 f=xr[u]; xv[2*u]=f.x; xv[2*u+1]=f.y; s+=f.x+f.y; s2+=f.x*f.x+f.y*f.y; }
        float mu=s*(1.f/DD), var=s2*(1.f/DD)-mu*mu, rsg=frsq(var+1e-5f);
        #pragma unroll
        for (int d=0; d<DD; d++) sm[XN+lane*DD+d] = (xv[d]-mu)*rsg*ln_g[d]+ln_b[d];
    }
    WSYNC();

    // ---- Phase B: ul = xn @ Wup_l + bup_l ----
    #pragma unroll
    for (int tt=0; tt<15; tt++){
        int t = gq*15+tt;
        if (act){
            const float2* xr = (const float2*)&sm[XN + t*DD];
            float a = blr;
            #pragma unroll
            for (int u=0;u<7;u++){ float2 f = xr[u]; a += f.x*wl[2*u] + f.y*wl[2*u+1]; }
            sm[UL + t*MM + jq] = a;
        }
    }
    WSYNC();

    // ---- Phase C: causal conv + silu -> c ----
    #pragma unroll
    for (int tt=0; tt<15; tt++){
        int t = gq*15+tt;
        if (act){
            float a = cbr;
            #pragma unroll
            for (int k=0;k<4;k++){
                int ts = t-3+k;
                if (ts>=0) a += sm[UL+ts*MM+jq]*cw[k];
            }
            sm[CB + t*MM + jq] = fsilu(a);
        }
    }
    WSYNC();

    // ---- Phase D: q (QH stride32), k (KA stride33), v (VV stride29) ----
    {
        const float rs28 = 0.18898223650461363f; // 1/sqrt(28)
        #pragma unroll
        for (int tt=0; tt<15; tt++){
            int t = gq*15+tt;
            if (act){
                const float4* cr = (const float4*)&sm[CB + t*MM];
                const float4* ur = (const float4*)&sm[UL + t*MM];
                float aq=bqr, ak=bkr, av=bvr;
                #pragma unroll
                for (int h4=0;h4<7;h4++){
                    float4 cf=cr[h4], uf=ur[h4];
                    aq += cf.x*wq[4*h4] + cf.y*wq[4*h4+1] + cf.z*wq[4*h4+2] + cf.w*wq[4*h4+3];
                    ak += cf.x*wk[4*h4] + cf.y*wk[4*h4+1] + cf.z*wk[4*h4+2] + cf.w*wk[4*h4+3];
                    av += uf.x*wv[4*h4] + uf.y*wv[4*h4+1] + uf.z*wv[4*h4+2] + uf.w*wv[4*h4+3];
                }
                sm[QH + t*32 + jq] = aq;
                sm[KA + t*33 + jq] = ak*rs28;
                sm[VV + t*29 + jq] = av;
            }
        }
    }
    // gif = c @ Wif + bif  (lane<60)
    if (lane < SS*2){
        int t=lane>>1, gg=lane&1;
        float a = bif[gg];
        const float4* cr = (const float4*)&sm[CB+t*MM];
        #pragma unroll
        for (int h4=0;h4<7;h4++){ float4 cf=cr[h4];
            a += cf.x*Wif[(4*h4)*2+gg] + cf.y*Wif[(4*h4+1)*2+gg]
               + cf.z*Wif[(4*h4+2)*2+gg] + cf.w*Wif[(4*h4+3)*2+gg]; }
        sm[ST2+lane]=a;   // gif lives in ST2 region
    }
    if (lane < SS) sm[VV + lane*29 + 28] = 1.f;   // ones col (disjoint from v writes)
    WSYNC();

    // ---- Preload weights for phases G/H ----
    const int dq  = lane % DD;
    const int g4  = lane / DD;
    const int dqi = act ? dq : 0;
    float wr[DD], wd[MM];
    float brr, skr, ggr, gbr, bdr;
    {
        #pragma unroll
        for (int d=0;d<DD;d++) wr[d]=Wup_r[d*MM+jqi];
        #pragma unroll
        for (int i2=0;i2<MM;i2++) wd[i2]=Wdown[i2*DD+dqi];
        brr=bup_r[jqi]; skr=skip[jqi]; ggr=gn_g[jqi]; gbr=gn_b[jqi]; bdr=bdown[dqi];
    }

    // ---- Phase D3: gate pre-scan; store exp(a_s), exp(-cm_t) ----
    if (lane < SS){
        float i_ = sm[ST2+2*lane], f_ = sm[ST2+2*lane+1];
        float F = f_, v;
        v = __shfl_up(F,1,64);  if (lane>=1)  F += v;
        v = __shfl_up(F,2,64);  if (lane>=2)  F += v;
        v = __shfl_up(F,4,64);  if (lane>=4)  F += v;
        v = __shfl_up(F,8,64);  if (lane>=8)  F += v;
        v = __shfl_up(F,16,64); if (lane>=16) F += v;
        float a = i_ - F;
        float cm = a;
        v = __shfl_up(cm,1,64);  if (lane>=1)  cm = fmaxf(cm,v);
        v = __shfl_up(cm,2,64);  if (lane>=2)  cm = fmaxf(cm,v);
        v = __shfl_up(cm,4,64);  if (lane>=4)  cm = fmaxf(cm,v);
        v = __shfl_up(cm,8,64);  if (lane>=8)  cm = fmaxf(cm,v);
        v = __shfl_up(cm,16,64); if (lane>=16) cm = fmaxf(cm,v);
        cm = fmaxf(cm, 0.f);   // m0 = 0 branch
        sm[EA+lane]  = __expf(a);
        sm[SIV+lane] = __expf(-cm);
    }
    WSYNC();

    // ---- Phase E: A[t][s] = (q_t.k_s)*ea_s*ecm_t (s<=t); A over k (stride32) ----
    {
        const int s = lane & 31, gh = lane >> 5;
        const bool sact = s < SS;
        float kreg[MM]; float eas = 0.f;
        #pragma unroll
        for (int h=0;h<MM;h++) kreg[h]=0.f;
        if (sact){
            #pragma unroll
            for (int h=0;h<MM;h++) kreg[h] = sm[KA + s*33 + h];
            eas = sm[EA + s];
        }
        WSYNC();   // all k reads complete (in order) before any A write below
        #pragma unroll
        for (int tt=0; tt<15; tt++){
            int t = gh*15 + tt;
            const float4* qr = (const float4*)&sm[QH + t*32];
            float d = 0.f;
            #pragma unroll
            for (int h4=0;h4<7;h4++){
                float4 qf = qr[h4];
                d += qf.x*kreg[4*h4] + qf.y*kreg[4*h4+1] + qf.z*kreg[4*h4+2] + qf.w*kreg[4*h4+3];
            }
            float val = (sact && s <= t) ? d * eas * sm[SIV+t] : 0.f;
            sm[KA + t*32 + s] = val;   // lanes s=30,31 write pad zeros
        }
    }
    WSYNC();

    // ---- Phase F: h_t[j] = sum_s A[t][s]*v_s[j]; j<28 -> QH stride29, j==28 -> EA ----
    {
        const int j = lane & 31, gh = lane >> 5;
        const bool jact = j < 29;
        float vcol[32];
        if (jact){
            #pragma unroll
            for (int s=0;s<SS;s++) vcol[s] = sm[VV + s*29 + j];
        }
        vcol[30]=0.f; vcol[31]=0.f;
        #pragma unroll
        for (int tt=0; tt<15; tt++){
            int t = gh*15 + tt;
            if (jact){
                const float4* ar = (const float4*)&sm[KA + t*32];
                float acc = 0.f;
                #pragma unroll
                for (int s4=0;s4<8;s4++){
                    float4 af = ar[s4];
                    acc += af.x*vcol[4*s4] + af.y*vcol[4*s4+1] + af.z*vcol[4*s4+2] + af.w*vcol[4*s4+3];
                }
                if (j < MM) sm[QH + t*29 + j] = acc;   // h (q dead)
                else        sm[EA + t] = acc;          // rowsum (exp(a) dead)
            }
        }
    }
    WSYNC();

    // ---- Phase G0: per-t stats: {mu*inv, rs} -> ST2 stride2, inv -> SIV ----
    if (lane < SS){
        float s=0.f,s2=0.f;
        #pragma unroll
        for (int u=0;u<MM;u++){ float v=sm[QH+lane*29+u]; s+=v; s2+=v*v; }
        float inv = frcp(fmaxf(fabsf(sm[EA+lane]), 1.f));
        float mu=s*(1.f/MM), var=s2*(1.f/MM)-mu*mu;
        sm[ST2+lane*2]   = mu*inv;
        sm[ST2+lane*2+1] = frsq(var*inv*inv + 1e-5f);
        sm[SIV+lane]     = inv;
    }
    WSYNC();

    // ---- Phase G: e = (hn + skip*c)*silu(ur) -> UL stride28 (ul dead) ----
    #pragma unroll
    for (int tt=0;tt<15;tt++){
        int t=gq*15+tt;
        if (act){
            const float2* xr = (const float2*)&sm[XN+t*DD];
            float urv = brr;
            #pragma unroll
            for (int u=0;u<7;u++){ float2 f=xr[u]; urv += f.x*wr[2*u]+f.y*wr[2*u+1]; }
            float inv = sm[SIV+t];
            float hv = sm[QH+t*29+jq]*inv;
            float hn = (hv-sm[ST2+t*2])*sm[ST2+t*2+1]*ggr + gbr;
            float h2 = hn + skr*sm[CB+t*MM+jq];
            sm[UL + t*MM + jq] = h2 * fsilu(urv);
        }
    }
    WSYNC();

    // ---- Phase H: y_m = e @ Wdown + bdown + x -> XN ----
    #pragma unroll
    for (int tt=0;tt<8;tt++){
        int t=g4*8+tt;
        if (act && t<SS){
            const float4* er=(const float4*)&sm[UL+t*MM];
            float a = bdr + xp[t*DD+dq];
            #pragma unroll
            for (int u=0;u<7;u++){ float4 f=er[u]; a += f.x*wd[4*u]+f.y*wd[4*u+1]+f.z*wd[4*u+2]+f.w*wd[4*u+3]; }
            sm[XN+t*DD+dq]=a;
        }
    }
    WSYNC();

    // ---- Phase I: sLSTM LN stats over y_m -> ST2 stride2 ----
    if (lane<SS){
        const float2* yr=(const float2*)&sm[XN+lane*DD];
        float s=0.f,s2=0.f;
        #pragma unroll
        for (int u=0;u<7;u++){ float2 f=yr[u]; s+=f.x+f.y; s2+=f.x*f.x+f.y*f.y; }
        float mu=s*(1.f/DD), var=s2*(1.f/DD)-mu*mu;
        sm[ST2+lane*2]=mu; sm[ST2+lane*2+1]=frsq(var+1e-5f);
    }
    WSYNC();

    // ---- Phase J: gx = yn @ sW + sb -> VV (v dead) ----
    for (int idx=lane; idx<SS*8; idx+=64){
        int t=idx>>3, gg=idx&7;
        float a=sb[gg];
        float mu=sm[ST2+t*2], rs=sm[ST2+t*2+1];
        #pragma unroll
        for (int d=0;d<DD;d++){
            float yn=(sm[XN+t*DD+d]-mu)*rs*s_ln_g[d]+s_ln_b[d];
            a += yn*sW[d*8+gg];
        }
        sm[VV+idx]=a;
    }
    WSYNC();

    // ---- Preload epilogue weights ----
    float swd0 = sWdown[0*DD+dqi], swd1 = sWdown[1*DD+dqi], swd2 = sWdown[2*DD+dqi];
    float sbd  = sbdown[dqi];

    // ---- Phase K: sLSTM scan (redundant on all lanes; lane0 writes hs) ----
    {
        float R0[8], R1[8];
        #pragma unroll
        for (int g=0; g<8; g++){ R0[g]=sR[g]; R1[g]=sR[8+g]; }
        float h0=0.f,h1=0.f,c0=0.f,c1=0.f,n0=0.f,n1=0.f,m0=0.f,m1=0.f;
        for (int t=0; t<SS; t++){
            const float2* gr = (const float2*)&sm[VV+t*8];
            float2 ga=gr[0], gb_=gr[1], gc=gr[2], gd=gr[3];
            float g0=ga.x+h0*R0[0]+h1*R1[0], g1=ga.y+h0*R0[1]+h1*R1[1];
            float g2=gb_.x+h0*R0[2]+h1*R1[2], g3=gb_.y+h0*R0[3]+h1*R1[3];
            float g4v=gc.x+h0*R0[4]+h1*R1[4], g5=gc.y+h0*R0[5]+h1*R1[5];
            float g6=gd.x+h0*R0[6]+h1*R1[6], g7=gd.y+h0*R0[7]+h1*R1[7];
            float z0=ftanh_(g0), z1=ftanh_(g1);
            float o0=fsigm(g6), o1=fsigm(g7);
            float mn0=fmaxf(g4v+m0, g2), mn1=fmaxf(g5+m1, g3);
            float ie0=__expf(g2-mn0), ie1=__expf(g3-mn1);
            float fe0=__expf(g4v+m0-mn0), fe1=__expf(g5+m1-mn1);
            c0 = fe0*c0 + ie0*z0;  c1 = fe1*c1 + ie1*z1;
            n0 = fe0*n0 + ie0;     n1 = fe1*n1 + ie1;
            h0 = o0*c0*frcp(n0);   h1 = o1*c1*frcp(n1);
            m0 = mn0; m1 = mn1;
            if (lane == 0){ sm[VV+240+t*2] = h0; sm[VV+240+t*2+1] = h1; }
        }
    }
    WSYNC();

    // ---- Phase L0: per-t u-values -> UV (dead A region) ----
    if (lane < SS){
        float a0 = sm[VV+240+lane*2], a1 = sm[VV+240+lane*2+1];
        float mu = 0.5f*(a0+a1);
        float d0 = a0-mu, d1 = a1-mu;
        float var = 0.5f*(d0*d0 + d1*d1);
        float rsg = frsq(var + 1e-5f);
        float hn0 = d0*rsg*s_gn_g[0] + s_gn_b[0];
        float hn1 = d1*rsg*s_gn_g[1] + s_gn_b[1];
        #pragma unroll
        for (int u3=0; u3<3; u3++){
            float p1 = hn0*sWup1[u3] + hn1*sWup1[3+u3] + sbup1[u3];
            float p2 = hn0*sWup2[u3] + hn1*sWup2[3+u3] + sbup2[u3];
            sm[UV + lane*3 + u3] = fgelu(p1)*p2;
        }
    }
    WSYNC();

    // ---- Phase L: y_s + tanh -> CB ----
    #pragma unroll
    for (int tt=0; tt<8; tt++){
        int t=g4*8+tt;
        if (act && t<SS){
            float acc = sbd + sm[XN+t*DD+dq]
                      + sm[UV+t*3]*swd0 + sm[UV+t*3+1]*swd1 + sm[UV+t*3+2]*swd2;
            sm[CB+t*DD+dq] = ftanh_(acc);
        }
    }
    WSYNC();

    // ---- Phase M: head fc1(420->32,relu) + fc3(32->1) ----
    {
        int j = lane & 31, half = lane >> 5;
        const float2* tyr = (const float2*)&sm[CB + half*210];
        float a = 0.f;
        const float* w1 = fc1w + (half*210)*32 + j;
        for (int d2=0; d2<105; d2++){
            float2 tv = tyr[d2];
            a += tv.x*w1[(2*d2)*32] + tv.y*w1[(2*d2+1)*32];
        }
        a += __shfl_xor(a, 32, 64);
        a += fc1b[j];
        float r = fmaxf(a, 0.f);
        float p = r * fc3w[j];
        #pragma unroll
        for (int off=16; off>=1; off>>=1) p += __shfl_xor(p, off, 64);
        if (lane == 0) out[b] = p + fc3b[0];
    }
}

extern "C" void kernel_launch(void* const* d_in, const int* in_sizes, int n_in,
                              void* d_out, int out_size, void* d_ws, size_t ws_size,
                              hipStream_t stream) {
    const float* x      = (const float*)d_in[0];
    const float* ln_g   = (const float*)d_in[1];
    const float* ln_b   = (const float*)d_in[2];
    const float* Wup_l  = (const float*)d_in[3];
    const float* bup_l  = (const float*)d_in[4];
    const float* Wup_r  = (const float*)d_in[5];
    const float* bup_r  = (const float*)d_in[6];
    const float* conv_w = (const float*)d_in[7];
    const float* conv_b = (const float*)d_in[8];
    const float* Wq     = (const float*)d_in[9];
    const float* bq     = (const float*)d_in[10];
    const float* Wk     = (const float*)d_in[11];
    const float* bk     = (const float*)d_in[12];
    const float* Wv     = (const float*)d_in[13];
    const float* bv     = (const float*)d_in[14];
    const float* Wif    = (const float*)d_in[15];
    const float* bif    = (const float*)d_in[16];
    const float* gn_g   = (const float*)d_in[17];
    const float* gn_b   = (const float*)d_in[18];
    const float* skip   = (const float*)d_in[19];
    const float* Wdown  = (const float*)d_in[20];
    const float* bdown  = (const float*)d_in[21];
    const float* s_ln_g = (const float*)d_in[22];
    const float* s_ln_b = (const float*)d_in[23];
    const float* sW     = (const float*)d_in[24];
    const float* sR     = (const float*)d_in[25];
    const float* sb     = (const float*)d_in[26];
    const float* s_gn_g = (const float*)d_in[27];
    const float* s_gn_b = (const float*)d_in[28];
    const float* sWup1  = (const float*)d_in[29];
    const float* sbup1  = (const float*)d_in[30];
    const float* sWup2  = (const float*)d_in[31];
    const float* sbup2  = (const float*)d_in[32];
    const float* sWdown = (const float*)d_in[33];
    const float* sbdown = (const float*)d_in[34];
    const float* fc1w   = (const float*)d_in[35];
    const float* fc1b   = (const float*)d_in[36];
    const float* fc3w   = (const float*)d_in[37];
    const float* fc3b   = (const float*)d_in[38];
    float* out = (float*)d_out;

    hipLaunchKernelGGL(net_kernel, dim3(8192), dim3(64), 0, stream,
        x, ln_g, ln_b, Wup_l, bup_l, Wup_r, bup_r, conv_w, conv_b,
        Wq, bq, Wk, bk, Wv, bv, Wif, bif, gn_g, gn_b, skip, Wdown, bdown,
        s_ln_g, s_ln_b, sW, sR, sb, s_gn_g, s_gn_b,
        sWup1, sbup1, sWup2, sbup2, sWdown, sbdown,
        fc1w, fc1b, fc3w, fc3b, out);
}

// Round 7
// 133.908 us; speedup vs baseline: 2.7436x; 1.1611x over previous
//
#include <hip/hip_runtime.h>
#include <hip/hip_bf16.h>

#define SS 30
#define DD 14
#define MM 28

// LDS float offsets
#define XN   0     // 420: xn -> y_m (H)
#define UL   420   // 840 stride28: ul -> e (G)
#define CB   1260  // 840 stride28: c -> tanh(y_s) (L, first 420)
#define QH   2100  // 928: h stride29 (rows up to 31 written, 30/31 unread)
#define CF16 3028  // 640 fl = 32 rows x 40 ushort: c bf16 (byte 12112, 16B-aligned) -> UV (L0)
#define UF16 3668  // 640 fl: ul bf16 (byte 14672, 16B-aligned)
#define VV   4308  // 300: gx(240)+hs@240(60)
#define ST2  4608  // 64: gif (D1) -> G0 stats stride2 -> I stats stride2
#define EA   4672  // 32: exp(a_s), pad 30,31 = 0
#define ECM  4704  // 32: exp(-cm_t), pad = 0 -> inv (G0)
#define UV   3028
#define SMTOT 4736 // 18,944 B

#define WSYNC() asm volatile("" ::: "memory")

typedef short bshort8 __attribute__((ext_vector_type(8)));
typedef float f32x16 __attribute__((ext_vector_type(16)));

union __align__(16) FragU { unsigned int u[4]; bshort8 v; };

__device__ __forceinline__ float frcp(float v){ return __builtin_amdgcn_rcpf(v); }
__device__ __forceinline__ float frsq(float v){ return __builtin_amdgcn_rsqf(v); }
__device__ __forceinline__ float fsigm(float v){ return frcp(1.f+__expf(-v)); }
__device__ __forceinline__ float fsilu(float v){ return v*frcp(1.f+__expf(-v)); }
__device__ __forceinline__ float ftanh_(float v){
    float c = fminf(fmaxf(v, -15.f), 15.f);
    float e = __expf(2.f*c);
    return (e-1.f)*frcp(e+1.f);
}
__device__ __forceinline__ float fgelu(float v){
    float t = ftanh_(0.7978845608028654f*(v + 0.044715f*v*v*v));
    return 0.5f*v*(1.f+t);
}
__device__ __forceinline__ unsigned int pkbf(float a, float b){
    __hip_bfloat162 h = __float22bfloat162_rn(make_float2(a,b));
    return *reinterpret_cast<unsigned int*>(&h);
}
__device__ __forceinline__ unsigned short bfr(float f){
    __hip_bfloat16 h = __float2bfloat16(f);
    return *reinterpret_cast<unsigned short*>(&h);
}

// Build weight frag: lane holds W_aug[h=8*hi+r+16*slice][j=lo], W is 28x28,
// aug: row 28 = bias, rows 29..31 = 0, cols j>=28 = 0; scale folded.
__device__ __forceinline__ void load_wfrag(const float* __restrict__ W,
                                           const float* __restrict__ bias, float scale,
                                           int lo, int hi, FragU& o0, FragU& o1){
    float t[16];
    #pragma unroll
    for (int sl=0; sl<2; sl++){
        #pragma unroll
        for (int r=0;r<8;r++){
            int h = 8*hi + r + 16*sl;
            float v = 0.f;
            if (lo < MM){
                if (h < MM) v = W[h*MM+lo]*scale;
                else if (h == MM) v = bias[lo]*scale;
            }
            t[sl*8+r] = v;
        }
    }
    #pragma unroll
    for (int p=0;p<4;p++){
        o0.u[p] = pkbf(t[2*p],   t[2*p+1]);
        o1.u[p] = pkbf(t[8+2*p], t[8+2*p+1]);
    }
}

// From D-frag d (col=lo, row=(g&3)+8*(g>>2)+4*hi), build bf16 frags holding
// [lane-dim=lo][dim2 = 8*hi+r (+16 for s1)] via cvt_pk + cross-half shfl.
__device__ __forceinline__ void asm_frag(const f32x16& d, int hi, FragU& s0, FragU& s1){
    unsigned int P[8], X[8];
    #pragma unroll
    for (int m=0;m<8;m++) P[m] = pkbf(d[2*m], d[2*m+1]);
    #pragma unroll
    for (int m=0;m<8;m++) X[m] = (unsigned int)__shfl_xor((int)P[m], 32, 64);
    s0.u[0] = hi ? X[2] : P[0];  s0.u[1] = hi ? X[3] : P[1];
    s0.u[2] = hi ? P[2] : X[0];  s0.u[3] = hi ? P[3] : X[1];
    s1.u[0] = hi ? X[6] : P[4];  s1.u[1] = hi ? X[7] : P[5];
    s1.u[2] = hi ? P[6] : X[4];  s1.u[3] = hi ? P[7] : X[5];
}

extern "C" __global__ void __launch_bounds__(64)
net_kernel(const float* __restrict__ xg,
           const float* __restrict__ ln_g, const float* __restrict__ ln_b,
           const float* __restrict__ Wup_l, const float* __restrict__ bup_l,
           const float* __restrict__ Wup_r, const float* __restrict__ bup_r,
           const float* __restrict__ conv_w, const float* __restrict__ conv_b,
           const float* __restrict__ Wq, const float* __restrict__ bq,
           const float* __restrict__ Wk, const float* __restrict__ bk,
           const float* __restrict__ Wv, const float* __restrict__ bv,
           const float* __restrict__ Wif, const float* __restrict__ bif,
           const float* __restrict__ gn_g, const float* __restrict__ gn_b,
           const float* __restrict__ skip,
           const float* __restrict__ Wdown, const float* __restrict__ bdown,
           const float* __restrict__ s_ln_g, const float* __restrict__ s_ln_b,
           const float* __restrict__ sW, const float* __restrict__ sR, const float* __restrict__ sb,
           const float* __restrict__ s_gn_g, const float* __restrict__ s_gn_b,
           const float* __restrict__ sWup1, const float* __restrict__ sbup1,
           const float* __restrict__ sWup2, const float* __restrict__ sbup2,
           const float* __restrict__ sWdown, const float* __restrict__ sbdown,
           const float* __restrict__ fc1w, const float* __restrict__ fc1b,
           const float* __restrict__ fc3w, const float* __restrict__ fc3b,
           float* __restrict__ out)
{
    __shared__ __align__(16) float sm[SMTOT];
    unsigned short* smu = reinterpret_cast<unsigned short*>(sm);
    char* smc = reinterpret_cast<char*>(sm);
    const int lane = threadIdx.x;
    const int b = blockIdx.x;
    const float* xp = xg + (size_t)b * (SS*DD);

    const int lo = lane & 31, hi = lane >> 5;
    const int jq = lane % MM;
    const int gq = lane / MM;
    const bool act = lane < 56;
    const int jqi = act ? jq : 0;

    // ---- bf16 staging pads: cols 28..31 = (1,0,0,0); rows 30,31 = 0 ----
    if (lane < SS){
        *(uint2*)(smc + CF16*4 + lane*80 + 56) = make_uint2(0x3F80u, 0u);
        *(uint2*)(smc + UF16*4 + lane*80 + 56) = make_uint2(0x3F80u, 0u);
    }
    if (lane < 20){
        *(uint2*)(smc + CF16*4 + 30*80 + lane*8) = make_uint2(0u,0u);
        *(uint2*)(smc + UF16*4 + 30*80 + lane*8) = make_uint2(0u,0u);
    }

    // ---- MFMA weight frags (global loads overlap phases A-C) ----
    FragU wq0,wq1, wk0,wk1, wv0,wv1;
    const float rs28 = 0.18898223650461363f; // 1/sqrt(28)
    load_wfrag(Wq, bq, 1.f,  lo, hi, wq0, wq1);
    load_wfrag(Wk, bk, rs28, lo, hi, wk0, wk1);
    load_wfrag(Wv, bv, 1.f,  lo, hi, wv0, wv1);

    // ---- VALU weight preloads (B/C) ----
    float wl[DD], cw[4];
    float blr, cbr;
    {
        #pragma unroll
        for (int d=0; d<DD; d++) wl[d] = Wup_l[d*MM+jqi];
        #pragma unroll
        for (int k=0; k<4; k++) cw[k] = conv_w[k*MM+jqi];
        blr = bup_l[jqi]; cbr = conv_b[jqi];
    }

    // ---- Phase A: LN1 -> xn (lane = t) ----
    if (lane < SS){
        float xv[DD];
        const float2* xr = (const float2*)(xp + lane*DD);
        float s=0.f, s2=0.f;
        #pragma unroll
        for (int u=0;u<7;u++){ float2 f=xr[u]; xv[2*u]=f.x; xv[2*u+1]=f.y; s+=f.x+f.y; s2+=f.x*f.x+f.y*f.y; }
        float mu=s*(1.f/DD), var=s2*(1.f/DD)-mu*mu, rsg=frsq(var+1e-5f);
        #pragma unroll
        for (int d=0; d<DD; d++) sm[XN+lane*DD+d] = (xv[d]-mu)*rsg*ln_g[d]+ln_b[d];
    }
    WSYNC();

    // ---- Phase B: ul = xn @ Wup_l + bup_l (fp32 + bf16 copy) ----
    #pragma unroll
    for (int tt=0; tt<15; tt++){
        int t = gq*15+tt;
        if (act){
            const float2* xr = (const float2*)&sm[XN + t*DD];
            float a = blr;
            #pragma unroll
            for (int u=0;u<7;u++){ float2 f = xr[u]; a += f.x*wl[2*u] + f.y*wl[2*u+1]; }
            sm[UL + t*MM + jq] = a;
            smu[UF16*2 + t*40 + jq] = bfr(a);
        }
    }
    WSYNC();

    // ---- Phase C: causal conv + silu -> c (fp32 + bf16 copy) ----
    #pragma unroll
    for (int tt=0; tt<15; tt++){
        int t = gq*15+tt;
        if (act){
            float a = cbr;
            #pragma unroll
            for (int k=0;k<4;k++){
                int ts = t-3+k;
                if (ts>=0) a += sm[UL+ts*MM+jq]*cw[k];
            }
            float cv = fsilu(a);
            sm[CB + t*MM + jq] = cv;
            smu[CF16*2 + t*40 + jq] = bfr(cv);
        }
    }
    WSYNC();

    // ---- gif = c @ Wif + bif -> ST2 (lane<60) ----
    if (lane < SS*2){
        int t=lane>>1, gg=lane&1;
        float a = bif[gg];
        const float4* cr = (const float4*)&sm[CB+t*MM];
        #pragma unroll
        for (int h4=0;h4<7;h4++){ float4 cf=cr[h4];
            a += cf.x*Wif[(4*h4)*2+gg] + cf.y*Wif[(4*h4+1)*2+gg]
               + cf.z*Wif[(4*h4+2)*2+gg] + cf.w*Wif[(4*h4+3)*2+gg]; }
        sm[ST2+lane]=a;
    }
    WSYNC();

    // ---- D3: gate pre-scan; exp(a_s) -> EA, exp(-cm_t) -> ECM (pads 30,31 = 0) ----
    if (lane < SS){
        float i_ = sm[ST2+2*lane], f_ = sm[ST2+2*lane+1];
        float F = f_, v;
        v = __shfl_up(F,1,64);  if (lane>=1)  F += v;
        v = __shfl_up(F,2,64);  if (lane>=2)  F += v;
        v = __shfl_up(F,4,64);  if (lane>=4)  F += v;
        v = __shfl_up(F,8,64);  if (lane>=8)  F += v;
        v = __shfl_up(F,16,64); if (lane>=16) F += v;
        float a = i_ - F;
        float cm = a;
        v = __shfl_up(cm,1,64);  if (lane>=1)  cm = fmaxf(cm,v);
        v = __shfl_up(cm,2,64);  if (lane>=2)  cm = fmaxf(cm,v);
        v = __shfl_up(cm,4,64);  if (lane>=4)  cm = fmaxf(cm,v);
        v = __shfl_up(cm,8,64);  if (lane>=8)  cm = fmaxf(cm,v);
        v = __shfl_up(cm,16,64); if (lane>=16) cm = fmaxf(cm,v);
        cm = fmaxf(cm, 0.f);
        sm[EA+lane]  = __expf(a);
        sm[ECM+lane] = __expf(-cm);
    } else if (lane < 32){
        sm[EA+lane] = 0.f; sm[ECM+lane] = 0.f;
    }
    WSYNC();

    // ================= MFMA section: q,k,v + scores + PV =================
    {
        // c^T / ul frags: lane holds X[t=lo][h=8hi+r+16s]
        FragU cf0 = *(const FragU*)(smc + CF16*4 + lo*80 + hi*16);
        FragU cf1 = *(const FragU*)(smc + CF16*4 + lo*80 + hi*16 + 32);
        FragU uf0 = *(const FragU*)(smc + UF16*4 + lo*80 + hi*16);
        FragU uf1 = *(const FragU*)(smc + UF16*4 + lo*80 + hi*16 + 32);

        f32x16 aq = {}, ak = {}, av = {};
        // qT = WqAug^T @ c^T : D[col=t][row=j]
        aq = __builtin_amdgcn_mfma_f32_32x32x16_bf16(wq0.v, cf0.v, aq, 0,0,0);
        aq = __builtin_amdgcn_mfma_f32_32x32x16_bf16(wq1.v, cf1.v, aq, 0,0,0);
        ak = __builtin_amdgcn_mfma_f32_32x32x16_bf16(wk0.v, cf0.v, ak, 0,0,0);
        ak = __builtin_amdgcn_mfma_f32_32x32x16_bf16(wk1.v, cf1.v, ak, 0,0,0);
        // v = ul @ WvAug : D[col=j][row=t]
        av = __builtin_amdgcn_mfma_f32_32x32x16_bf16(uf0.v, wv0.v, av, 0,0,0);
        av = __builtin_amdgcn_mfma_f32_32x32x16_bf16(uf1.v, wv1.v, av, 0,0,0);

        // assemble q[t=lo][j-slices], k[s=lo][j-slices]
        FragU eq0, eq1, ek0, ek1;
        asm_frag(aq, hi, eq0, eq1);
        asm_frag(ak, hi, ek0, ek1);

        // ES^T = k @ q^T : D[col=t=lo][row=s]
        f32x16 es = {};
        es = __builtin_amdgcn_mfma_f32_32x32x16_bf16(ek0.v, eq0.v, es, 0,0,0);
        es = __builtin_amdgcn_mfma_f32_32x32x16_bf16(ek1.v, eq1.v, es, 0,0,0);

        // epilogue: A^T[s][t] = es * ea[s]*ecm[t] masked s<=t
        float ecmt = sm[ECM + lo];
        #pragma unroll
        for (int g=0; g<16; g++){
            int srow = (g&3) + 8*(g>>2) + 4*hi;
            float w = sm[EA + srow] * ecmt;
            es[g] = (srow <= lo) ? es[g]*w : 0.f;
        }

        // F: h = A @ V : A-frag [t=lo][s-slices], B-frag v[s][j=lo]
        FragU fa0, fa1, vb0, vb1;
        asm_frag(es, hi, fa0, fa1);
        asm_frag(av, hi, vb0, vb1);
        if (lo == MM){  // ones column j=28 -> rowsum
            const unsigned int ONE2 = 0x3F803F80u;
            vb0.u[0]=ONE2; vb0.u[1]=ONE2; vb0.u[2]=ONE2; vb0.u[3]=ONE2;
            vb1.u[0]=ONE2; vb1.u[1]=ONE2; vb1.u[2]=ONE2; vb1.u[3]= hi ? 0u : ONE2;
        }
        f32x16 hacc = {};
        hacc = __builtin_amdgcn_mfma_f32_32x32x16_bf16(fa0.v, vb0.v, hacc, 0,0,0);
        hacc = __builtin_amdgcn_mfma_f32_32x32x16_bf16(fa1.v, vb1.v, hacc, 0,0,0);

        // write h[t][j] stride29 (j=lo<29; rows 30,31 discarded by region sizing)
        #pragma unroll
        for (int g=0; g<16; g++){
            int trow = (g&3) + 8*(g>>2) + 4*hi;
            if (lo < 29) sm[QH + trow*29 + lo] = hacc[g];
        }
    }
    WSYNC();

    // ---- VALU weight preloads for G/H/L ----
    const int dq  = lane % DD;
    const int g4  = lane / DD;
    const int dqi = act ? dq : 0;
    float wr[DD], wd[MM];
    float brr, skr, ggr, gbr, bdr;
    {
        #pragma unroll
        for (int d=0;d<DD;d++) wr[d]=Wup_r[d*MM+jqi];
        #pragma unroll
        for (int i2=0;i2<MM;i2++) wd[i2]=Wdown[i2*DD+dqi];
        brr=bup_r[jqi]; skr=skip[jqi]; ggr=gn_g[jqi]; gbr=gn_b[jqi]; bdr=bdown[dqi];
    }
    float swd0 = sWdown[0*DD+dqi], swd1 = sWdown[1*DD+dqi], swd2 = sWdown[2*DD+dqi];
    float sbd  = sbdown[dqi];

    // ---- Phase G0: per-t stats (rowsum at col 28) ----
    if (lane < SS){
        float s=0.f,s2=0.f;
        #pragma unroll
        for (int u=0;u<MM;u++){ float v=sm[QH+lane*29+u]; s+=v; s2+=v*v; }
        float inv = frcp(fmaxf(fabsf(sm[QH+lane*29+MM]), 1.f));
        float mu=s*(1.f/MM), var=s2*(1.f/MM)-mu*mu;
        sm[ST2+lane*2]   = mu*inv;
        sm[ST2+lane*2+1] = frsq(var*inv*inv + 1e-5f);
        sm[ECM+lane]     = inv;   // inv (ECM dead)
    }
    WSYNC();

    // ---- Phase G: e = (hn + skip*c)*silu(ur) -> UL ----
    #pragma unroll
    for (int tt=0;tt<15;tt++){
        int t=gq*15+tt;
        if (act){
            const float2* xr = (const float2*)&sm[XN+t*DD];
            float urv = brr;
            #pragma unroll
            for (int u=0;u<7;u++){ float2 f=xr[u]; urv += f.x*wr[2*u]+f.y*wr[2*u+1]; }
            float inv = sm[ECM+t];
            float hv = sm[QH+t*29+jq]*inv;
            float hn = (hv-sm[ST2+t*2])*sm[ST2+t*2+1]*ggr + gbr;
            float h2 = hn + skr*sm[CB+t*MM+jq];
            sm[UL + t*MM + jq] = h2 * fsilu(urv);
        }
    }
    WSYNC();

    // ---- Phase H: y_m = e @ Wdown + bdown + x -> XN ----
    #pragma unroll
    for (int tt=0;tt<8;tt++){
        int t=g4*8+tt;
        if (act && t<SS){
            const float4* er=(const float4*)&sm[UL+t*MM];
            float a = bdr + xp[t*DD+dq];
            #pragma unroll
            for (int u=0;u<7;u++){ float4 f=er[u]; a += f.x*wd[4*u]+f.y*wd[4*u+1]+f.z*wd[4*u+2]+f.w*wd[4*u+3]; }
            sm[XN+t*DD+dq]=a;
        }
    }
    WSYNC();

    // ---- Phase I: sLSTM LN stats -> ST2 ----
    if (lane<SS){
        const float2* yr=(const float2*)&sm[XN+lane*DD];
        float s=0.f,s2=0.f;
        #pragma unroll
        for (int u=0;u<7;u++){ float2 f=yr[u]; s+=f.x+f.y; s2+=f.x*f.x+f.y*f.y; }
        float mu=s*(1.f/DD), var=s2*(1.f/DD)-mu*mu;
        sm[ST2+lane*2]=mu; sm[ST2+lane*2+1]=frsq(var+1e-5f);
    }
    WSYNC();

    // ---- Phase J: gx = yn @ sW + sb -> VV ----
    for (int idx=lane; idx<SS*8; idx+=64){
        int t=idx>>3, gg=idx&7;
        float a=sb[gg];
        float mu=sm[ST2+t*2], rs=sm[ST2+t*2+1];
        #pragma unroll
        for (int d=0;d<DD;d++){
            float yn=(sm[XN+t*DD+d]-mu)*rs*s_ln_g[d]+s_ln_b[d];
            a += yn*sW[d*8+gg];
        }
        sm[VV+idx]=a;
    }
    WSYNC();

    // ---- Phase K: sLSTM scan ----
    {
        float R0[8], R1[8];
        #pragma unroll
        for (int g=0; g<8; g++){ R0[g]=sR[g]; R1[g]=sR[8+g]; }
        float h0=0.f,h1=0.f,c0=0.f,c1=0.f,n0=0.f,n1=0.f,m0=0.f,m1=0.f;
        for (int t=0; t<SS; t++){
            const float2* gr = (const float2*)&sm[VV+t*8];
            float2 ga=gr[0], gb_=gr[1], gc=gr[2], gd=gr[3];
            float g0=ga.x+h0*R0[0]+h1*R1[0], g1=ga.y+h0*R0[1]+h1*R1[1];
            float g2=gb_.x+h0*R0[2]+h1*R1[2], g3=gb_.y+h0*R0[3]+h1*R1[3];
            float g4v=gc.x+h0*R0[4]+h1*R1[4], g5=gc.y+h0*R0[5]+h1*R1[5];
            float g6=gd.x+h0*R0[6]+h1*R1[6], g7=gd.y+h0*R0[7]+h1*R1[7];
            float z0=ftanh_(g0), z1=ftanh_(g1);
            float o0=fsigm(g6), o1=fsigm(g7);
            float mn0=fmaxf(g4v+m0, g2), mn1=fmaxf(g5+m1, g3);
            float ie0=__expf(g2-mn0), ie1=__expf(g3-mn1);
            float fe0=__expf(g4v+m0-mn0), fe1=__expf(g5+m1-mn1);
            c0 = fe0*c0 + ie0*z0;  c1 = fe1*c1 + ie1*z1;
            n0 = fe0*n0 + ie0;     n1 = fe1*n1 + ie1;
            h0 = o0*c0*frcp(n0);   h1 = o1*c1*frcp(n1);
            m0 = mn0; m1 = mn1;
            if (lane == 0){ sm[VV+240+t*2] = h0; sm[VV+240+t*2+1] = h1; }
        }
    }
    WSYNC();

    // ---- Phase L0: per-t u-values -> UV ----
    if (lane < SS){
        float a0 = sm[VV+240+lane*2], a1 = sm[VV+240+lane*2+1];
        float mu = 0.5f*(a0+a1);
        float d0 = a0-mu, d1 = a1-mu;
        float var = 0.5f*(d0*d0 + d1*d1);
        float rsg = frsq(var + 1e-5f);
        float hn0 = d0*rsg*s_gn_g[0] + s_gn_b[0];
        float hn1 = d1*rsg*s_gn_g[1] + s_gn_b[1];
        #pragma unroll
        for (int u3=0; u3<3; u3++){
            float p1 = hn0*sWup1[u3] + hn1*sWup1[3+u3] + sbup1[u3];
            float p2 = hn0*sWup2[u3] + hn1*sWup2[3+u3] + sbup2[u3];
            sm[UV + lane*3 + u3] = fgelu(p1)*p2;
        }
    }
    WSYNC();

    // ---- Phase L: y_s + tanh -> CB ----
    #pragma unroll
    for (int tt=0; tt<8; tt++){
        int t=g4*8+tt;
        if (act && t<SS){
            float acc = sbd + sm[XN+t*DD+dq]
                      + sm[UV+t*3]*swd0 + sm[UV+t*3+1]*swd1 + sm[UV+t*3+2]*swd2;
            sm[CB+t*DD+dq] = ftanh_(acc);
        }
    }
    WSYNC();

    // ---- Phase M: head fc1(420->32,relu) + fc3(32->1) ----
    {
        int j = lane & 31, half = lane >> 5;
        const float2* tyr = (const float2*)&sm[CB + half*210];
        float a = 0.f;
        const float* w1 = fc1w + (half*210)*32 + j;
        for (int d2=0; d2<105; d2++){
            float2 tv = tyr[d2];
            a += tv.x*w1[(2*d2)*32] + tv.y*w1[(2*d2+1)*32];
        }
        a += __shfl_xor(a, 32, 64);
        a += fc1b[j];
        float r = fmaxf(a, 0.f);
        float p = r * fc3w[j];
        #pragma unroll
        for (int off=16; off>=1; off>>=1) p += __shfl_xor(p, off, 64);
        if (lane == 0) out[b] = p + fc3b[0];
    }
}

extern "C" void kernel_launch(void* const* d_in, const int* in_sizes, int n_in,
                              void* d_out, int out_size, void* d_ws, size_t ws_size,
                              hipStream_t stream) {
    const float* x      = (const float*)d_in[0];
    const float* ln_g   = (const float*)d_in[1];
    const float* ln_b   = (const float*)d_in[2];
    const float* Wup_l  = (const float*)d_in[3];
    const float* bup_l  = (const float*)d_in[4];
    const float* Wup_r  = (const float*)d_in[5];
    const float* bup_r  = (const float*)d_in[6];
    const float* conv_w = (const float*)d_in[7];
    const float* conv_b = (const float*)d_in[8];
    const float* Wq     = (const float*)d_in[9];
    const float* bq     = (const float*)d_in[10];
    const float* Wk     = (const float*)d_in[11];
    const float* bk     = (const float*)d_in[12];
    const float* Wv     = (const float*)d_in[13];
    const float* bv     = (const float*)d_in[14];
    const float* Wif    = (const float*)d_in[15];
    const float* bif    = (const float*)d_in[16];
    const float* gn_g   = (const float*)d_in[17];
    const float* gn_b   = (const float*)d_in[18];
    const float* skip   = (const float*)d_in[19];
    const float* Wdown  = (const float*)d_in[20];
    const float* bdown  = (const float*)d_in[21];
    const float* s_ln_g = (const float*)d_in[22];
    const float* s_ln_b = (const float*)d_in[23];
    const float* sW     = (const float*)d_in[24];
    const float* sR     = (const float*)d_in[25];
    const float* sb     = (const float*)d_in[26];
    const float* s_gn_g = (const float*)d_in[27];
    const float* s_gn_b = (const float*)d_in[28];
    const float* sWup1  = (const float*)d_in[29];
    const float* sbup1  = (const float*)d_in[30];
    const float* sWup2  = (const float*)d_in[31];
    const float* sbup2  = (const float*)d_in[32];
    const float* sWdown = (const float*)d_in[33];
    const float* sbdown = (const float*)d_in[34];
    const float* fc1w   = (const float*)d_in[35];
    const float* fc1b   = (const float*)d_in[36];
    const float* fc3w   = (const float*)d_in[37];
    const float* fc3b   = (const float*)d_in[38];
    float* out = (float*)d_out;

    hipLaunchKernelGGL(net_kernel, dim3(8192), dim3(64), 0, stream,
        x, ln_g, ln_b, Wup_l, bup_l, Wup_r, bup_r, conv_w, conv_b,
        Wq, bq, Wk, bk, Wv, bv, Wif, bif, gn_g, gn_b, skip, Wdown, bdown,
        s_ln_g, s_ln_b, sW, sR, sb, s_gn_g, s_gn_b,
        sWup1, sbup1, sWup2, sbup2, sWdown, sbdown,
        fc1w, fc1b, fc3w, fc3b, out);
}

// Round 8
// 132.600 us; speedup vs baseline: 2.7707x; 1.0099x over previous
//
#include <hip/hip_runtime.h>
#include <hip/hip_bf16.h>

#define SS 30
#define DD 14
#define MM 28

// Per-batch LDS float offsets (PB = 3060 fl = 12,240 B; block = 2 batches = 24,480 B)
#define XN   0     // 420: xn -> y_m (H)
#define QH   420   // 930: h stride29 (trow up to 31 written: max idx 927)
#define CF16 1352  // 640 fl = 32 rows x 40 ushort: c bf16 (byte 5408, 16B-aligned)
#define UF16 1992  // 640 fl: ul bf16 (byte 7968, 16B-aligned) -> e bf16 (G) 
#define VV   2632  // 300: gx(240)+hs@240(60)
#define ST2  2932  // 64: gif (D1) -> G0 stats stride2 -> I stats stride2
#define EA   2996  // 32: exp(a_s), pads 30,31 = 0
#define ECM  3028  // 32: exp(-cm_t), pads = 0 -> inv (G0)
#define TY   1352  // 420 fp32 tanh(y_s) (CF16 dead after G)
#define UV   1992  // 90 (UF16 dead after H)
#define PB   3060

#define WSYNC() asm volatile("" ::: "memory")

typedef short bshort8 __attribute__((ext_vector_type(8)));
typedef float f32x16 __attribute__((ext_vector_type(16)));

union __align__(16) FragU { unsigned int u[4]; bshort8 v; };

__device__ __forceinline__ float frcp(float v){ return __builtin_amdgcn_rcpf(v); }
__device__ __forceinline__ float frsq(float v){ return __builtin_amdgcn_rsqf(v); }
__device__ __forceinline__ float fsigm(float v){ return frcp(1.f+__expf(-v)); }
__device__ __forceinline__ float fsilu(float v){ return v*frcp(1.f+__expf(-v)); }
__device__ __forceinline__ float ftanh_(float v){
    float c = fminf(fmaxf(v, -15.f), 15.f);
    float e = __expf(2.f*c);
    return (e-1.f)*frcp(e+1.f);
}
__device__ __forceinline__ float fgelu(float v){
    float t = ftanh_(0.7978845608028654f*(v + 0.044715f*v*v*v));
    return 0.5f*v*(1.f+t);
}
__device__ __forceinline__ unsigned int pkbf(float a, float b){
    __hip_bfloat162 h = __float22bfloat162_rn(make_float2(a,b));
    return *reinterpret_cast<unsigned int*>(&h);
}
__device__ __forceinline__ unsigned short bfr(float f){
    __hip_bfloat16 h = __float2bfloat16(f);
    return *reinterpret_cast<unsigned short*>(&h);
}
__device__ __forceinline__ float lobf(unsigned int u){ return __uint_as_float(u<<16); }
__device__ __forceinline__ float hibf(unsigned int u){ return __uint_as_float(u & 0xFFFF0000u); }

// Weight frag: lane holds W_aug[h=8*hi+r+16*slice][j=lo]; row 28 = bias, 29..31 = 0.
__device__ __forceinline__ void load_wfrag(const float* __restrict__ W,
                                           const float* __restrict__ bias, float scale,
                                           int lo, int hi, FragU& o0, FragU& o1){
    float t[16];
    #pragma unroll
    for (int sl=0; sl<2; sl++){
        #pragma unroll
        for (int r=0;r<8;r++){
            int h = 8*hi + r + 16*sl;
            float v = 0.f;
            if (lo < MM){
                if (h < MM) v = W[h*MM+lo]*scale;
                else if (h == MM) v = bias[lo]*scale;
            }
            t[sl*8+r] = v;
        }
    }
    #pragma unroll
    for (int p=0;p<4;p++){
        o0.u[p] = pkbf(t[2*p],   t[2*p+1]);
        o1.u[p] = pkbf(t[8+2*p], t[8+2*p+1]);
    }
}

// D-frag (col=lo, row=(g&3)+8*(g>>2)+4*hi) -> bf16 frags [lane=lo][dim2=8*hi+r(+16)]
__device__ __forceinline__ void asm_frag(const f32x16& d, int hi, FragU& s0, FragU& s1){
    unsigned int P[8], X[8];
    #pragma unroll
    for (int m=0;m<8;m++) P[m] = pkbf(d[2*m], d[2*m+1]);
    #pragma unroll
    for (int m=0;m<8;m++) X[m] = (unsigned int)__shfl_xor((int)P[m], 32, 64);
    s0.u[0] = hi ? X[2] : P[0];  s0.u[1] = hi ? X[3] : P[1];
    s0.u[2] = hi ? P[2] : X[0];  s0.u[3] = hi ? P[3] : X[1];
    s1.u[0] = hi ? X[6] : P[4];  s1.u[1] = hi ? X[7] : P[5];
    s1.u[2] = hi ? P[6] : X[4];  s1.u[3] = hi ? P[7] : X[5];
}

extern "C" __global__ void __launch_bounds__(128)
net_kernel(const float* __restrict__ xg,
           const float* __restrict__ ln_g, const float* __restrict__ ln_b,
           const float* __restrict__ Wup_l, const float* __restrict__ bup_l,
           const float* __restrict__ Wup_r, const float* __restrict__ bup_r,
           const float* __restrict__ conv_w, const float* __restrict__ conv_b,
           const float* __restrict__ Wq, const float* __restrict__ bq,
           const float* __restrict__ Wk, const float* __restrict__ bk,
           const float* __restrict__ Wv, const float* __restrict__ bv,
           const float* __restrict__ Wif, const float* __restrict__ bif,
           const float* __restrict__ gn_g, const float* __restrict__ gn_b,
           const float* __restrict__ skip,
           const float* __restrict__ Wdown, const float* __restrict__ bdown,
           const float* __restrict__ s_ln_g, const float* __restrict__ s_ln_b,
           const float* __restrict__ sW, const float* __restrict__ sR, const float* __restrict__ sb,
           const float* __restrict__ s_gn_g, const float* __restrict__ s_gn_b,
           const float* __restrict__ sWup1, const float* __restrict__ sbup1,
           const float* __restrict__ sWup2, const float* __restrict__ sbup2,
           const float* __restrict__ sWdown, const float* __restrict__ sbdown,
           const float* __restrict__ fc1w, const float* __restrict__ fc1b,
           const float* __restrict__ fc3w, const float* __restrict__ fc3b,
           float* __restrict__ out)
{
    __shared__ __align__(16) float smAll[2*PB];
    const int tid  = threadIdx.x;
    const int wid  = tid >> 6;
    const int lane = tid & 63;
    const int b = blockIdx.x*2 + wid;
    float* sm = smAll + wid*PB;
    unsigned short* smu = reinterpret_cast<unsigned short*>(sm);
    char* smc = reinterpret_cast<char*>(sm);
    const float* xp = xg + (size_t)b * (SS*DD);

    const int lo = lane & 31, hi = lane >> 5;
    const int jq = lane % MM;
    const int gq = lane / MM;
    const bool act = lane < 56;
    const int jqi = act ? jq : 0;

    // ---- bf16 staging pads: cols 28..31 = (1,0,0,0); rows 30,31 = 0 ----
    if (lane < SS){
        *(uint2*)(smc + CF16*4 + lane*80 + 56) = make_uint2(0x3F80u, 0u);
        *(uint2*)(smc + UF16*4 + lane*80 + 56) = make_uint2(0x3F80u, 0u);
    }
    if (lane < 20){
        *(uint2*)(smc + CF16*4 + 30*80 + lane*8) = make_uint2(0u,0u);
        *(uint2*)(smc + UF16*4 + 30*80 + lane*8) = make_uint2(0u,0u);
    }

    // ---- MFMA weight frags (global loads overlap phases A-C) ----
    FragU wq0,wq1, wk0,wk1, wv0,wv1;
    const float rs28 = 0.18898223650461363f; // 1/sqrt(28)
    load_wfrag(Wq, bq, 1.f,  lo, hi, wq0, wq1);
    load_wfrag(Wk, bk, rs28, lo, hi, wk0, wk1);
    load_wfrag(Wv, bv, 1.f,  lo, hi, wv0, wv1);

    // ---- VALU weight preloads (B/C) ----
    float wl[DD], cw[4];
    float blr, cbr;
    {
        #pragma unroll
        for (int d=0; d<DD; d++) wl[d] = Wup_l[d*MM+jqi];
        #pragma unroll
        for (int k=0; k<4; k++) cw[k] = conv_w[k*MM+jqi];
        blr = bup_l[jqi]; cbr = conv_b[jqi];
    }

    // ---- Phase A: LN1 -> xn (lane = t) ----
    if (lane < SS){
        float xv[DD];
        const float2* xr = (const float2*)(xp + lane*DD);
        float s=0.f, s2=0.f;
        #pragma unroll
        for (int u=0;u<7;u++){ float2 f=xr[u]; xv[2*u]=f.x; xv[2*u+1]=f.y; s+=f.x+f.y; s2+=f.x*f.x+f.y*f.y; }
        float mu=s*(1.f/DD), var=s2*(1.f/DD)-mu*mu, rsg=frsq(var+1e-5f);
        #pragma unroll
        for (int d=0; d<DD; d++) sm[XN+lane*DD+d] = (xv[d]-mu)*rsg*ln_g[d]+ln_b[d];
    }
    WSYNC();

    // ---- Phase B: ul = xn @ Wup_l + bup_l -> bf16 only ----
    #pragma unroll
    for (int tt=0; tt<15; tt++){
        int t = gq*15+tt;
        if (act){
            const float2* xr = (const float2*)&sm[XN + t*DD];
            float a = blr;
            #pragma unroll
            for (int u=0;u<7;u++){ float2 f = xr[u]; a += f.x*wl[2*u] + f.y*wl[2*u+1]; }
            smu[UF16*2 + t*40 + jq] = bfr(a);
        }
    }
    WSYNC();

    // ---- Phase C: causal conv + silu -> c bf16 only (reads bf16 ul) ----
    #pragma unroll
    for (int tt=0; tt<15; tt++){
        int t = gq*15+tt;
        if (act){
            float a = cbr;
            #pragma unroll
            for (int k=0;k<4;k++){
                int ts = t-3+k;
                if (ts>=0){
                    float ulv = lobf((unsigned int)smu[UF16*2 + ts*40 + jq]);
                    a += ulv*cw[k];
                }
            }
            smu[CF16*2 + t*40 + jq] = bfr(fsilu(a));
        }
    }
    WSYNC();

    // ---- gif = c(bf16) @ Wif + bif -> ST2 (lane<60) ----
    if (lane < SS*2){
        int t=lane>>1, gg=lane&1;
        float a = bif[gg];
        const uint2* cr = (const uint2*)(smc + CF16*4 + t*80);
        #pragma unroll
        for (int p=0;p<7;p++){
            uint2 cu = cr[p];
            a += lobf(cu.x)*Wif[(4*p)*2+gg]   + hibf(cu.x)*Wif[(4*p+1)*2+gg]
               + lobf(cu.y)*Wif[(4*p+2)*2+gg] + hibf(cu.y)*Wif[(4*p+3)*2+gg];
        }
        sm[ST2+lane]=a;
    }
    WSYNC();

    // ---- D3: gate pre-scan; exp(a_s) -> EA, exp(-cm_t) -> ECM (pads 30,31 = 0) ----
    if (lane < SS){
        float i_ = sm[ST2+2*lane], f_ = sm[ST2+2*lane+1];
        float F = f_, v;
        v = __shfl_up(F,1,64);  if (lane>=1)  F += v;
        v = __shfl_up(F,2,64);  if (lane>=2)  F += v;
        v = __shfl_up(F,4,64);  if (lane>=4)  F += v;
        v = __shfl_up(F,8,64);  if (lane>=8)  F += v;
        v = __shfl_up(F,16,64); if (lane>=16) F += v;
        float a = i_ - F;
        float cm = a;
        v = __shfl_up(cm,1,64);  if (lane>=1)  cm = fmaxf(cm,v);
        v = __shfl_up(cm,2,64);  if (lane>=2)  cm = fmaxf(cm,v);
        v = __shfl_up(cm,4,64);  if (lane>=4)  cm = fmaxf(cm,v);
        v = __shfl_up(cm,8,64);  if (lane>=8)  cm = fmaxf(cm,v);
        v = __shfl_up(cm,16,64); if (lane>=16) cm = fmaxf(cm,v);
        cm = fmaxf(cm, 0.f);
        sm[EA+lane]  = __expf(a);
        sm[ECM+lane] = __expf(-cm);
    } else if (lane < 32){
        sm[EA+lane] = 0.f; sm[ECM+lane] = 0.f;
    }
    WSYNC();

    // ================= MFMA section: q,k,v + scores + PV =================
    {
        FragU cf0 = *(const FragU*)(smc + CF16*4 + lo*80 + hi*16);
        FragU cf1 = *(const FragU*)(smc + CF16*4 + lo*80 + hi*16 + 32);
        FragU uf0 = *(const FragU*)(smc + UF16*4 + lo*80 + hi*16);
        FragU uf1 = *(const FragU*)(smc + UF16*4 + lo*80 + hi*16 + 32);

        f32x16 aq = {}, ak = {}, av = {};
        aq = __builtin_amdgcn_mfma_f32_32x32x16_bf16(wq0.v, cf0.v, aq, 0,0,0);
        aq = __builtin_amdgcn_mfma_f32_32x32x16_bf16(wq1.v, cf1.v, aq, 0,0,0);
        ak = __builtin_amdgcn_mfma_f32_32x32x16_bf16(wk0.v, cf0.v, ak, 0,0,0);
        ak = __builtin_amdgcn_mfma_f32_32x32x16_bf16(wk1.v, cf1.v, ak, 0,0,0);
        av = __builtin_amdgcn_mfma_f32_32x32x16_bf16(uf0.v, wv0.v, av, 0,0,0);
        av = __builtin_amdgcn_mfma_f32_32x32x16_bf16(uf1.v, wv1.v, av, 0,0,0);

        FragU eq0, eq1, ek0, ek1;
        asm_frag(aq, hi, eq0, eq1);
        asm_frag(ak, hi, ek0, ek1);

        f32x16 es = {};
        es = __builtin_amdgcn_mfma_f32_32x32x16_bf16(ek0.v, eq0.v, es, 0,0,0);
        es = __builtin_amdgcn_mfma_f32_32x32x16_bf16(ek1.v, eq1.v, es, 0,0,0);

        float ecmt = sm[ECM + lo];
        #pragma unroll
        for (int g=0; g<16; g++){
            int srow = (g&3) + 8*(g>>2) + 4*hi;
            float w = sm[EA + srow] * ecmt;
            es[g] = (srow <= lo) ? es[g]*w : 0.f;
        }

        FragU fa0, fa1, vb0, vb1;
        asm_frag(es, hi, fa0, fa1);
        asm_frag(av, hi, vb0, vb1);
        if (lo == MM){
            const unsigned int ONE2 = 0x3F803F80u;
            vb0.u[0]=ONE2; vb0.u[1]=ONE2; vb0.u[2]=ONE2; vb0.u[3]=ONE2;
            vb1.u[0]=ONE2; vb1.u[1]=ONE2; vb1.u[2]=ONE2; vb1.u[3]= hi ? 0u : ONE2;
        }
        f32x16 hacc = {};
        hacc = __builtin_amdgcn_mfma_f32_32x32x16_bf16(fa0.v, vb0.v, hacc, 0,0,0);
        hacc = __builtin_amdgcn_mfma_f32_32x32x16_bf16(fa1.v, vb1.v, hacc, 0,0,0);

        #pragma unroll
        for (int g=0; g<16; g++){
            int trow = (g&3) + 8*(g>>2) + 4*hi;
            if (lo < 29) sm[QH + trow*29 + lo] = hacc[g];  // QH sized 930 (trow<=31 safe)
        }
    }
    WSYNC();

    // ---- VALU weight preloads for G/H/L ----
    const int dq  = lane % DD;
    const int g4  = lane / DD;
    const int dqi = act ? dq : 0;
    float wr[DD], wd[MM];
    float brr, skr, ggr, gbr, bdr;
    {
        #pragma unroll
        for (int d=0;d<DD;d++) wr[d]=Wup_r[d*MM+jqi];
        #pragma unroll
        for (int i2=0;i2<MM;i2++) wd[i2]=Wdown[i2*DD+dqi];
        brr=bup_r[jqi]; skr=skip[jqi]; ggr=gn_g[jqi]; gbr=gn_b[jqi]; bdr=bdown[dqi];
    }
    float swd0 = sWdown[0*DD+dqi], swd1 = sWdown[1*DD+dqi], swd2 = sWdown[2*DD+dqi];
    float sbd  = sbdown[dqi];

    // ---- Phase G0: per-t stats (rowsum at col 28) ----
    if (lane < SS){
        float s=0.f,s2=0.f;
        #pragma unroll
        for (int u=0;u<MM;u++){ float v=sm[QH+lane*29+u]; s+=v; s2+=v*v; }
        float inv = frcp(fmaxf(fabsf(sm[QH+lane*29+MM]), 1.f));
        float mu=s*(1.f/MM), var=s2*(1.f/MM)-mu*mu;
        sm[ST2+lane*2]   = mu*inv;
        sm[ST2+lane*2+1] = frsq(var*inv*inv + 1e-5f);
        sm[ECM+lane]     = inv;
    }
    WSYNC();

    // ---- Phase G: e = (hn + skip*c)*silu(ur) -> e bf16 in UF16 (ul dead) ----
    #pragma unroll
    for (int tt=0;tt<15;tt++){
        int t=gq*15+tt;
        if (act){
            const float2* xr = (const float2*)&sm[XN+t*DD];
            float urv = brr;
            #pragma unroll
            for (int u=0;u<7;u++){ float2 f=xr[u]; urv += f.x*wr[2*u]+f.y*wr[2*u+1]; }
            float inv = sm[ECM+t];
            float hv = sm[QH+t*29+jq]*inv;
            float hn = (hv-sm[ST2+t*2])*sm[ST2+t*2+1]*ggr + gbr;
            float cv = lobf((unsigned int)smu[CF16*2 + t*40 + jq]);
            float h2 = hn + skr*cv;
            smu[UF16*2 + t*40 + jq] = bfr(h2 * fsilu(urv));
        }
    }
    WSYNC();

    // ---- Phase H: y_m = e(bf16) @ Wdown + bdown + x -> XN ----
    #pragma unroll
    for (int tt=0;tt<8;tt++){
        int t=g4*8+tt;
        if (act && t<SS){
            const uint2* er = (const uint2*)(smc + UF16*4 + t*80);
            float a = bdr + xp[t*DD+dq];
            #pragma unroll
            for (int p=0;p<7;p++){
                uint2 eu = er[p];
                a += lobf(eu.x)*wd[4*p]   + hibf(eu.x)*wd[4*p+1]
                   + lobf(eu.y)*wd[4*p+2] + hibf(eu.y)*wd[4*p+3];
            }
            sm[XN+t*DD+dq]=a;
        }
    }
    WSYNC();

    // ---- Phase I: sLSTM LN stats -> ST2 ----
    if (lane<SS){
        const float2* yr=(const float2*)&sm[XN+lane*DD];
        float s=0.f,s2=0.f;
        #pragma unroll
        for (int u=0;u<7;u++){ float2 f=yr[u]; s+=f.x+f.y; s2+=f.x*f.x+f.y*f.y; }
        float mu=s*(1.f/DD), var=s2*(1.f/DD)-mu*mu;
        sm[ST2+lane*2]=mu; sm[ST2+lane*2+1]=frsq(var+1e-5f);
    }
    WSYNC();

    // ---- Phase J: gx = yn @ sW + sb -> VV ----
    for (int idx=lane; idx<SS*8; idx+=64){
        int t=idx>>3, gg=idx&7;
        float a=sb[gg];
        float mu=sm[ST2+t*2], rs=sm[ST2+t*2+1];
        #pragma unroll
        for (int d=0;d<DD;d++){
            float yn=(sm[XN+t*DD+d]-mu)*rs*s_ln_g[d]+s_ln_b[d];
            a += yn*sW[d*8+gg];
        }
        sm[VV+idx]=a;
    }
    WSYNC();

    // ---- Phase K: sLSTM scan ----
    {
        float R0[8], R1[8];
        #pragma unroll
        for (int g=0; g<8; g++){ R0[g]=sR[g]; R1[g]=sR[8+g]; }
        float h0=0.f,h1=0.f,c0=0.f,c1=0.f,n0=0.f,n1=0.f,m0=0.f,m1=0.f;
        for (int t=0; t<SS; t++){
            const float2* gr = (const float2*)&sm[VV+t*8];
            float2 ga=gr[0], gb_=gr[1], gc=gr[2], gd=gr[3];
            float g0=ga.x+h0*R0[0]+h1*R1[0], g1=ga.y+h0*R0[1]+h1*R1[1];
            float g2=gb_.x+h0*R0[2]+h1*R1[2], g3=gb_.y+h0*R0[3]+h1*R1[3];
            float g4v=gc.x+h0*R0[4]+h1*R1[4], g5=gc.y+h0*R0[5]+h1*R1[5];
            float g6=gd.x+h0*R0[6]+h1*R1[6], g7=gd.y+h0*R0[7]+h1*R1[7];
            float z0=ftanh_(g0), z1=ftanh_(g1);
            float o0=fsigm(g6), o1=fsigm(g7);
            float mn0=fmaxf(g4v+m0, g2), mn1=fmaxf(g5+m1, g3);
            float ie0=__expf(g2-mn0), ie1=__expf(g3-mn1);
            float fe0=__expf(g4v+m0-mn0), fe1=__expf(g5+m1-mn1);
            c0 = fe0*c0 + ie0*z0;  c1 = fe1*c1 + ie1*z1;
            n0 = fe0*n0 + ie0;     n1 = fe1*n1 + ie1;
            h0 = o0*c0*frcp(n0);   h1 = o1*c1*frcp(n1);
            m0 = mn0; m1 = mn1;
            if (lane == 0){ sm[VV+240+t*2] = h0; sm[VV+240+t*2+1] = h1; }
        }
    }
    WSYNC();

    // ---- Phase L0: per-t u-values -> UV (UF16 dead) ----
    if (lane < SS){
        float a0 = sm[VV+240+lane*2], a1 = sm[VV+240+lane*2+1];
        float mu = 0.5f*(a0+a1);
        float d0 = a0-mu, d1 = a1-mu;
        float var = 0.5f*(d0*d0 + d1*d1);
        float rsg = frsq(var + 1e-5f);
        float hn0 = d0*rsg*s_gn_g[0] + s_gn_b[0];
        float hn1 = d1*rsg*s_gn_g[1] + s_gn_b[1];
        #pragma unroll
        for (int u3=0; u3<3; u3++){
            float p1 = hn0*sWup1[u3] + hn1*sWup1[3+u3] + sbup1[u3];
            float p2 = hn0*sWup2[u3] + hn1*sWup2[3+u3] + sbup2[u3];
            sm[UV + lane*3 + u3] = fgelu(p1)*p2;
        }
    }
    WSYNC();

    // ---- Phase L: y_s + tanh -> TY (CF16 dead) ----
    #pragma unroll
    for (int tt=0; tt<8; tt++){
        int t=g4*8+tt;
        if (act && t<SS){
            float acc = sbd + sm[XN+t*DD+dq]
                      + sm[UV+t*3]*swd0 + sm[UV+t*3+1]*swd1 + sm[UV+t*3+2]*swd2;
            sm[TY+t*DD+dq] = ftanh_(acc);
        }
    }
    WSYNC();

    // ---- Phase M: head fc1(420->32,relu) + fc3(32->1) ----
    {
        int j = lane & 31, half = lane >> 5;
        const float2* tyr = (const float2*)&sm[TY + half*210];
        float a = 0.f;
        const float* w1 = fc1w + (half*210)*32 + j;
        for (int d2=0; d2<105; d2++){
            float2 tv = tyr[d2];
            a += tv.x*w1[(2*d2)*32] + tv.y*w1[(2*d2+1)*32];
        }
        a += __shfl_xor(a, 32, 64);
        a += fc1b[j];
        float r = fmaxf(a, 0.f);
        float p = r * fc3w[j];
        #pragma unroll
        for (int off=16; off>=1; off>>=1) p += __shfl_xor(p, off, 64);
        if (lane == 0) out[b] = p + fc3b[0];
    }
}

extern "C" void kernel_launch(void* const* d_in, const int* in_sizes, int n_in,
                              void* d_out, int out_size, void* d_ws, size_t ws_size,
                              hipStream_t stream) {
    const float* x      = (const float*)d_in[0];
    const float* ln_g   = (const float*)d_in[1];
    const float* ln_b   = (const float*)d_in[2];
    const float* Wup_l  = (const float*)d_in[3];
    const float* bup_l  = (const float*)d_in[4];
    const float* Wup_r  = (const float*)d_in[5];
    const float* bup_r  = (const float*)d_in[6];
    const float* conv_w = (const float*)d_in[7];
    const float* conv_b = (const float*)d_in[8];
    const float* Wq     = (const float*)d_in[9];
    const float* bq     = (const float*)d_in[10];
    const float* Wk     = (const float*)d_in[11];
    const float* bk     = (const float*)d_in[12];
    const float* Wv     = (const float*)d_in[13];
    const float* bv     = (const float*)d_in[14];
    const float* Wif    = (const float*)d_in[15];
    const float* bif    = (const float*)d_in[16];
    const float* gn_g   = (const float*)d_in[17];
    const float* gn_b   = (const float*)d_in[18];
    const float* skip   = (const float*)d_in[19];
    const float* Wdown  = (const float*)d_in[20];
    const float* bdown  = (const float*)d_in[21];
    const float* s_ln_g = (const float*)d_in[22];
    const float* s_ln_b = (const float*)d_in[23];
    const float* sW     = (const float*)d_in[24];
    const float* sR     = (const float*)d_in[25];
    const float* sb     = (const float*)d_in[26];
    const float* s_gn_g = (const float*)d_in[27];
    const float* s_gn_b = (const float*)d_in[28];
    const float* sWup1  = (const float*)d_in[29];
    const float* sbup1  = (const float*)d_in[30];
    const float* sWup2  = (const float*)d_in[31];
    const float* sbup2  = (const float*)d_in[32];
    const float* sWdown = (const float*)d_in[33];
    const float* sbdown = (const float*)d_in[34];
    const float* fc1w   = (const float*)d_in[35];
    const float* fc1b   = (const float*)d_in[36];
    const float* fc3w   = (const float*)d_in[37];
    const float* fc3b   = (const float*)d_in[38];
    float* out = (float*)d_out;

    hipLaunchKernelGGL(net_kernel, dim3(4096), dim3(128), 0, stream,
        x, ln_g, ln_b, Wup_l, bup_l, Wup_r, bup_r, conv_w, conv_b,
        Wq, bq, Wk, bk, Wv, bv, Wif, bif, gn_g, gn_b, skip, Wdown, bdown,
        s_ln_g, s_ln_b, sW, sR, sb, s_gn_g, s_gn_b,
        sWup1, sbup1, sWup2, sbup2, sWdown, sbdown,
        fc1w, fc1b, fc3w, fc3b, out);
}

// Round 9
// 132.360 us; speedup vs baseline: 2.7757x; 1.0018x over previous
//
#include <hip/hip_runtime.h>
#include <hip/hip_bf16.h>

#define SS 30
#define DD 14
#define MM 28

// Per-batch LDS float offsets (PB = 3060 fl = 12,240 B; block = 2 batches = 24,480 B)
#define XN   0     // 420: xn -> y_m (H)
#define QH   420   // 930: h stride29 (trow<=31 writes: max 420+31*29+28=1347 < 1352)
#define CF16 1352  // 640 fl = 32 rows x 40 ushort: c bf16 -> TY (L)
#define UF16 1992  // 640 fl: ul bf16 -> e bf16 (G) -> UV (L0)
#define VV   2632  // 300: gx(240)+hs@240(60)
#define ST2  2932  // 64: gif (D1) -> G0 stats stride2 -> I stats stride2
#define EA   2996  // 32: exp(a_s), pads 30,31 = 0
#define ECM  3028  // 32: exp(-cm_t), pads = 0 -> inv (G0)
#define TY   1352  // 420 fp32 tanh(y_s)
#define UV   1992  // 90
#define PB   3060

#define WSYNC() asm volatile("" ::: "memory")

typedef short bshort8 __attribute__((ext_vector_type(8)));
typedef float f32x16 __attribute__((ext_vector_type(16)));

union __align__(16) FragU { unsigned int u[4]; bshort8 v; };

__device__ __forceinline__ float frcp(float v){ return __builtin_amdgcn_rcpf(v); }
__device__ __forceinline__ float frsq(float v){ return __builtin_amdgcn_rsqf(v); }
__device__ __forceinline__ float fsigm(float v){ return frcp(1.f+__expf(-v)); }
__device__ __forceinline__ float fsilu(float v){ return v*frcp(1.f+__expf(-v)); }
__device__ __forceinline__ float ftanh_(float v){
    float c = fminf(fmaxf(v, -15.f), 15.f);
    float e = __expf(2.f*c);
    return (e-1.f)*frcp(e+1.f);
}
__device__ __forceinline__ float fgelu(float v){
    float t = ftanh_(0.7978845608028654f*(v + 0.044715f*v*v*v));
    return 0.5f*v*(1.f+t);
}
__device__ __forceinline__ unsigned int pkbf(float a, float b){
    __hip_bfloat162 h = __float22bfloat162_rn(make_float2(a,b));
    return *reinterpret_cast<unsigned int*>(&h);
}
__device__ __forceinline__ unsigned short bfr(float f){
    __hip_bfloat16 h = __float2bfloat16(f);
    return *reinterpret_cast<unsigned short*>(&h);
}
__device__ __forceinline__ float lobf(unsigned int u){ return __uint_as_float(u<<16); }
__device__ __forceinline__ float hibf(unsigned int u){ return __uint_as_float(u & 0xFFFF0000u); }

// Weight frag: lane holds W_aug[h=8*hi+r+16*slice][j=lo]; W is 28 x ncol;
// aug row 28 = bias, rows 29..31 = 0; cols >= ncol = 0; scale folded.
__device__ __forceinline__ void load_wfrag(const float* __restrict__ W,
                                           const float* __restrict__ bias, float scale,
                                           int ncol, int lo, int hi, FragU& o0, FragU& o1){
    float t[16];
    #pragma unroll
    for (int sl=0; sl<2; sl++){
        #pragma unroll
        for (int r=0;r<8;r++){
            int h = 8*hi + r + 16*sl;
            float v = 0.f;
            if (lo < ncol){
                if (h < MM) v = W[h*ncol+lo]*scale;
                else if (h == MM) v = bias[lo]*scale;
            }
            t[sl*8+r] = v;
        }
    }
    #pragma unroll
    for (int p=0;p<4;p++){
        o0.u[p] = pkbf(t[2*p],   t[2*p+1]);
        o1.u[p] = pkbf(t[8+2*p], t[8+2*p+1]);
    }
}

// D-frag (col=lo, row=(g&3)+8*(g>>2)+4*hi) -> bf16 frags [lane=lo][dim2=8*hi+r(+16)]
__device__ __forceinline__ void asm_frag(const f32x16& d, int hi, FragU& s0, FragU& s1){
    unsigned int P[8], X[8];
    #pragma unroll
    for (int m=0;m<8;m++) P[m] = pkbf(d[2*m], d[2*m+1]);
    #pragma unroll
    for (int m=0;m<8;m++) X[m] = (unsigned int)__shfl_xor((int)P[m], 32, 64);
    s0.u[0] = hi ? X[2] : P[0];  s0.u[1] = hi ? X[3] : P[1];
    s0.u[2] = hi ? P[2] : X[0];  s0.u[3] = hi ? P[3] : X[1];
    s1.u[0] = hi ? X[6] : P[4];  s1.u[1] = hi ? X[7] : P[5];
    s1.u[2] = hi ? P[6] : X[4];  s1.u[3] = hi ? P[7] : X[5];
}

extern "C" __global__ void __launch_bounds__(64)
net_kernel(const float* __restrict__ xg,
           const float* __restrict__ ln_g, const float* __restrict__ ln_b,
           const float* __restrict__ Wup_l, const float* __restrict__ bup_l,
           const float* __restrict__ Wup_r, const float* __restrict__ bup_r,
           const float* __restrict__ conv_w, const float* __restrict__ conv_b,
           const float* __restrict__ Wq, const float* __restrict__ bq,
           const float* __restrict__ Wk, const float* __restrict__ bk,
           const float* __restrict__ Wv, const float* __restrict__ bv,
           const float* __restrict__ Wif, const float* __restrict__ bif,
           const float* __restrict__ gn_g, const float* __restrict__ gn_b,
           const float* __restrict__ skip,
           const float* __restrict__ Wdown, const float* __restrict__ bdown,
           const float* __restrict__ s_ln_g, const float* __restrict__ s_ln_b,
           const float* __restrict__ sW, const float* __restrict__ sR, const float* __restrict__ sb,
           const float* __restrict__ s_gn_g, const float* __restrict__ s_gn_b,
           const float* __restrict__ sWup1, const float* __restrict__ sbup1,
           const float* __restrict__ sWup2, const float* __restrict__ sbup2,
           const float* __restrict__ sWdown, const float* __restrict__ sbdown,
           const float* __restrict__ fc1w, const float* __restrict__ fc1b,
           const float* __restrict__ fc3w, const float* __restrict__ fc3b,
           float* __restrict__ out)
{
    __shared__ __align__(16) float smAll[2*PB];
    const int lane = threadIdx.x;
    const int b0 = blockIdx.x*2;
    const float* xp0 = xg + (size_t)b0 * (SS*DD);
    const float* xp1 = xp0 + SS*DD;

    const int lo = lane & 31, hi = lane >> 5;
    const int il = lane & 31;        // in-group lane for batch-split phases
    const int bbD = lane >> 5;       // batch selector for split phases
    float* smD = smAll + bbD*PB;
    const int jq = lane % MM;
    const int gq = lane / MM;
    const bool act = lane < 56;
    const int jqi = act ? jq : 0;

    // ---- bf16 staging pads, both batches: cols 28..31=(1,0,0,0); rows 30,31=0 ----
    if (lane < 60){
        int bb = lane >= 30; int t = lane - bb*30;
        char* smc = (char*)(smAll + bb*PB);
        *(uint2*)(smc + CF16*4 + t*80 + 56) = make_uint2(0x3F80u, 0u);
        *(uint2*)(smc + UF16*4 + t*80 + 56) = make_uint2(0x3F80u, 0u);
    }
    if (lane < 40){
        int bb = lane >= 20; int i = lane - bb*20;
        char* smc = (char*)(smAll + bb*PB);
        *(uint2*)(smc + CF16*4 + 30*80 + i*8) = make_uint2(0u,0u);
        *(uint2*)(smc + UF16*4 + 30*80 + i*8) = make_uint2(0u,0u);
    }

    // ---- MFMA weight frags (shared across both batches) ----
    FragU wq0,wq1, wk0,wk1, wv0,wv1, wd0,wd1;
    const float rs28 = 0.18898223650461363f; // 1/sqrt(28)
    load_wfrag(Wq, bq, 1.f,  MM, lo, hi, wq0, wq1);
    load_wfrag(Wk, bk, rs28, MM, lo, hi, wk0, wk1);
    load_wfrag(Wv, bv, 1.f,  MM, lo, hi, wv0, wv1);
    load_wfrag(Wdown, bdown, 1.f, DD, lo, hi, wd0, wd1);

    // ---- VALU weight preloads (B/C) ----
    float wl[DD], cw[4];
    float blr, cbr;
    {
        #pragma unroll
        for (int d=0; d<DD; d++) wl[d] = Wup_l[d*MM+jqi];
        #pragma unroll
        for (int k=0; k<4; k++) cw[k] = conv_w[k*MM+jqi];
        blr = bup_l[jqi]; cbr = conv_b[jqi];
    }

    // ---- Phase A: LN1 -> xn (lane<60: (bb,t)) ----
    if (lane < 60){
        int bb = lane >= 30; int t = lane - bb*30;
        float* sm = smAll + bb*PB;
        const float2* xr = (const float2*)((bb? xp1:xp0) + t*DD);
        float xv[DD];
        float s=0.f, s2=0.f;
        #pragma unroll
        for (int u=0;u<7;u++){ float2 f=xr[u]; xv[2*u]=f.x; xv[2*u+1]=f.y; s+=f.x+f.y; s2+=f.x*f.x+f.y*f.y; }
        float mu=s*(1.f/DD), var=s2*(1.f/DD)-mu*mu, rsg=frsq(var+1e-5f);
        #pragma unroll
        for (int d=0; d<DD; d++) sm[XN+t*DD+d] = (xv[d]-mu)*rsg*ln_g[d]+ln_b[d];
    }
    WSYNC();

    // ---- Phase B: ul = xn @ Wup_l + bup_l -> bf16 (both batches) ----
    #pragma unroll
    for (int bb=0; bb<2; bb++){
        float* sm = smAll + bb*PB;
        unsigned short* smu = (unsigned short*)sm;
        #pragma unroll
        for (int tt=0; tt<15; tt++){
            int t = gq*15+tt;
            if (act){
                const float2* xr = (const float2*)&sm[XN + t*DD];
                float a = blr;
                #pragma unroll
                for (int u=0;u<7;u++){ float2 f = xr[u]; a += f.x*wl[2*u] + f.y*wl[2*u+1]; }
                smu[UF16*2 + t*40 + jq] = bfr(a);
            }
        }
    }
    WSYNC();

    // ---- Phase C: causal conv + silu -> c bf16 (both batches) ----
    #pragma unroll
    for (int bb=0; bb<2; bb++){
        unsigned short* smu = (unsigned short*)(smAll + bb*PB);
        #pragma unroll
        for (int tt=0; tt<15; tt++){
            int t = gq*15+tt;
            if (act){
                float a = cbr;
                #pragma unroll
                for (int k=0;k<4;k++){
                    int ts = t-3+k;
                    if (ts>=0) a += lobf((unsigned int)smu[UF16*2 + ts*40 + jq])*cw[k];
                }
                smu[CF16*2 + t*40 + jq] = bfr(fsilu(a));
            }
        }
    }
    WSYNC();

    // ---- gif = c(bf16) @ Wif + bif -> ST2 (both batches) ----
    #pragma unroll
    for (int bb=0; bb<2; bb++){
        float* sm = smAll + bb*PB;
        char* smc = (char*)sm;
        if (lane < SS*2){
            int t=lane>>1, gg=lane&1;
            float a = bif[gg];
            const uint2* cr = (const uint2*)(smc + CF16*4 + t*80);
            #pragma unroll
            for (int p=0;p<7;p++){
                uint2 cu = cr[p];
                a += lobf(cu.x)*Wif[(4*p)*2+gg]   + hibf(cu.x)*Wif[(4*p+1)*2+gg]
                   + lobf(cu.y)*Wif[(4*p+2)*2+gg] + hibf(cu.y)*Wif[(4*p+3)*2+gg];
            }
            sm[ST2+lane]=a;
        }
    }
    WSYNC();

    // ---- D3: gate pre-scan (lanes 0-31: batch0, 32-63: batch1; width-32 shuffles) ----
    if (il < SS){
        float i_ = smD[ST2+2*il], f_ = smD[ST2+2*il+1];
        float F = f_, v;
        v = __shfl_up(F,1,32);  if (il>=1)  F += v;
        v = __shfl_up(F,2,32);  if (il>=2)  F += v;
        v = __shfl_up(F,4,32);  if (il>=4)  F += v;
        v = __shfl_up(F,8,32);  if (il>=8)  F += v;
        v = __shfl_up(F,16,32); if (il>=16) F += v;
        float a = i_ - F;
        float cm = a;
        v = __shfl_up(cm,1,32);  if (il>=1)  cm = fmaxf(cm,v);
        v = __shfl_up(cm,2,32);  if (il>=2)  cm = fmaxf(cm,v);
        v = __shfl_up(cm,4,32);  if (il>=4)  cm = fmaxf(cm,v);
        v = __shfl_up(cm,8,32);  if (il>=8)  cm = fmaxf(cm,v);
        v = __shfl_up(cm,16,32); if (il>=16) cm = fmaxf(cm,v);
        cm = fmaxf(cm, 0.f);
        smD[EA+il]  = __expf(a);
        smD[ECM+il] = __expf(-cm);
    } else {
        smD[EA+il] = 0.f; smD[ECM+il] = 0.f;
    }
    WSYNC();

    // ================= MFMA section: q,k,v + scores + PV (per batch) =========
    #pragma unroll
    for (int bb=0; bb<2; bb++){
        float* sm = smAll + bb*PB;
        char* smc = (char*)sm;
        FragU cf0 = *(const FragU*)(smc + CF16*4 + lo*80 + hi*16);
        FragU cf1 = *(const FragU*)(smc + CF16*4 + lo*80 + hi*16 + 32);
        FragU uf0 = *(const FragU*)(smc + UF16*4 + lo*80 + hi*16);
        FragU uf1 = *(const FragU*)(smc + UF16*4 + lo*80 + hi*16 + 32);

        f32x16 aq = {}, ak = {}, av = {};
        aq = __builtin_amdgcn_mfma_f32_32x32x16_bf16(wq0.v, cf0.v, aq, 0,0,0);
        aq = __builtin_amdgcn_mfma_f32_32x32x16_bf16(wq1.v, cf1.v, aq, 0,0,0);
        ak = __builtin_amdgcn_mfma_f32_32x32x16_bf16(wk0.v, cf0.v, ak, 0,0,0);
        ak = __builtin_amdgcn_mfma_f32_32x32x16_bf16(wk1.v, cf1.v, ak, 0,0,0);
        av = __builtin_amdgcn_mfma_f32_32x32x16_bf16(uf0.v, wv0.v, av, 0,0,0);
        av = __builtin_amdgcn_mfma_f32_32x32x16_bf16(uf1.v, wv1.v, av, 0,0,0);

        FragU eq0, eq1, ek0, ek1;
        asm_frag(aq, hi, eq0, eq1);
        asm_frag(ak, hi, ek0, ek1);

        f32x16 es = {};
        es = __builtin_amdgcn_mfma_f32_32x32x16_bf16(ek0.v, eq0.v, es, 0,0,0);
        es = __builtin_amdgcn_mfma_f32_32x32x16_bf16(ek1.v, eq1.v, es, 0,0,0);

        float ecmt = sm[ECM + lo];
        #pragma unroll
        for (int g=0; g<16; g++){
            int srow = (g&3) + 8*(g>>2) + 4*hi;
            float w = sm[EA + srow] * ecmt;
            es[g] = (srow <= lo) ? es[g]*w : 0.f;
        }

        FragU fa0, fa1, vb0, vb1;
        asm_frag(es, hi, fa0, fa1);
        asm_frag(av, hi, vb0, vb1);
        if (lo == MM){
            const unsigned int ONE2 = 0x3F803F80u;
            vb0.u[0]=ONE2; vb0.u[1]=ONE2; vb0.u[2]=ONE2; vb0.u[3]=ONE2;
            vb1.u[0]=ONE2; vb1.u[1]=ONE2; vb1.u[2]=ONE2; vb1.u[3]= hi ? 0u : ONE2;
        }
        f32x16 hacc = {};
        hacc = __builtin_amdgcn_mfma_f32_32x32x16_bf16(fa0.v, vb0.v, hacc, 0,0,0);
        hacc = __builtin_amdgcn_mfma_f32_32x32x16_bf16(fa1.v, vb1.v, hacc, 0,0,0);

        #pragma unroll
        for (int g=0; g<16; g++){
            int trow = (g&3) + 8*(g>>2) + 4*hi;
            if (lo < 29) sm[QH + trow*29 + lo] = hacc[g];
        }
    }
    WSYNC();

    // ---- VALU weight preloads for G/L ----
    const int dq  = lane % DD;
    const int g4  = lane / DD;
    const int dqi = act ? dq : 0;
    float wr[DD];
    float brr, skr, ggr, gbr;
    {
        #pragma unroll
        for (int d=0;d<DD;d++) wr[d]=Wup_r[d*MM+jqi];
        brr=bup_r[jqi]; skr=skip[jqi]; ggr=gn_g[jqi]; gbr=gn_b[jqi];
    }
    float swd0 = sWdown[0*DD+dqi], swd1 = sWdown[1*DD+dqi], swd2 = sWdown[2*DD+dqi];
    float sbd  = sbdown[dqi];

    // ---- Phase G0: per-t stats (split: il<30, bbD) ----
    if (il < SS){
        float s=0.f,s2=0.f;
        #pragma unroll
        for (int u=0;u<MM;u++){ float v=smD[QH+il*29+u]; s+=v; s2+=v*v; }
        float inv = frcp(fmaxf(fabsf(smD[QH+il*29+MM]), 1.f));
        float mu=s*(1.f/MM), var=s2*(1.f/MM)-mu*mu;
        smD[ST2+il*2]   = mu*inv;
        smD[ST2+il*2+1] = frsq(var*inv*inv + 1e-5f);
        smD[ECM+il]     = inv;
    }
    WSYNC();

    // ---- Phase G: e = (hn + skip*c)*silu(ur) -> e bf16 in UF16 (both batches) ----
    #pragma unroll
    for (int bb=0; bb<2; bb++){
        float* sm = smAll + bb*PB;
        unsigned short* smu = (unsigned short*)sm;
        #pragma unroll
        for (int tt=0;tt<15;tt++){
            int t=gq*15+tt;
            if (act){
                const float2* xr = (const float2*)&sm[XN+t*DD];
                float urv = brr;
                #pragma unroll
                for (int u=0;u<7;u++){ float2 f=xr[u]; urv += f.x*wr[2*u]+f.y*wr[2*u+1]; }
                float inv = sm[ECM+t];
                float hv = sm[QH+t*29+jq]*inv;
                float hn = (hv-sm[ST2+t*2])*sm[ST2+t*2+1]*ggr + gbr;
                float cv = lobf((unsigned int)smu[CF16*2 + t*40 + jq]);
                float h2 = hn + skr*cv;
                smu[UF16*2 + t*40 + jq] = bfr(h2 * fsilu(urv));
            }
        }
    }
    WSYNC();

    // ---- Phase H (MFMA): y_m = e @ WdownAug + x -> XN (both batches) ----
    #pragma unroll
    for (int bb=0; bb<2; bb++){
        float* sm = smAll + bb*PB;
        char* smc = (char*)sm;
        const float* xp = bb ? xp1 : xp0;
        FragU ef0 = *(const FragU*)(smc + UF16*4 + lo*80 + hi*16);
        FragU ef1 = *(const FragU*)(smc + UF16*4 + lo*80 + hi*16 + 32);
        f32x16 ym = {};
        ym = __builtin_amdgcn_mfma_f32_32x32x16_bf16(ef0.v, wd0.v, ym, 0,0,0);
        ym = __builtin_amdgcn_mfma_f32_32x32x16_bf16(ef1.v, wd1.v, ym, 0,0,0);
        #pragma unroll
        for (int g=0; g<16; g++){
            int trow = (g&3) + 8*(g>>2) + 4*hi;
            if (lo < DD && trow < SS) sm[XN + trow*DD + lo] = ym[g] + xp[trow*DD + lo];
        }
    }
    WSYNC();

    // ---- Phase I: sLSTM LN stats (split: il<30, bbD) ----
    if (il < SS){
        const float2* yr=(const float2*)&smD[XN+il*DD];
        float s=0.f,s2=0.f;
        #pragma unroll
        for (int u=0;u<7;u++){ float2 f=yr[u]; s+=f.x+f.y; s2+=f.x*f.x+f.y*f.y; }
        float mu=s*(1.f/DD), var=s2*(1.f/DD)-mu*mu;
        smD[ST2+il*2]=mu; smD[ST2+il*2+1]=frsq(var+1e-5f);
    }
    WSYNC();

    // ---- Phase J: gx = yn @ sW + sb -> VV (both batches) ----
    #pragma unroll
    for (int bb=0; bb<2; bb++){
        float* sm = smAll + bb*PB;
        for (int idx=lane; idx<SS*8; idx+=64){
            int t=idx>>3, gg=idx&7;
            float a=sb[gg];
            float mu=sm[ST2+t*2], rs=sm[ST2+t*2+1];
            #pragma unroll
            for (int d=0;d<DD;d++){
                float yn=(sm[XN+t*DD+d]-mu)*rs*s_ln_g[d]+s_ln_b[d];
                a += yn*sW[d*8+gg];
            }
            sm[VV+idx]=a;
        }
    }
    WSYNC();

    // ---- Phase K: sLSTM scan (lanes 0-31: batch0, 32-63: batch1) ----
    {
        float R0[8], R1[8];
        #pragma unroll
        for (int g=0; g<8; g++){ R0[g]=sR[g]; R1[g]=sR[8+g]; }
        float h0=0.f,h1=0.f,c0=0.f,c1=0.f,n0=0.f,n1=0.f,m0=0.f,m1=0.f;
        for (int t=0; t<SS; t++){
            const float2* gr = (const float2*)&smD[VV+t*8];
            float2 ga=gr[0], gb_=gr[1], gc=gr[2], gd=gr[3];
            float g0=ga.x+h0*R0[0]+h1*R1[0], g1=ga.y+h0*R0[1]+h1*R1[1];
            float g2=gb_.x+h0*R0[2]+h1*R1[2], g3=gb_.y+h0*R0[3]+h1*R1[3];
            float g4v=gc.x+h0*R0[4]+h1*R1[4], g5=gc.y+h0*R0[5]+h1*R1[5];
            float g6=gd.x+h0*R0[6]+h1*R1[6], g7=gd.y+h0*R0[7]+h1*R1[7];
            float z0=ftanh_(g0), z1=ftanh_(g1);
            float o0=fsigm(g6), o1=fsigm(g7);
            float mn0=fmaxf(g4v+m0, g2), mn1=fmaxf(g5+m1, g3);
            float ie0=__expf(g2-mn0), ie1=__expf(g3-mn1);
            float fe0=__expf(g4v+m0-mn0), fe1=__expf(g5+m1-mn1);
            c0 = fe0*c0 + ie0*z0;  c1 = fe1*c1 + ie1*z1;
            n0 = fe0*n0 + ie0;     n1 = fe1*n1 + ie1;
            h0 = o0*c0*frcp(n0);   h1 = o1*c1*frcp(n1);
            m0 = mn0; m1 = mn1;
            if (il == 0){ smD[VV+240+t*2] = h0; smD[VV+240+t*2+1] = h1; }
        }
    }
    WSYNC();

    // ---- Phase L0: per-t u-values -> UV (split: il<30, bbD) ----
    if (il < SS){
        float a0 = smD[VV+240+il*2], a1 = smD[VV+240+il*2+1];
        float mu = 0.5f*(a0+a1);
        float d0 = a0-mu, d1 = a1-mu;
        float var = 0.5f*(d0*d0 + d1*d1);
        float rsg = frsq(var + 1e-5f);
        float hn0 = d0*rsg*s_gn_g[0] + s_gn_b[0];
        float hn1 = d1*rsg*s_gn_g[1] + s_gn_b[1];
        #pragma unroll
        for (int u3=0; u3<3; u3++){
            float p1 = hn0*sWup1[u3] + hn1*sWup1[3+u3] + sbup1[u3];
            float p2 = hn0*sWup2[u3] + hn1*sWup2[3+u3] + sbup2[u3];
            smD[UV + il*3 + u3] = fgelu(p1)*p2;
        }
    }
    WSYNC();

    // ---- Phase L: y_s + tanh -> TY (both batches) ----
    #pragma unroll
    for (int bb=0; bb<2; bb++){
        float* sm = smAll + bb*PB;
        #pragma unroll
        for (int tt=0; tt<8; tt++){
            int t=g4*8+tt;
            if (act && t<SS){
                float acc = sbd + sm[XN+t*DD+dq]
                          + sm[UV+t*3]*swd0 + sm[UV+t*3+1]*swd1 + sm[UV+t*3+2]*swd2;
                sm[TY+t*DD+dq] = ftanh_(acc);
            }
        }
    }
    WSYNC();

    // ---- Phase M: head fc1+fc3, fc1w loads shared across both batches ----
    {
        int j = lane & 31, half = lane >> 5;
        const float2* ty0 = (const float2*)&smAll[TY + half*210];
        const float2* ty1 = (const float2*)&smAll[PB + TY + half*210];
        float a0 = 0.f, a1 = 0.f;
        const float* w1 = fc1w + (half*210)*32 + j;
        for (int d2=0; d2<105; d2++){
            float wa = w1[(2*d2)*32], wb = w1[(2*d2+1)*32];
            float2 t0 = ty0[d2], t1 = ty1[d2];
            a0 += t0.x*wa + t0.y*wb;
            a1 += t1.x*wa + t1.y*wb;
        }
        a0 += __shfl_xor(a0, 32, 64);
        a1 += __shfl_xor(a1, 32, 64);
        float fb = fc1b[j], f3 = fc3w[j];
        float p0 = fmaxf(a0+fb, 0.f)*f3;
        float p1 = fmaxf(a1+fb, 0.f)*f3;
        #pragma unroll
        for (int off=16; off>=1; off>>=1){
            p0 += __shfl_xor(p0, off, 64);
            p1 += __shfl_xor(p1, off, 64);
        }
        if (lane == 0){
            out[b0]   = p0 + fc3b[0];
            out[b0+1] = p1 + fc3b[0];
        }
    }
}

extern "C" void kernel_launch(void* const* d_in, const int* in_sizes, int n_in,
                              void* d_out, int out_size, void* d_ws, size_t ws_size,
                              hipStream_t stream) {
    const float* x      = (const float*)d_in[0];
    const float* ln_g   = (const float*)d_in[1];
    const float* ln_b   = (const float*)d_in[2];
    const float* Wup_l  = (const float*)d_in[3];
    const float* bup_l  = (const float*)d_in[4];
    const float* Wup_r  = (const float*)d_in[5];
    const float* bup_r  = (const float*)d_in[6];
    const float* conv_w = (const float*)d_in[7];
    const float* conv_b = (const float*)d_in[8];
    const float* Wq     = (const float*)d_in[9];
    const float* bq     = (const float*)d_in[10];
    const float* Wk     = (const float*)d_in[11];
    const float* bk     = (const float*)d_in[12];
    const float* Wv     = (const float*)d_in[13];
    const float* bv     = (const float*)d_in[14];
    const float* Wif    = (const float*)d_in[15];
    const float* bif    = (const float*)d_in[16];
    const float* gn_g   = (const float*)d_in[17];
    const float* gn_b   = (const float*)d_in[18];
    const float* skip   = (const float*)d_in[19];
    const float* Wdown  = (const float*)d_in[20];
    const float* bdown  = (const float*)d_in[21];
    const float* s_ln_g = (const float*)d_in[22];
    const float* s_ln_b = (const float*)d_in[23];
    const float* sW     = (const float*)d_in[24];
    const float* sR     = (const float*)d_in[25];
    const float* sb     = (const float*)d_in[26];
    const float* s_gn_g = (const float*)d_in[27];
    const float* s_gn_b = (const float*)d_in[28];
    const float* sWup1  = (const float*)d_in[29];
    const float* sbup1  = (const float*)d_in[30];
    const float* sWup2  = (const float*)d_in[31];
    const float* sbup2  = (const float*)d_in[32];
    const float* sWdown = (const float*)d_in[33];
    const float* sbdown = (const float*)d_in[34];
    const float* fc1w   = (const float*)d_in[35];
    const float* fc1b   = (const float*)d_in[36];
    const float* fc3w   = (const float*)d_in[37];
    const float* fc3b   = (const float*)d_in[38];
    float* out = (float*)d_out;

    hipLaunchKernelGGL(net_kernel, dim3(4096), dim3(64), 0, stream,
        x, ln_g, ln_b, Wup_l, bup_l, Wup_r, bup_r, conv_w, conv_b,
        Wq, bq, Wk, bk, Wv, bv, Wif, bif, gn_g, gn_b, skip, Wdown, bdown,
        s_ln_g, s_ln_b, sW, sR, sb, s_gn_g, s_gn_b,
        sWup1, sbup1, sWup2, sbup2, sWdown, sbdown,
        fc1w, fc1b, fc3w, fc3b, out);
}

// Round 10
// 132.087 us; speedup vs baseline: 2.7814x; 1.0021x over previous
//
#include <hip/hip_runtime.h>
#include <hip/hip_bf16.h>

#define SS 30
#define DD 14
#define MM 28

// Per-batch LDS float offsets (PB = 3060 fl = 12,240 B; block = 2 batches)
#define XN   0     // 420: xn -> y_m (H)
#define QH   420   // 930: h stride29 (trow<=31 writes: max 420+31*29+28=1347 < 1352)
#define CF16 1352  // 640 fl = 32 rows x 40 ushort: c bf16 -> yn fp32 (I) -> tanh TY (L)
#define UF16 1992  // 640 fl: ul bf16 -> e bf16 (G) -> UV (L0)
#define VV   2632  // 300: gx(240)+hs@240(60)
#define ST2  2932  // 64: gif (D1) -> G0 stats stride2 -> I stats (unused now)
#define EA   2996  // 32: exp(a_s), pads 30,31 = 0
#define ECM  3028  // 32: exp(-cm_t), pads = 0 -> inv (G0)
#define TY   1352  // 420 fp32: yn (I..J) then tanh(y_s) (L..M)
#define UV   1992  // 90
#define PB   3060

#define WSYNC() asm volatile("" ::: "memory")

typedef short bshort8 __attribute__((ext_vector_type(8)));
typedef float f32x16 __attribute__((ext_vector_type(16)));

union __align__(16) FragU { unsigned int u[4]; bshort8 v; };

__device__ __forceinline__ float frcp(float v){ return __builtin_amdgcn_rcpf(v); }
__device__ __forceinline__ float frsq(float v){ return __builtin_amdgcn_rsqf(v); }
__device__ __forceinline__ float fsigm(float v){ return frcp(1.f+__expf(-v)); }
__device__ __forceinline__ float fsilu(float v){ return v*frcp(1.f+__expf(-v)); }
__device__ __forceinline__ float ftanh_(float v){
    float c = fminf(fmaxf(v, -15.f), 15.f);
    float e = __expf(2.f*c);
    return (e-1.f)*frcp(e+1.f);
}
__device__ __forceinline__ float fgelu(float v){
    float t = ftanh_(0.7978845608028654f*(v + 0.044715f*v*v*v));
    return 0.5f*v*(1.f+t);
}
__device__ __forceinline__ unsigned int pkbf(float a, float b){
    __hip_bfloat162 h = __float22bfloat162_rn(make_float2(a,b));
    return *reinterpret_cast<unsigned int*>(&h);
}
__device__ __forceinline__ unsigned short bfr(float f){
    __hip_bfloat16 h = __float2bfloat16(f);
    return *reinterpret_cast<unsigned short*>(&h);
}
__device__ __forceinline__ float lobf(unsigned int u){ return __uint_as_float(u<<16); }
__device__ __forceinline__ float hibf(unsigned int u){ return __uint_as_float(u & 0xFFFF0000u); }

__device__ __forceinline__ void load_wfrag(const float* __restrict__ W,
                                           const float* __restrict__ bias, float scale,
                                           int ncol, int lo, int hi, FragU& o0, FragU& o1){
    float t[16];
    #pragma unroll
    for (int sl=0; sl<2; sl++){
        #pragma unroll
        for (int r=0;r<8;r++){
            int h = 8*hi + r + 16*sl;
            float v = 0.f;
            if (lo < ncol){
                if (h < MM) v = W[h*ncol+lo]*scale;
                else if (h == MM) v = bias[lo]*scale;
            }
            t[sl*8+r] = v;
        }
    }
    #pragma unroll
    for (int p=0;p<4;p++){
        o0.u[p] = pkbf(t[2*p],   t[2*p+1]);
        o1.u[p] = pkbf(t[8+2*p], t[8+2*p+1]);
    }
}

__device__ __forceinline__ void asm_frag(const f32x16& d, int hi, FragU& s0, FragU& s1){
    unsigned int P[8], X[8];
    #pragma unroll
    for (int m=0;m<8;m++) P[m] = pkbf(d[2*m], d[2*m+1]);
    #pragma unroll
    for (int m=0;m<8;m++) X[m] = (unsigned int)__shfl_xor((int)P[m], 32, 64);
    s0.u[0] = hi ? X[2] : P[0];  s0.u[1] = hi ? X[3] : P[1];
    s0.u[2] = hi ? P[2] : X[0];  s0.u[3] = hi ? P[3] : X[1];
    s1.u[0] = hi ? X[6] : P[4];  s1.u[1] = hi ? X[7] : P[5];
    s1.u[2] = hi ? P[6] : X[4];  s1.u[3] = hi ? P[7] : X[5];
}

extern "C" __global__ void __launch_bounds__(64)
net_kernel(const float* __restrict__ xg,
           const float* __restrict__ ln_g, const float* __restrict__ ln_b,
           const float* __restrict__ Wup_l, const float* __restrict__ bup_l,
           const float* __restrict__ Wup_r, const float* __restrict__ bup_r,
           const float* __restrict__ conv_w, const float* __restrict__ conv_b,
           const float* __restrict__ Wq, const float* __restrict__ bq,
           const float* __restrict__ Wk, const float* __restrict__ bk,
           const float* __restrict__ Wv, const float* __restrict__ bv,
           const float* __restrict__ Wif, const float* __restrict__ bif,
           const float* __restrict__ gn_g, const float* __restrict__ gn_b,
           const float* __restrict__ skip,
           const float* __restrict__ Wdown, const float* __restrict__ bdown,
           const float* __restrict__ s_ln_g, const float* __restrict__ s_ln_b,
           const float* __restrict__ sW, const float* __restrict__ sR, const float* __restrict__ sb,
           const float* __restrict__ s_gn_g, const float* __restrict__ s_gn_b,
           const float* __restrict__ sWup1, const float* __restrict__ sbup1,
           const float* __restrict__ sWup2, const float* __restrict__ sbup2,
           const float* __restrict__ sWdown, const float* __restrict__ sbdown,
           const float* __restrict__ fc1w, const float* __restrict__ fc1b,
           const float* __restrict__ fc3w, const float* __restrict__ fc3b,
           float* __restrict__ out)
{
    __shared__ __align__(16) float smAll[2*PB];
    const int lane = threadIdx.x;
    const int b0 = blockIdx.x*2;
    const float* xp0 = xg + (size_t)b0 * (SS*DD);
    const float* xp1 = xp0 + SS*DD;

    const int lo = lane & 31, hi = lane >> 5;
    const int il = lane & 31;
    const int bbD = lane >> 5;
    float* smD = smAll + bbD*PB;
    const int jq = lane % MM;
    const int gq = lane / MM;
    const bool act = lane < 56;
    const int jqi = act ? jq : 0;

    // ---- bf16 staging pads ----
    if (lane < 60){
        int bb = lane >= 30; int t = lane - bb*30;
        char* smc = (char*)(smAll + bb*PB);
        *(uint2*)(smc + CF16*4 + t*80 + 56) = make_uint2(0x3F80u, 0u);
        *(uint2*)(smc + UF16*4 + t*80 + 56) = make_uint2(0x3F80u, 0u);
    }
    if (lane < 40){
        int bb = lane >= 20; int i = lane - bb*20;
        char* smc = (char*)(smAll + bb*PB);
        *(uint2*)(smc + CF16*4 + 30*80 + i*8) = make_uint2(0u,0u);
        *(uint2*)(smc + UF16*4 + 30*80 + i*8) = make_uint2(0u,0u);
    }

    // ---- MFMA weight frags (shared across batches) ----
    FragU wq0,wq1, wk0,wk1, wv0,wv1, wd0,wd1;
    const float rs28 = 0.18898223650461363f;
    load_wfrag(Wq, bq, 1.f,  MM, lo, hi, wq0, wq1);
    load_wfrag(Wk, bk, rs28, MM, lo, hi, wk0, wk1);
    load_wfrag(Wv, bv, 1.f,  MM, lo, hi, wv0, wv1);
    load_wfrag(Wdown, bdown, 1.f, DD, lo, hi, wd0, wd1);

    // ---- VALU weight preloads ----
    float wl[DD], cw[4], wr[DD];
    float blr, cbr, brr;
    {
        #pragma unroll
        for (int d=0; d<DD; d++){ wl[d] = Wup_l[d*MM+jqi]; wr[d] = Wup_r[d*MM+jqi]; }
        #pragma unroll
        for (int k=0; k<4; k++) cw[k] = conv_w[k*MM+jqi];
        blr = bup_l[jqi]; cbr = conv_b[jqi]; brr = bup_r[jqi];
    }

    // ---- Phase A: LN1 -> xn ----
    if (lane < 60){
        int bb = lane >= 30; int t = lane - bb*30;
        float* sm = smAll + bb*PB;
        const float2* xr = (const float2*)((bb? xp1:xp0) + t*DD);
        float xv[DD];
        float s=0.f, s2=0.f;
        #pragma unroll
        for (int u=0;u<7;u++){ float2 f=xr[u]; xv[2*u]=f.x; xv[2*u+1]=f.y; s+=f.x+f.y; s2+=f.x*f.x+f.y*f.y; }
        float mu=s*(1.f/DD), var=s2*(1.f/DD)-mu*mu, rsg=frsq(var+1e-5f);
        #pragma unroll
        for (int d=0; d<DD; d++) sm[XN+t*DD+d] = (xv[d]-mu)*rsg*ln_g[d]+ln_b[d];
    }
    WSYNC();

    // ---- Phase B+C fused: ul in regs; conv from regs + 3 shuffles ----
    #pragma unroll
    for (int bb=0; bb<2; bb++){
        float* sm = smAll + bb*PB;
        unsigned short* smu = (unsigned short*)sm;
        float ulr[15];
        #pragma unroll
        for (int tt=0; tt<15; tt++){
            int t = gq*15+tt;
            float a = blr;
            if (act){
                const float2* xr = (const float2*)&sm[XN + t*DD];
                #pragma unroll
                for (int u=0;u<7;u++){ float2 f = xr[u]; a += f.x*wl[2*u] + f.y*wl[2*u+1]; }
                smu[UF16*2 + t*40 + jq] = bfr(a);
            }
            ulr[tt] = a;
        }
        float u12 = __shfl(ulr[12], jq, 64);
        float u13 = __shfl(ulr[13], jq, 64);
        float u14 = __shfl(ulr[14], jq, 64);
        float gqf = (gq==1) ? 1.f : 0.f;
        #pragma unroll
        for (int tt=0; tt<15; tt++){
            int t = gq*15+tt;
            float h3, h2, h1;
            if (tt>=3){ h3=ulr[tt-3]; h2=ulr[tt-2]; h1=ulr[tt-1]; }
            else if (tt==2){ h3=gqf*u14; h2=ulr[0]; h1=ulr[1]; }
            else if (tt==1){ h3=gqf*u13; h2=gqf*u14; h1=ulr[0]; }
            else           { h3=gqf*u12; h2=gqf*u13; h1=gqf*u14; }
            float a = cbr + cw[0]*h3 + cw[1]*h2 + cw[2]*h1 + cw[3]*ulr[tt];
            if (act) smu[CF16*2 + t*40 + jq] = bfr(fsilu(a));
        }
    }
    WSYNC();

    // ---- gif = c(bf16) @ Wif + bif -> ST2 ----
    #pragma unroll
    for (int bb=0; bb<2; bb++){
        float* sm = smAll + bb*PB;
        char* smc = (char*)sm;
        if (lane < SS*2){
            int t=lane>>1, gg=lane&1;
            float a = bif[gg];
            const uint2* cr = (const uint2*)(smc + CF16*4 + t*80);
            #pragma unroll
            for (int p=0;p<7;p++){
                uint2 cu = cr[p];
                a += lobf(cu.x)*Wif[(4*p)*2+gg]   + hibf(cu.x)*Wif[(4*p+1)*2+gg]
                   + lobf(cu.y)*Wif[(4*p+2)*2+gg] + hibf(cu.y)*Wif[(4*p+3)*2+gg];
            }
            sm[ST2+lane]=a;
        }
    }
    WSYNC();

    // ---- D3: gate pre-scan (split, width-32) ----
    if (il < SS){
        float i_ = smD[ST2+2*il], f_ = smD[ST2+2*il+1];
        float F = f_, v;
        v = __shfl_up(F,1,32);  if (il>=1)  F += v;
        v = __shfl_up(F,2,32);  if (il>=2)  F += v;
        v = __shfl_up(F,4,32);  if (il>=4)  F += v;
        v = __shfl_up(F,8,32);  if (il>=8)  F += v;
        v = __shfl_up(F,16,32); if (il>=16) F += v;
        float a = i_ - F;
        float cm = a;
        v = __shfl_up(cm,1,32);  if (il>=1)  cm = fmaxf(cm,v);
        v = __shfl_up(cm,2,32);  if (il>=2)  cm = fmaxf(cm,v);
        v = __shfl_up(cm,4,32);  if (il>=4)  cm = fmaxf(cm,v);
        v = __shfl_up(cm,8,32);  if (il>=8)  cm = fmaxf(cm,v);
        v = __shfl_up(cm,16,32); if (il>=16) cm = fmaxf(cm,v);
        cm = fmaxf(cm, 0.f);
        smD[EA+il]  = __expf(a);
        smD[ECM+il] = __expf(-cm);
    } else {
        smD[EA+il] = 0.f; smD[ECM+il] = 0.f;
    }
    WSYNC();

    // ---- urv precompute (regs; fills MFMA stall slots below) ----
    float urvA[15], urvB[15];
    #pragma unroll
    for (int bb=0; bb<2; bb++){
        float* sm = smAll + bb*PB;
        #pragma unroll
        for (int tt=0; tt<15; tt++){
            int t = gq*15+tt;
            float a = brr;
            if (act){
                const float2* xr = (const float2*)&sm[XN + t*DD];
                #pragma unroll
                for (int u=0;u<7;u++){ float2 f=xr[u]; a += f.x*wr[2*u]+f.y*wr[2*u+1]; }
            }
            if (bb) urvB[tt] = a; else urvA[tt] = a;
        }
    }

    // ================= MFMA section: q,k,v + scores + PV =================
    #pragma unroll
    for (int bb=0; bb<2; bb++){
        float* sm = smAll + bb*PB;
        char* smc = (char*)sm;
        FragU cf0 = *(const FragU*)(smc + CF16*4 + lo*80 + hi*16);
        FragU cf1 = *(const FragU*)(smc + CF16*4 + lo*80 + hi*16 + 32);
        FragU uf0 = *(const FragU*)(smc + UF16*4 + lo*80 + hi*16);
        FragU uf1 = *(const FragU*)(smc + UF16*4 + lo*80 + hi*16 + 32);

        f32x16 aq = {}, ak = {}, av = {};
        aq = __builtin_amdgcn_mfma_f32_32x32x16_bf16(wq0.v, cf0.v, aq, 0,0,0);
        aq = __builtin_amdgcn_mfma_f32_32x32x16_bf16(wq1.v, cf1.v, aq, 0,0,0);
        ak = __builtin_amdgcn_mfma_f32_32x32x16_bf16(wk0.v, cf0.v, ak, 0,0,0);
        ak = __builtin_amdgcn_mfma_f32_32x32x16_bf16(wk1.v, cf1.v, ak, 0,0,0);
        av = __builtin_amdgcn_mfma_f32_32x32x16_bf16(uf0.v, wv0.v, av, 0,0,0);
        av = __builtin_amdgcn_mfma_f32_32x32x16_bf16(uf1.v, wv1.v, av, 0,0,0);

        FragU eq0, eq1, ek0, ek1;
        asm_frag(aq, hi, eq0, eq1);
        asm_frag(ak, hi, ek0, ek1);

        f32x16 es = {};
        es = __builtin_amdgcn_mfma_f32_32x32x16_bf16(ek0.v, eq0.v, es, 0,0,0);
        es = __builtin_amdgcn_mfma_f32_32x32x16_bf16(ek1.v, eq1.v, es, 0,0,0);

        float ecmt = sm[ECM + lo];
        #pragma unroll
        for (int g=0; g<16; g++){
            int srow = (g&3) + 8*(g>>2) + 4*hi;
            float w = sm[EA + srow] * ecmt;
            es[g] = (srow <= lo) ? es[g]*w : 0.f;
        }

        FragU fa0, fa1, vb0, vb1;
        asm_frag(es, hi, fa0, fa1);
        asm_frag(av, hi, vb0, vb1);
        if (lo == MM){
            const unsigned int ONE2 = 0x3F803F80u;
            vb0.u[0]=ONE2; vb0.u[1]=ONE2; vb0.u[2]=ONE2; vb0.u[3]=ONE2;
            vb1.u[0]=ONE2; vb1.u[1]=ONE2; vb1.u[2]=ONE2; vb1.u[3]= hi ? 0u : ONE2;
        }
        f32x16 hacc = {};
        hacc = __builtin_amdgcn_mfma_f32_32x32x16_bf16(fa0.v, vb0.v, hacc, 0,0,0);
        hacc = __builtin_amdgcn_mfma_f32_32x32x16_bf16(fa1.v, vb1.v, hacc, 0,0,0);

        #pragma unroll
        for (int g=0; g<16; g++){
            int trow = (g&3) + 8*(g>>2) + 4*hi;
            if (lo < 29) sm[QH + trow*29 + lo] = hacc[g];
        }
    }
    WSYNC();

    // ---- VALU weight preloads for G/L ----
    const int dq  = lane % DD;
    const int g4  = lane / DD;
    const int dqi = act ? dq : 0;
    float skr, ggr, gbr;
    skr=skip[jqi]; ggr=gn_g[jqi]; gbr=gn_b[jqi];
    float swd0 = sWdown[0*DD+dqi], swd1 = sWdown[1*DD+dqi], swd2 = sWdown[2*DD+dqi];
    float sbd  = sbdown[dqi];

    // ---- Phase G0: per-t stats (split) ----
    if (il < SS){
        float s=0.f,s2=0.f;
        #pragma unroll
        for (int u=0;u<MM;u++){ float v=smD[QH+il*29+u]; s+=v; s2+=v*v; }
        float inv = frcp(fmaxf(fabsf(smD[QH+il*29+MM]), 1.f));
        float mu=s*(1.f/MM), var=s2*(1.f/MM)-mu*mu;
        smD[ST2+il*2]   = mu*inv;
        smD[ST2+il*2+1] = frsq(var*inv*inv + 1e-5f);
        smD[ECM+il]     = inv;
    }
    WSYNC();

    // ---- Phase G: e = (hn + skip*c)*silu(urv) -> e bf16 ----
    #pragma unroll
    for (int bb=0; bb<2; bb++){
        float* sm = smAll + bb*PB;
        unsigned short* smu = (unsigned short*)sm;
        #pragma unroll
        for (int tt=0;tt<15;tt++){
            int t=gq*15+tt;
            if (act){
                float urv = bb ? urvB[tt] : urvA[tt];
                float inv = sm[ECM+t];
                float hv = sm[QH+t*29+jq]*inv;
                float hn = (hv-sm[ST2+t*2])*sm[ST2+t*2+1]*ggr + gbr;
                float cv = lobf((unsigned int)smu[CF16*2 + t*40 + jq]);
                float h2 = hn + skr*cv;
                smu[UF16*2 + t*40 + jq] = bfr(h2 * fsilu(urv));
            }
        }
    }
    WSYNC();

    // ---- Phase H (MFMA): y_m = e @ WdownAug + x -> XN ----
    #pragma unroll
    for (int bb=0; bb<2; bb++){
        float* sm = smAll + bb*PB;
        char* smc = (char*)sm;
        const float* xp = bb ? xp1 : xp0;
        FragU ef0 = *(const FragU*)(smc + UF16*4 + lo*80 + hi*16);
        FragU ef1 = *(const FragU*)(smc + UF16*4 + lo*80 + hi*16 + 32);
        f32x16 ym = {};
        ym = __builtin_amdgcn_mfma_f32_32x32x16_bf16(ef0.v, wd0.v, ym, 0,0,0);
        ym = __builtin_amdgcn_mfma_f32_32x32x16_bf16(ef1.v, wd1.v, ym, 0,0,0);
        #pragma unroll
        for (int g=0; g<16; g++){
            int trow = (g&3) + 8*(g>>2) + 4*hi;
            if (lo < DD && trow < SS) sm[XN + trow*DD + lo] = ym[g] + xp[trow*DD + lo];
        }
    }
    WSYNC();

    // ---- Phase I: sLSTM LN -> write yn to TY (c dead) ----
    if (il < SS){
        const float2* yr=(const float2*)&smD[XN+il*DD];
        float yv[DD];
        float s=0.f,s2=0.f;
        #pragma unroll
        for (int u=0;u<7;u++){ float2 f=yr[u]; yv[2*u]=f.x; yv[2*u+1]=f.y; s+=f.x+f.y; s2+=f.x*f.x+f.y*f.y; }
        float mu=s*(1.f/DD), var=s2*(1.f/DD)-mu*mu, rs=frsq(var+1e-5f);
        #pragma unroll
        for (int d=0;d<DD;d++)
            smD[TY+il*DD+d] = (yv[d]-mu)*rs*s_ln_g[d] + s_ln_b[d];
    }
    WSYNC();

    // ---- Phase J: gx = yn @ sW + sb -> VV ----
    #pragma unroll
    for (int bb=0; bb<2; bb++){
        float* sm = smAll + bb*PB;
        for (int idx=lane; idx<SS*8; idx+=64){
            int t=idx>>3, gg=idx&7;
            float a=sb[gg];
            const float2* yr = (const float2*)&sm[TY+t*DD];
            #pragma unroll
            for (int u=0;u<7;u++){
                float2 f=yr[u];
                a += f.x*sW[(2*u)*8+gg] + f.y*sW[(2*u+1)*8+gg];
            }
            sm[VV+idx]=a;
        }
    }
    WSYNC();

    // ---- Phase K: sLSTM scan (split; gx prefetch; folded rcp) ----
    {
        float R0[8], R1[8];
        #pragma unroll
        for (int g=0; g<8; g++){ R0[g]=sR[g]; R1[g]=sR[8+g]; }
        float h0=0.f,h1=0.f,c0=0.f,c1=0.f,n0=0.f,n1=0.f,m0=0.f,m1=0.f;
        const float2* gr = (const float2*)&smD[VV];
        float2 A0=gr[0], A1=gr[1], A2=gr[2], A3=gr[3];
        for (int t=0; t<SS; t++){
            float2 N0,N1,N2,N3;
            if (t < SS-1){
                const float2* nx = (const float2*)&smD[VV+(t+1)*8];
                N0=nx[0]; N1=nx[1]; N2=nx[2]; N3=nx[3];
            }
            float g0=A0.x+h0*R0[0]+h1*R1[0], g1=A0.y+h0*R0[1]+h1*R1[1];
            float g2=A1.x+h0*R0[2]+h1*R1[2], g3=A1.y+h0*R0[3]+h1*R1[3];
            float g4v=A2.x+h0*R0[4]+h1*R1[4], g5=A2.y+h0*R0[5]+h1*R1[5];
            float g6=A3.x+h0*R0[6]+h1*R1[6], g7=A3.y+h0*R0[7]+h1*R1[7];
            float z0=ftanh_(g0), z1=ftanh_(g1);
            float mn0=fmaxf(g4v+m0, g2), mn1=fmaxf(g5+m1, g3);
            float ie0=__expf(g2-mn0), ie1=__expf(g3-mn1);
            float fe0=__expf(g4v+m0-mn0), fe1=__expf(g5+m1-mn1);
            c0 = fe0*c0 + ie0*z0;  c1 = fe1*c1 + ie1*z1;
            n0 = fe0*n0 + ie0;     n1 = fe1*n1 + ie1;
            h0 = c0*frcp((1.f+__expf(-g6))*n0);
            h1 = c1*frcp((1.f+__expf(-g7))*n1);
            m0 = mn0; m1 = mn1;
            if (il == 0){ smD[VV+240+t*2] = h0; smD[VV+240+t*2+1] = h1; }
            A0=N0; A1=N1; A2=N2; A3=N3;
        }
    }
    WSYNC();

    // ---- Phase L0: per-t u-values -> UV ----
    if (il < SS){
        float a0 = smD[VV+240+il*2], a1 = smD[VV+240+il*2+1];
        float mu = 0.5f*(a0+a1);
        float d0 = a0-mu, d1 = a1-mu;
        float var = 0.5f*(d0*d0 + d1*d1);
        float rsg = frsq(var + 1e-5f);
        float hn0 = d0*rsg*s_gn_g[0] + s_gn_b[0];
        float hn1 = d1*rsg*s_gn_g[1] + s_gn_b[1];
        #pragma unroll
        for (int u3=0; u3<3; u3++){
            float p1 = hn0*sWup1[u3] + hn1*sWup1[3+u3] + sbup1[u3];
            float p2 = hn0*sWup2[u3] + hn1*sWup2[3+u3] + sbup2[u3];
            smD[UV + il*3 + u3] = fgelu(p1)*p2;
        }
    }
    WSYNC();

    // ---- Phase L: y_s + tanh -> TY (yn dead) ----
    #pragma unroll
    for (int bb=0; bb<2; bb++){
        float* sm = smAll + bb*PB;
        #pragma unroll
        for (int tt=0; tt<8; tt++){
            int t=g4*8+tt;
            if (act && t<SS){
                float acc = sbd + sm[XN+t*DD+dq]
                          + sm[UV+t*3]*swd0 + sm[UV+t*3+1]*swd1 + sm[UV+t*3+2]*swd2;
                sm[TY+t*DD+dq] = ftanh_(acc);
            }
        }
    }
    WSYNC();

    // ---- Phase M: head fc1+fc3 (w1 loads shared) ----
    {
        int j = lane & 31, half = lane >> 5;
        const float2* ty0 = (const float2*)&smAll[TY + half*210];
        const float2* ty1 = (const float2*)&smAll[PB + TY + half*210];
        float a0 = 0.f, a1 = 0.f;
        const float* w1 = fc1w + (half*210)*32 + j;
        for (int d2=0; d2<105; d2++){
            float wa = w1[(2*d2)*32], wb = w1[(2*d2+1)*32];
            float2 t0 = ty0[d2], t1 = ty1[d2];
            a0 += t0.x*wa + t0.y*wb;
            a1 += t1.x*wa + t1.y*wb;
        }
        a0 += __shfl_xor(a0, 32, 64);
        a1 += __shfl_xor(a1, 32, 64);
        float fb = fc1b[j], f3 = fc3w[j];
        float p0 = fmaxf(a0+fb, 0.f)*f3;
        float p1 = fmaxf(a1+fb, 0.f)*f3;
        #pragma unroll
        for (int off=16; off>=1; off>>=1){
            p0 += __shfl_xor(p0, off, 64);
            p1 += __shfl_xor(p1, off, 64);
        }
        if (lane == 0){
            out[b0]   = p0 + fc3b[0];
            out[b0+1] = p1 + fc3b[0];
        }
    }
}

extern "C" void kernel_launch(void* const* d_in, const int* in_sizes, int n_in,
                              void* d_out, int out_size, void* d_ws, size_t ws_size,
                              hipStream_t stream) {
    const float* x      = (const float*)d_in[0];
    const float* ln_g   = (const float*)d_in[1];
    const float* ln_b   = (const float*)d_in[2];
    const float* Wup_l  = (const float*)d_in[3];
    const float* bup_l  = (const float*)d_in[4];
    const float* Wup_r  = (const float*)d_in[5];
    const float* bup_r  = (const float*)d_in[6];
    const float* conv_w = (const float*)d_in[7];
    const float* conv_b = (const float*)d_in[8];
    const float* Wq     = (const float*)d_in[9];
    const float* bq     = (const float*)d_in[10];
    const float* Wk     = (const float*)d_in[11];
    const float* bk     = (const float*)d_in[12];
    const float* Wv     = (const float*)d_in[13];
    const float* bv     = (const float*)d_in[14];
    const float* Wif    = (const float*)d_in[15];
    const float* bif    = (const float*)d_in[16];
    const float* gn_g   = (const float*)d_in[17];
    const float* gn_b   = (const float*)d_in[18];
    const float* skip   = (const float*)d_in[19];
    const float* Wdown  = (const float*)d_in[20];
    const float* bdown  = (const float*)d_in[21];
    const float* s_ln_g = (const float*)d_in[22];
    const float* s_ln_b = (const float*)d_in[23];
    const float* sW     = (const float*)d_in[24];
    const float* sR     = (const float*)d_in[25];
    const float* sb     = (const float*)d_in[26];
    const float* s_gn_g = (const float*)d_in[27];
    const float* s_gn_b = (const float*)d_in[28];
    const float* sWup1  = (const float*)d_in[29];
    const float* sbup1  = (const float*)d_in[30];
    const float* sWup2  = (const float*)d_in[31];
    const float* sbup2  = (const float*)d_in[32];
    const float* sWdown = (const float*)d_in[33];
    const float* sbdown = (const float*)d_in[34];
    const float* fc1w   = (const float*)d_in[35];
    const float* fc1b   = (const float*)d_in[36];
    const float* fc3w   = (const float*)d_in[37];
    const float* fc3b   = (const float*)d_in[38];
    float* out = (float*)d_out;

    hipLaunchKernelGGL(net_kernel, dim3(4096), dim3(64), 0, stream,
        x, ln_g, ln_b, Wup_l, bup_l, Wup_r, bup_r, conv_w, conv_b,
        Wq, bq, Wk, bk, Wv, bv, Wif, bif, gn_g, gn_b, skip, Wdown, bdown,
        s_ln_g, s_ln_b, sW, sR, sb, s_gn_g, s_gn_b,
        sWup1, sbup1, sWup2, sbup2, sWdown, sbdown,
        fc1w, fc1b, fc3w, fc3b, out);
}